// Round 1
// baseline (1069.199 us; speedup 1.0000x reference)
//
#include <hip/hip_runtime.h>
#include <math.h>

#define B_    64
#define N_    1024
#define D_    128
#define DP1   129
#define NC_   10
#define QB    128     // queries per block (4 waves x 32)
#define KT    32      // key tile
#define SCf   0.31622776601683794f
#define SCALE 0.08804509063256238f   // 1/sqrt(129)

typedef __bf16 bf16x8 __attribute__((ext_vector_type(8)));
typedef float  f32x16 __attribute__((ext_vector_type(16)));
typedef unsigned long long ull;

#define MFMA(a, b, c) __builtin_amdgcn_mfma_f32_32x32x16_bf16((a), (b), (c), 0, 0, 0)

static __device__ __forceinline__ float dpp_add_step(float f, int ctrl, int rmask) {
    if (ctrl == 0x111) { int t = __builtin_amdgcn_update_dpp(0, __builtin_bit_cast(int, f), 0x111, 0xf, 0xf, true); return f + __builtin_bit_cast(float, t); }
    if (ctrl == 0x112) { int t = __builtin_amdgcn_update_dpp(0, __builtin_bit_cast(int, f), 0x112, 0xf, 0xf, true); return f + __builtin_bit_cast(float, t); }
    if (ctrl == 0x114) { int t = __builtin_amdgcn_update_dpp(0, __builtin_bit_cast(int, f), 0x114, 0xf, 0xf, true); return f + __builtin_bit_cast(float, t); }
    if (ctrl == 0x118) { int t = __builtin_amdgcn_update_dpp(0, __builtin_bit_cast(int, f), 0x118, 0xf, 0xf, true); return f + __builtin_bit_cast(float, t); }
    if (ctrl == 0x142 && rmask == 0xa) { int t = __builtin_amdgcn_update_dpp(0, __builtin_bit_cast(int, f), 0x142, 0xa, 0xf, true); return f + __builtin_bit_cast(float, t); }
    { int t = __builtin_amdgcn_update_dpp(0, __builtin_bit_cast(int, f), 0x143, 0xc, 0xf, true); return f + __builtin_bit_cast(float, t); }
}

// full 64-lane sum, result broadcast to all lanes
static __device__ __forceinline__ float wave_sum64(float f) {
    f = dpp_add_step(f, 0x111, 0xf);
    f = dpp_add_step(f, 0x112, 0xf);
    f = dpp_add_step(f, 0x114, 0xf);
    f = dpp_add_step(f, 0x118, 0xf);
    f = dpp_add_step(f, 0x142, 0xa);
    f = dpp_add_step(f, 0x143, 0xc);
    return __builtin_bit_cast(float, __builtin_amdgcn_readlane(__builtin_bit_cast(int, f), 63));
}

// per-32-lane-half sum, each lane gets its half's total
static __device__ __forceinline__ float half_sum32(float f, int half) {
    f = dpp_add_step(f, 0x111, 0xf);
    f = dpp_add_step(f, 0x112, 0xf);
    f = dpp_add_step(f, 0x114, 0xf);
    f = dpp_add_step(f, 0x118, 0xf);
    f = dpp_add_step(f, 0x142, 0xa);
    float s0 = __builtin_bit_cast(float, __builtin_amdgcn_readlane(__builtin_bit_cast(int, f), 31));
    float s1 = __builtin_bit_cast(float, __builtin_amdgcn_readlane(__builtin_bit_cast(int, f), 63));
    return half ? s1 : s0;
}

static __device__ __forceinline__ float readlane_f(float v, int lane) {
    return __builtin_bit_cast(float, __builtin_amdgcn_readlane(__builtin_bit_cast(int, v), lane));
}

static __device__ __forceinline__ bf16x8 ld_lds8(const __bf16* p) {
    union { bf16x8 v; ull q[2]; } u;
    u.q[0] = *(const ull*)(p);
    u.q[1] = *(const ull*)(p + 4);
    return u.v;
}

// async global->LDS, 16B per lane; LDS dest = wave-uniform base + lane*16 (HW-added)
typedef const __attribute__((address_space(1))) unsigned int* glds_gp;
typedef __attribute__((address_space(3))) unsigned int* glds_lp;
static __device__ __forceinline__ void glds16(const void* g, void* l) {
    __builtin_amdgcn_global_load_lds((glds_gp)g, (glds_lp)l, 16, 0, 0);
}

// ---------------- mask dtype detection (int32 vs packed int8 bool) ----------------
__global__ __launch_bounds__(256) void k_detect_mask(const int* __restrict__ mask_w,
                                                     int* __restrict__ flag) {
    __shared__ int bad;
    if (threadIdx.x == 0) bad = 0;
    __syncthreads();
    int local = 0;
    for (int i = threadIdx.x; i < 16384; i += 256) {
        int v = mask_w[i];
        if (v != 0 && v != 1) local = 1;
    }
    if (local) atomicOr(&bad, 1);
    __syncthreads();
    if (threadIdx.x == 0) *flag = bad;   // 1 => data is packed int8 bools
}

static __device__ __forceinline__ int read_mask(const int* mw, int is_i8, int idx) {
    if (is_i8) return (int)((const unsigned char*)mw)[idx];
    return mw[idx];
}

// ---------------- Wo -> bf16 hi/lo, layout [o][144] (K padded 129->144 with zeros) ----------------
__global__ __launch_bounds__(256) void k_prep_wo(const float* __restrict__ Wo,
                                                 __bf16* __restrict__ Woh,
                                                 __bf16* __restrict__ Wol) {
    int idx = blockIdx.x * 256 + threadIdx.x;
    if (idx >= 128 * 144) return;
    int o = idx / 144, d = idx - o * 144;
    float v = (d < DP1) ? Wo[o * DP1 + d] : 0.f;
    __bf16 h = (__bf16)v;
    Woh[idx] = h;
    Wol[idx] = (__bf16)(v - (float)h);
}

// ---------------- embedding + Lorentz expmap0 -> bf16 hi/lo rows + comp0/comp128 f32 ----------------
// r11: rows written with 16B-granule XOR swizzle (granule g at position g ^ (row&15)) so that
// k_attn can stage with global_load_lds (linear dest) and still read LDS bank-conflict-free.
__global__ __launch_bounds__(256) void k_prep(const int* __restrict__ tok,
                                              const float* __restrict__ emb,
                                              __bf16* __restrict__ Xh, __bf16* __restrict__ Xl,
                                              float* __restrict__ X0g, float* __restrict__ X128g) {
    __shared__ float Xf[64][132];
    const int t = threadIdx.x, w = t >> 6, l = t & 63;
    const int base = blockIdx.x * 64;
    for (int it = 0; it < 16; ++it) {
        const int tk = w * 16 + it;
        const int id = tok[base + tk];
        const float2 v = ((const float2*)(emb + (size_t)id * D_))[l];
        float s = wave_sum64(v.x * v.x + v.y * v.y);
        float nv = fmaxf(sqrtf(s), 1e-7f);
        float a = SCf * nv;
        float a2 = a * a;
        float shc, ch;
        if (a < 0.5f) {
            shc = 1.f + a2 * (1.f/6.f) * (1.f + a2 * (1.f/20.f) * (1.f + a2 * (1.f/42.f)));
            ch  = 1.f + a2 * 0.5f * (1.f + a2 * (1.f/12.f) * (1.f + a2 * (1.f/30.f)));
        } else {
            float ea = __expf(a), ei = 1.f / ea;
            ch = 0.5f * (ea + ei);
            shc = 0.5f * (ea - ei) / a;
        }
        Xf[tk][1 + 2 * l] = v.x * shc;
        Xf[tk][2 + 2 * l] = v.y * shc;
        if (l == 0) Xf[tk][0] = ch / SCf;
    }
    __syncthreads();
    const int tk2 = t >> 2, dg = (t & 3) * 32;
    const int sw = tk2 & 15;                       // (global row)&15 == tk2&15 (base mult of 64)
    for (int i = 0; i < 32; i += 8) {
        bf16x8 hv, lv;
        #pragma unroll
        for (int j = 0; j < 8; ++j) {
            float f = Xf[tk2][dg + i + j];
            __bf16 h = (__bf16)f;
            hv[j] = h;
            lv[j] = (__bf16)(f - (float)h);
        }
        const int g = (dg + i) >> 3;               // logical 8-elem granule 0..15
        const int off = ((g ^ sw) << 3);           // swizzled u16 offset within row
        *(bf16x8*)(Xh + (size_t)(base + tk2) * D_ + off) = hv;
        *(bf16x8*)(Xl + (size_t)(base + tk2) * D_ + off) = lv;
    }
    if (t < 64) {
        X0g[base + t]   = Xf[t][0];
        X128g[base + t] = Xf[t][D_];
    }
}

// ---------------- fused MFMA attention ----------------
// r10: grid x=batch -> XCD=b%8, per-XCD K working set 8x512KB=4MB=L2 (FETCH 154->35MB).
// r11: (a) global_load_lds staging (linear LDS dest, swizzle baked into global layout by k_prep)
//      -> no reg round-trip, no ds_write staging, phase-A reads become single ds_read_b128;
//      (b) LDS 53.8->51.2KB + launch_bounds(256,3) -> 3 blocks/CU (was 2), 3 waves/SIMD;
//      (c) s_setprio(1) around MFMA clusters (T5).
__global__ __launch_bounds__(256, 3) void k_attn(
        const __bf16* __restrict__ Xh, const __bf16* __restrict__ Xl,
        const float* __restrict__ X0g, const float* __restrict__ X128g,
        const int* __restrict__ mask, const int* __restrict__ mflag,
        const __bf16* __restrict__ Woh, const __bf16* __restrict__ Wol,
        const float* __restrict__ bo,
        float* __restrict__ Y, float* __restrict__ Y2) {
    extern __shared__ char smem[];
    // KB[2]: per buffer KH 32x128 bf16 (8192B) + KL 32x128 bf16 (8192B); two buffers 32768 B
    __bf16* KB = (__bf16*)smem;
    __bf16* Pb = (__bf16*)(smem + 32768);       // 18432 B (per-wave P hi/lo, rows 36-stride)
    __shared__ float K0s[2][KT];
    __shared__ float K128s[2][KT];
    __shared__ int   Ms[2][KT];

    const int b    = blockIdx.x;                // batch on x: XCD-local L2 reuse
    const int qb   = blockIdx.y * QB;
    const int t    = threadIdx.x;
    const int w    = t >> 6;
    const int l    = t & 63;
    const int l31  = l & 31;
    const int half = l >> 5;
    const int is8  = *mflag;

    // ---- Q fragments (A operand): A[m=lane&31][k=half*8+j], hi/lo, 8 k-steps over comps 0..127 ----
    const size_t qrow = (size_t)(b * N_ + qb + w * 32 + l31);
    const int swq = l31 & 15;                   // qrow&15 == l31&15
    bf16x8 qfh[8], qfl[8];
    #pragma unroll
    for (int ks = 0; ks < 8; ++ks) {
        const int off = (((2 * ks + half) ^ swq) << 3);
        qfh[ks] = *(const bf16x8*)(Xh + qrow * D_ + off);
        qfl[ks] = *(const bf16x8*)(Xl + qrow * D_ + off);
    }
    float q0[16], q128[16];
    #pragma unroll
    for (int r = 0; r < 16; ++r) {
        const int qr = (r & 3) + 8 * (r >> 2) + 4 * half;
        q0[r]   = X0g[b * N_ + qb + w * 32 + qr];
        q128[r] = X128g[b * N_ + qb + w * 32 + qr];
    }

    // ---- staging: async global->LDS (both layouts linear; swizzle already baked in global) ----
    auto stage = [&](int kt, int buf) {
        const size_t gb = (size_t)(b * N_ + kt * KT) * (D_ * 2);   // byte offset of tile
        const char* gh = (const char*)Xh + gb + w * 2048;
        const char* gl = (const char*)Xl + gb + w * 2048;
        char* lh = smem + buf * 16384 + w * 2048;
        char* ll = smem + buf * 16384 + 8192 + w * 2048;
        glds16(gh + l * 16,        lh);
        glds16(gh + 1024 + l * 16, lh + 1024);
        glds16(gl + l * 16,        ll);
        glds16(gl + 1024 + l * 16, ll + 1024);
    };
    float sK0 = 0.f, sK128 = 0.f;
    int   sM = 0;
    auto ldK = [&](int kt) {
        if (t < KT) {
            sK0   = X0g[b * N_ + kt * KT + t];
            sK128 = X128g[b * N_ + kt * KT + t];
            sM    = read_mask(mask, is8, b * N_ + kt * KT + t);
        }
    };
    auto stK = [&](int buf) {
        if (t < KT) { K0s[buf][t] = sK0; K128s[buf][t] = sK128; Ms[buf][t] = sM; }
    };

    f32x16 accM[4] = {};
    float  mu128p[16] = {};

    stage(0, 0);
    ldK(0);
    stK(0);

    for (int kt = 0; kt < N_ / KT; ++kt) {
        __syncthreads();                         // drains vmcnt: buffer kt&1 fully staged
        const int cur = kt & 1;
        const int ktn = (kt < 31) ? kt + 1 : 31;
        stage(ktn, cur ^ 1);                     // async loads overlap this tile's compute
        ldK(ktn);

        const __bf16* KH = KB + cur * 8192;
        const __bf16* KL = KH + 4096;

        // ---- phase A: S = Q . K ----
        f32x16 accS = {};
        __builtin_amdgcn_s_setprio(1);
        #pragma unroll
        for (int ks = 0; ks < 8; ++ks) {
            const int off = (((2 * ks + half) ^ (l31 & 15)) << 3);   // row = key = l31
            bf16x8 bh = *(const bf16x8*)(KH + l31 * D_ + off);
            bf16x8 bl = *(const bf16x8*)(KL + l31 * D_ + off);
            accS = MFMA(qfh[ks], bh, accS);
            accS = MFMA(qfh[ks], bl, accS);
            accS = MFMA(qfl[ks], bh, accS);
        }
        __builtin_amdgcn_s_setprio(0);
        const float k0v = K0s[cur][l31], k128v = K128s[cur][l31];
        const int   mv  = Ms[cur][l31];
        #pragma unroll
        for (int r = 0; r < 16; ++r) {
            float sc = (2.f * q0[r] * k0v - accS[r] - q128[r] * k128v) * SCALE;
            float e  = mv ? __expf(sc) : 0.f;
            mu128p[r] += e * k128v;
            __bf16 eh = (__bf16)e;
            __bf16 el = (__bf16)(e - (float)eh);
            const int qr = (r & 3) + 8 * (r >> 2) + 4 * half;
            Pb[(w * 2 + 0) * 1152 + qr * 36 + l31] = eh;
            Pb[(w * 2 + 1) * 1152 + qr * 36 + l31] = el;
        }

        // ---- phase B: mu += P . X; B-fragments = columns of KH/KL (swizzled gather) ----
        #pragma unroll
        for (int ks = 0; ks < 2; ++ks) {
            bf16x8 ah = ld_lds8(Pb + (w * 2 + 0) * 1152 + l31 * 36 + ks * 16 + half * 8);
            bf16x8 al = ld_lds8(Pb + (w * 2 + 1) * 1152 + l31 * 36 + ks * 16 + half * 8);
            #pragma unroll
            for (int nt = 0; nt < 4; ++nt) {
                bf16x8 bh, bl;
                #pragma unroll
                for (int j = 0; j < 8; ++j) {
                    const int key = ks * 16 + half * 8 + j;
                    const int swk = half * 8 + j;            // key&15
                    const int idx = key * D_ +
                        ((((nt * 4 + (l31 >> 3)) ^ swk) << 3) | (l31 & 7));
                    bh[j] = KH[idx];
                    bl[j] = KL[idx];
                }
                __builtin_amdgcn_s_setprio(1);
                accM[nt] = MFMA(ah, bh, accM[nt]);
                accM[nt] = MFMA(ah, bl, accM[nt]);
                accM[nt] = MFMA(al, bh, accM[nt]);
                __builtin_amdgcn_s_setprio(0);
            }
        }

        stK(cur ^ 1);                            // next-tile scalars (nobody reads buf^1 this tile)
    }

    #pragma unroll
    for (int r = 0; r < 16; ++r) mu128p[r] = half_sum32(mu128p[r], half);
    float rno[16];
    #pragma unroll
    for (int r = 0; r < 16; ++r) {
        float p = 0.f;
        #pragma unroll
        for (int nt = 0; nt < 4; ++nt) p += accM[nt][r] * accM[nt][r];
        if (l31 == 0) p -= 2.f * accM[0][r] * accM[0][r];
        p = half_sum32(p, half);
        float negI = -(p + mu128p[r] * mu128p[r]);
        negI = fmaxf(negI, 1e-7f);
        rno[r] = 1.f / (SCf * sqrtf(negI));
    }
    #pragma unroll
    for (int nt = 0; nt < 4; ++nt)
        #pragma unroll
        for (int r = 0; r < 16; ++r) accM[nt][r] *= rno[r];
    #pragma unroll
    for (int r = 0; r < 16; ++r) mu128p[r] *= rno[r];

    __syncthreads();                             // done with KB/Pb; alias as MuA
    __bf16* MuA = (__bf16*)smem + w * (32 * 148);
    #pragma unroll
    for (int r = 0; r < 16; ++r) {
        const int qr = (r & 3) + 8 * (r >> 2) + 4 * half;
        #pragma unroll
        for (int nt = 0; nt < 4; ++nt)
            MuA[qr * 148 + nt * 32 + l31] = (__bf16)accM[nt][r];
        if (l31 == 0) MuA[qr * 148 + 128] = (__bf16)mu128p[r];
        if (l31 >= 1 && l31 <= 15) MuA[qr * 148 + 128 + l31] = (__bf16)0.f;
    }
    bf16x8 Ah[9];
    #pragma unroll
    for (int ks = 0; ks < 9; ++ks) Ah[ks] = ld_lds8(MuA + l31 * 148 + ks * 16 + half * 8);
    #pragma unroll
    for (int r = 0; r < 16; ++r) {
        const int qr = (r & 3) + 8 * (r >> 2) + 4 * half;
        #pragma unroll
        for (int nt = 0; nt < 4; ++nt) {
            float m = accM[nt][r];
            MuA[qr * 148 + nt * 32 + l31] = (__bf16)(m - (float)(__bf16)m);
        }
        if (l31 == 0) {
            float m = mu128p[r];
            MuA[qr * 148 + 128] = (__bf16)(m - (float)(__bf16)m);
        }
    }
    bf16x8 Al[9];
    #pragma unroll
    for (int ks = 0; ks < 9; ++ks) Al[ks] = ld_lds8(MuA + l31 * 148 + ks * 16 + half * 8);

    f32x16 accU[4] = {};
    __builtin_amdgcn_s_setprio(1);
    #pragma unroll
    for (int ks = 0; ks < 9; ++ks) {
        #pragma unroll
        for (int nt = 0; nt < 4; ++nt) {
            bf16x8 bh = *(const bf16x8*)(Woh + (size_t)(nt * 32 + l31) * 144 + ks * 16 + half * 8);
            bf16x8 bl = *(const bf16x8*)(Wol + (size_t)(nt * 32 + l31) * 144 + ks * 16 + half * 8);
            accU[nt] = MFMA(Ah[ks], bh, accU[nt]);
            accU[nt] = MFMA(Ah[ks], bl, accU[nt]);
            accU[nt] = MFMA(Al[ks], bh, accU[nt]);
        }
    }
    __builtin_amdgcn_s_setprio(0);

    float bov[4];
    #pragma unroll
    for (int nt = 0; nt < 4; ++nt) bov[nt] = bo[nt * 32 + l31];
    #pragma unroll
    for (int r = 0; r < 16; ++r) {
        float p = 0.f;
        #pragma unroll
        for (int nt = 0; nt < 4; ++nt) {
            float uv = accU[nt][r] + bov[nt];
            accU[nt][r] = uv;
            p += uv * uv;
        }
        float nn = half_sum32(p, half);
        float nu = fmaxf(sqrtf(nn), 1e-7f);
        float aa = SCf * nu;
        float cf = tanhf(aa) / aa;
        const int qr = (r & 3) + 8 * (r >> 2) + 4 * half;
        const size_t row = (size_t)(b * N_ + qb + w * 32 + qr);
        #pragma unroll
        for (int nt = 0; nt < 4; ++nt)
            Y[row * D_ + nt * 32 + l31] = accU[nt][r] * cf;
        if (l31 == 0) Y2[row] = nn * cf * cf;
    }
}

// ---------------- diagonal Gram blocks: G[b][c][i][k] = <y_i, y_k>, i,k in chunk c ----------------
__global__ __launch_bounds__(256) void k_gram(const float* __restrict__ Y,
                                              float* __restrict__ G) {
    const int c = blockIdx.x, b = blockIdx.y;
    const int t = threadIdx.x, w = t >> 6, l = t & 63;
    const int l31 = l & 31, half = l >> 5;
    const int rt = w >> 1, ct = w & 1;                 // 32x32 tile of the 64x64 block
    const size_t base = (size_t)(b * N_ + c * 64);
    const float* Ar = Y + (base + rt * 32 + l31) * D_;
    const float* Br = Y + (base + ct * 32 + l31) * D_;
    f32x16 acc = {};
    #pragma unroll
    for (int ks = 0; ks < 8; ++ks) {
        const int c0 = ks * 16 + half * 8;
        float4 a0 = *(const float4*)(Ar + c0);
        float4 a1 = *(const float4*)(Ar + c0 + 4);
        float4 b0 = *(const float4*)(Br + c0);
        float4 b1 = *(const float4*)(Br + c0 + 4);
        float av[8] = {a0.x, a0.y, a0.z, a0.w, a1.x, a1.y, a1.z, a1.w};
        float bv[8] = {b0.x, b0.y, b0.z, b0.w, b1.x, b1.y, b1.z, b1.w};
        bf16x8 ah, al, bh, bl;
        #pragma unroll
        for (int j = 0; j < 8; ++j) {
            __bf16 h = (__bf16)av[j]; ah[j] = h; al[j] = (__bf16)(av[j] - (float)h);
            __bf16 g = (__bf16)bv[j]; bh[j] = g; bl[j] = (__bf16)(bv[j] - (float)g);
        }
        acc = MFMA(ah, bh, acc);
        acc = MFMA(ah, bl, acc);
        acc = MFMA(al, bh, acc);
    }
    float* Gb = G + ((size_t)(b * 16 + c) << 12);
    #pragma unroll
    for (int r = 0; r < 16; ++r) {
        const int row = rt * 32 + (r & 3) + 8 * (r >> 2) + 4 * half;
        Gb[row * 64 + ct * 32 + l31] = acc[r];
    }
}

// ---------------- Mobius fold: Gram-scan, all per-step operands in REGISTERS ----------------
__global__ __launch_bounds__(64, 1) void k_pool(const float* __restrict__ Y,
                                                const float* __restrict__ Y2,
                                                const float* __restrict__ G,
                                                const int* __restrict__ mask,
                                                const int* __restrict__ mflag,
                                                const float* __restrict__ Wf,
                                                const float* __restrict__ bf_,
                                                float* __restrict__ out) {
    __shared__ float  prt[64][65];
    __shared__ double vb[D_];
    const int b = blockIdx.x, l = threadIdx.x;
    const int is8 = *mflag;

    int cl = 0;
    for (int i = l; i < N_; i += 64) cl += read_mask(mask, is8, b * N_ + i);
    const int cntT = (int)(wave_sum64((float)cl) + 0.5f);

    const float2* __restrict__ Yp = (const float2*)(Y + (size_t)b * N_ * D_) + l;   // lane column
    const float*  __restrict__ Gp = G + ((size_t)b << 16) + l;   // block c, row i: Gp[c*4096 + i*64]
    const float*  __restrict__ Pp = Y2 + b * N_;

    float  GA[64], GB[64];
    float  py2A, py2B;
    int    msA, msB;
    float2 yring[2][16];

    #pragma unroll
    for (int i = 0; i < 64; ++i) GA[i] = Gp[i * 64];
    py2A = Pp[l];
    msA  = read_mask(mask, is8, b * N_ + l);
    #pragma unroll
    for (int k = 0; k < 16; ++k) yring[0][k] = Yp[(size_t)k * 64];

    float U0 = 0.f, U1 = 0.f, g = 0.f, Dh = 1.f, P = 0.f;

    auto chunk = [&](int c, float (&Gc)[64], float (&Gn)[64],
                     float py2c, float& py2n, int msc, int& msn) {
        const int cn = (c < 15) ? c + 1 : 15;
        #pragma unroll
        for (int i = 0; i < 64; ++i) Gn[i] = Gp[cn * 4096 + i * 64];
        py2n = Pp[cn * 64 + l];
        msn  = read_mask(mask, is8, b * N_ + cn * 64 + l);

        #pragma unroll
        for (int q = 0; q < 4; ++q) {
            #pragma unroll
            for (int k = 0; k < 16; ++k) {
                int gs = c * 64 + (q + 1) * 16 + k;
                if (gs > N_ - 1) gs = N_ - 1;
                yring[(q + 1) & 1][k] = Yp[(size_t)gs * 64];
            }
            #pragma unroll
            for (int k = 0; k < 16; ++k) {
                const int ir = q * 16 + k;                      // compile-time lane index
                const float2 yv  = yring[q & 1][k];
                const float  Gv  = Gc[ir];
                const float  py2 = readlane_f(py2c, ir);
                const bool   m   = (__builtin_amdgcn_readlane(msc, ir) != 0);
                const float Dsq   = Dh * Dh;
                const float Bh    = fmaf(-0.1f, P, Dsq);
                const float Donep = Dh * fmaf(0.1f, py2, 1.f);
                const float tP    = (0.01f * py2) * P;
                const float puy  = readlane_f(g, ir);
                const float Ahat = fmaf(0.2f, puy, Donep);
                float dh = fmaf(Dh, fmaf(0.2f, puy, Dh), tP);
                dh = fmaxf(dh, 1e-12f * Dsq);
                const float Draw = m ? dh : Dh;
                const float Am   = m ? Ahat : 1.f;
                const float Bm   = m ? Bh   : 0.f;
                const float Pn   = fmaf(Am, fmaf(Am, P, (2.f * Bm) * puy), (Bm * Bm) * py2);
                if ((k & 3) == 3) {                 // exact 2^-e rescale every 4th step
                    const int e = ilogbf(Draw);
                    const float Aef = ldexpf(Am, -e);
                    const float Bef = ldexpf(Bm, -e);
                    Dh = ldexpf(Draw, -e);
                    P  = ldexpf(Pn, -2 * e);
                    g  = fmaf(Aef, g, Bef * Gv);
                    U0 = fmaf(Aef, U0, Bef * yv.x);
                    U1 = fmaf(Aef, U1, Bef * yv.y);
                } else {
                    Dh = Draw;
                    P  = Pn;
                    g  = fmaf(Am, g, Bm * Gv);
                    U0 = fmaf(Am, U0, Bm * yv.x);
                    U1 = fmaf(Am, U1, Bm * yv.y);
                }
            }
        }
        if (c < 15) {
            const int nb = (c + 1) * 64;
            #pragma unroll
            for (int k0 = 0; k0 < 64; k0 += 16) {
                float2 tmp[16];
                #pragma unroll
                for (int k = 0; k < 16; ++k) tmp[k] = Yp[(size_t)(nb + k0 + k) * 64];
                #pragma unroll
                for (int k = 0; k < 16; ++k)
                    prt[k0 + k][l] = fmaf(U0, tmp[k].x, U1 * tmp[k].y);
            }
            float s0 = 0.f, s1 = 0.f, s2 = 0.f, s3 = 0.f;
            #pragma unroll
            for (int p = 0; p < 64; p += 4) {
                s0 += prt[l][p];     s1 += prt[l][p + 1];
                s2 += prt[l][p + 2]; s3 += prt[l][p + 3];
            }
            g = (s0 + s1) + (s2 + s3);
        }
    };

    for (int cc = 0; cc < 8; ++cc) {
        chunk(2 * cc,     GA, GB, py2A, py2B, msA, msB);
        chunk(2 * cc + 1, GB, GA, py2B, py2A, msB, msA);
    }

    const double SCd = 0.31622776601683794;
    const double sD = 1.0 / (double)Dh;
    double a0 = sD * (double)U0, a1 = sD * (double)U1;
    double n2 = fmax((double)P * (sD * sD), 0.0);
    double n = sqrt(n2);
    double tt = SCd * n;
    tt = fmin(fmax(tt, 1e-7), 1.0 - 1e-6);
    int cm = cntT > 0 ? cntT : 1;
    float rf = (float)(1.0 / (double)cm);        // ref casts r to float32
    double r = (double)rf;
    double dv = fmax(SCd * n, 1e-7);
    double f = tanh(r * atanh(tt)) / dv;
    double p0 = a0 * f, p1 = a1 * f;
    double q2;
    if (cntT == 0) {                             // fallback: first token's y
        float2 y0v = *(const float2*)(Y + (size_t)(b * N_) * D_ + 2 * l);
        p0 = y0v.x; p1 = y0v.y;
        q2 = (double)Y2[b * N_];
    } else {
        q2 = f * f * n2;
    }
    double npn = fmax(sqrt(q2), 1e-7);
    double t2 = fmin(fmax(SCd * npn, 1e-7), 1.0 - 1e-6);
    double f2 = atanh(t2) / (SCd * npn);
    vb[2 * l]     = p0 * f2;
    vb[2 * l + 1] = p1 * f2;
    __syncthreads();

    if (l < NC_) {
        double o = (double)bf_[l];
        for (int d = 0; d < D_; ++d) o += vb[d] * (double)Wf[l * D_ + d];
        out[b * NC_ + l] = (float)o;
    }
}

extern "C" void kernel_launch(void* const* d_in, const int* in_sizes, int n_in,
                              void* d_out, int out_size, void* d_ws, size_t ws_size,
                              hipStream_t stream) {
    const int*   tok  = (const int*)d_in[0];
    const int*   mask = (const int*)d_in[1];
    const float* emb  = (const float*)d_in[2];
    const float* Wo   = (const float*)d_in[3];
    const float* bo   = (const float*)d_in[4];
    const float* Wf   = (const float*)d_in[5];
    const float* bf_  = (const float*)d_in[6];
    float* out = (float*)d_out;

    char* wsb = (char*)d_ws;
    __bf16* Xh   = (__bf16*)wsb;                              // 16,777,216 B (reused as Gram after k_attn)
    __bf16* Xl   = (__bf16*)(wsb + 16777216);                 // 16,777,216 B
    float*  X0g  = (float*)(wsb + 33554432);                  //    262,144 B
    float*  X128g= (float*)(wsb + 33816576);                  //    262,144 B
    __bf16* Woh  = (__bf16*)(wsb + 34078720);                 //     36,864 B
    __bf16* Wol  = (__bf16*)(wsb + 34115584);                 //     36,864 B
    float*  Y    = (float*)(wsb + 34152448);                  // 33,554,432 B
    float*  Y2   = (float*)(wsb + 67706880);                  //    262,144 B
    int*    flag = (int*)(wsb + 67969024);                    // total ~67.97 MB
    float*  Gram = (float*)wsb;                               // aliases Xh (dead after k_attn): 16.77 MB

    k_detect_mask<<<dim3(1), dim3(256), 0, stream>>>(mask, flag);
    k_prep_wo<<<dim3(72), dim3(256), 0, stream>>>(Wo, Woh, Wol);
    k_prep<<<dim3(B_ * N_ / 64), dim3(256), 0, stream>>>(tok, emb, Xh, Xl, X0g, X128g);
    k_attn<<<dim3(B_, N_ / QB), dim3(256), 51200, stream>>>(Xh, Xl, X0g, X128g, mask, flag,
                                                            Woh, Wol, bo, Y, Y2);
    k_gram<<<dim3(16, B_), dim3(256), 0, stream>>>(Y, Gram);
    k_pool<<<dim3(B_), dim3(64), 0, stream>>>(Y, Y2, Gram, mask, flag, Wf, bf_, out);
}

// Round 2
// 789.213 us; speedup vs baseline: 1.3548x; 1.3548x over previous
//
#include <hip/hip_runtime.h>
#include <math.h>

#define B_    64
#define N_    1024
#define D_    128
#define DP1   129
#define NC_   10
#define QB    128     // queries per block (4 waves x 32)
#define KT    32      // key tile
#define SCf   0.31622776601683794f
#define SCALE 0.08804509063256238f   // 1/sqrt(129)

typedef __bf16 bf16x8 __attribute__((ext_vector_type(8)));
typedef float  f32x16 __attribute__((ext_vector_type(16)));
typedef unsigned long long ull;

#define MFMA(a, b, c) __builtin_amdgcn_mfma_f32_32x32x16_bf16((a), (b), (c), 0, 0, 0)

static __device__ __forceinline__ float dpp_add_step(float f, int ctrl, int rmask) {
    if (ctrl == 0x111) { int t = __builtin_amdgcn_update_dpp(0, __builtin_bit_cast(int, f), 0x111, 0xf, 0xf, true); return f + __builtin_bit_cast(float, t); }
    if (ctrl == 0x112) { int t = __builtin_amdgcn_update_dpp(0, __builtin_bit_cast(int, f), 0x112, 0xf, 0xf, true); return f + __builtin_bit_cast(float, t); }
    if (ctrl == 0x114) { int t = __builtin_amdgcn_update_dpp(0, __builtin_bit_cast(int, f), 0x114, 0xf, 0xf, true); return f + __builtin_bit_cast(float, t); }
    if (ctrl == 0x118) { int t = __builtin_amdgcn_update_dpp(0, __builtin_bit_cast(int, f), 0x118, 0xf, 0xf, true); return f + __builtin_bit_cast(float, t); }
    if (ctrl == 0x142 && rmask == 0xa) { int t = __builtin_amdgcn_update_dpp(0, __builtin_bit_cast(int, f), 0x142, 0xa, 0xf, true); return f + __builtin_bit_cast(float, t); }
    { int t = __builtin_amdgcn_update_dpp(0, __builtin_bit_cast(int, f), 0x143, 0xc, 0xf, true); return f + __builtin_bit_cast(float, t); }
}

// full 64-lane sum, result broadcast to all lanes
static __device__ __forceinline__ float wave_sum64(float f) {
    f = dpp_add_step(f, 0x111, 0xf);
    f = dpp_add_step(f, 0x112, 0xf);
    f = dpp_add_step(f, 0x114, 0xf);
    f = dpp_add_step(f, 0x118, 0xf);
    f = dpp_add_step(f, 0x142, 0xa);
    f = dpp_add_step(f, 0x143, 0xc);
    return __builtin_bit_cast(float, __builtin_amdgcn_readlane(__builtin_bit_cast(int, f), 63));
}

// per-32-lane-half sum, each lane gets its half's total
static __device__ __forceinline__ float half_sum32(float f, int half) {
    f = dpp_add_step(f, 0x111, 0xf);
    f = dpp_add_step(f, 0x112, 0xf);
    f = dpp_add_step(f, 0x114, 0xf);
    f = dpp_add_step(f, 0x118, 0xf);
    f = dpp_add_step(f, 0x142, 0xa);
    float s0 = __builtin_bit_cast(float, __builtin_amdgcn_readlane(__builtin_bit_cast(int, f), 31));
    float s1 = __builtin_bit_cast(float, __builtin_amdgcn_readlane(__builtin_bit_cast(int, f), 63));
    return half ? s1 : s0;
}

static __device__ __forceinline__ float readlane_f(float v, int lane) {
    return __builtin_bit_cast(float, __builtin_amdgcn_readlane(__builtin_bit_cast(int, v), lane));
}

static __device__ __forceinline__ bf16x8 ld_lds8(const __bf16* p) {
    union { bf16x8 v; ull q[2]; } u;
    u.q[0] = *(const ull*)(p);
    u.q[1] = *(const ull*)(p + 4);
    return u.v;
}

// 16B-equivalent LDS read as 4 x b32 (only 4B alignment required; stride-34 rows)
static __device__ __forceinline__ bf16x8 ld_lds4x32(const __bf16* p) {
    union { bf16x8 v; unsigned int d[4]; } u;
    u.d[0] = *(const unsigned int*)(p);
    u.d[1] = *(const unsigned int*)(p + 2);
    u.d[2] = *(const unsigned int*)(p + 4);
    u.d[3] = *(const unsigned int*)(p + 6);
    return u.v;
}

// ---------------- mask dtype detection (int32 vs packed int8 bool) ----------------
__global__ __launch_bounds__(256) void k_detect_mask(const int* __restrict__ mask_w,
                                                     int* __restrict__ flag) {
    __shared__ int bad;
    if (threadIdx.x == 0) bad = 0;
    __syncthreads();
    int local = 0;
    for (int i = threadIdx.x; i < 16384; i += 256) {
        int v = mask_w[i];
        if (v != 0 && v != 1) local = 1;
    }
    if (local) atomicOr(&bad, 1);
    __syncthreads();
    if (threadIdx.x == 0) *flag = bad;   // 1 => data is packed int8 bools
}

static __device__ __forceinline__ int read_mask(const int* mw, int is_i8, int idx) {
    if (is_i8) return (int)((const unsigned char*)mw)[idx];
    return mw[idx];
}

// ---------------- Wo -> bf16 hi/lo, layout [o][144] (K padded 129->144 with zeros) ----------------
__global__ __launch_bounds__(256) void k_prep_wo(const float* __restrict__ Wo,
                                                 __bf16* __restrict__ Woh,
                                                 __bf16* __restrict__ Wol) {
    int idx = blockIdx.x * 256 + threadIdx.x;
    if (idx >= 128 * 144) return;
    int o = idx / 144, d = idx - o * 144;
    float v = (d < DP1) ? Wo[o * DP1 + d] : 0.f;
    __bf16 h = (__bf16)v;
    Woh[idx] = h;
    Wol[idx] = (__bf16)(v - (float)h);
}

// ---------------- embedding + Lorentz expmap0 -> bf16 hi/lo rows + comp0/comp128 f32 ----------------
__global__ __launch_bounds__(256) void k_prep(const int* __restrict__ tok,
                                              const float* __restrict__ emb,
                                              __bf16* __restrict__ Xh, __bf16* __restrict__ Xl,
                                              float* __restrict__ X0g, float* __restrict__ X128g) {
    __shared__ float Xf[64][132];
    const int t = threadIdx.x, w = t >> 6, l = t & 63;
    const int base = blockIdx.x * 64;
    for (int it = 0; it < 16; ++it) {
        const int tk = w * 16 + it;
        const int id = tok[base + tk];
        const float2 v = ((const float2*)(emb + (size_t)id * D_))[l];
        float s = wave_sum64(v.x * v.x + v.y * v.y);
        float nv = fmaxf(sqrtf(s), 1e-7f);
        float a = SCf * nv;
        float a2 = a * a;
        float shc, ch;
        if (a < 0.5f) {
            shc = 1.f + a2 * (1.f/6.f) * (1.f + a2 * (1.f/20.f) * (1.f + a2 * (1.f/42.f)));
            ch  = 1.f + a2 * 0.5f * (1.f + a2 * (1.f/12.f) * (1.f + a2 * (1.f/30.f)));
        } else {
            float ea = __expf(a), ei = 1.f / ea;
            ch = 0.5f * (ea + ei);
            shc = 0.5f * (ea - ei) / a;
        }
        Xf[tk][1 + 2 * l] = v.x * shc;
        Xf[tk][2 + 2 * l] = v.y * shc;
        if (l == 0) Xf[tk][0] = ch / SCf;
    }
    __syncthreads();
    const int tk2 = t >> 2, dg = (t & 3) * 32;
    for (int i = 0; i < 32; i += 8) {
        bf16x8 hv, lv;
        #pragma unroll
        for (int j = 0; j < 8; ++j) {
            float f = Xf[tk2][dg + i + j];
            __bf16 h = (__bf16)f;
            hv[j] = h;
            lv[j] = (__bf16)(f - (float)h);
        }
        *(bf16x8*)(Xh + (size_t)(base + tk2) * D_ + dg + i) = hv;
        *(bf16x8*)(Xl + (size_t)(base + tk2) * D_ + dg + i) = lv;
    }
    if (t < 64) {
        X0g[base + t]   = Xf[t][0];
        X128g[base + t] = Xf[t][D_];
    }
}

// ---------------- fused MFMA attention (r12) ----------------
// r10: grid x=batch -> XCD=b%8, per-XCD K working set 8x512KB=4MB=L2 (FETCH 154->35MB).
// r11 POST-MORTEM: global_load_lds staging -> FETCH 35MB->1.27GB, 838us. Direct-to-LDS loads
//   do NOT get the L2 panel reuse this mapping depends on. REVERTED to reg-staged ds_write.
// r12: (a) Pb stride 36->34 (reads via 4x b32, 4B-aligned; 17-dword rows, gcd(17,32)=1 ->
//   conflict-free) -> dynamic LDS 53760->51200 -> 3 blocks/CU (was 2); (b) launch_bounds(256,3);
//   (c) s_setprio(1) around MFMA clusters (T5).
__global__ __launch_bounds__(256, 3) void k_attn(
        const __bf16* __restrict__ Xh, const __bf16* __restrict__ Xl,
        const float* __restrict__ X0g, const float* __restrict__ X128g,
        const int* __restrict__ mask, const int* __restrict__ mflag,
        const __bf16* __restrict__ Woh, const __bf16* __restrict__ Wol,
        const float* __restrict__ bo,
        float* __restrict__ Y, float* __restrict__ Y2) {
    extern __shared__ char smem[];
    // KBUF[2]: hi 32x132 + lo 32x132 bf16 per buffer (8448 elems, 16896 B); two buffers 33792 B
    __bf16* KB = (__bf16*)smem;
    __bf16* Pb = (__bf16*)(smem + 33792);       // 17408 B (per-wave P hi/lo, rows 34-stride)
    __shared__ float K0s[2][KT];
    __shared__ float K128s[2][KT];
    __shared__ int   Ms[2][KT];

    const int b    = blockIdx.x;                // batch on x: XCD-local L2 reuse
    const int qb   = blockIdx.y * QB;
    const int t    = threadIdx.x;
    const int w    = t >> 6;
    const int l    = t & 63;
    const int l31  = l & 31;
    const int half = l >> 5;
    const int is8  = *mflag;

    // ---- Q fragments (A operand): A[m=lane&31][k=half*8+j], hi/lo, 8 k-steps over comps 0..127 ----
    const size_t qrow = (size_t)(b * N_ + qb + w * 32 + l31);
    bf16x8 qfh[8], qfl[8];
    #pragma unroll
    for (int ks = 0; ks < 8; ++ks) {
        qfh[ks] = *(const bf16x8*)(Xh + qrow * D_ + ks * 16 + half * 8);
        qfl[ks] = *(const bf16x8*)(Xl + qrow * D_ + ks * 16 + half * 8);
    }
    float q0[16], q128[16];
    #pragma unroll
    for (int r = 0; r < 16; ++r) {
        const int qr = (r & 3) + 8 * (r >> 2) + 4 * half;
        q0[r]   = X0g[b * N_ + qb + w * 32 + qr];
        q128[r] = X128g[b * N_ + qb + w * 32 + qr];
    }

    // ---- staging lambdas: global -> regs -> LDS (stride 132, b64 writes: 8B-aligned) ----
    const int skey = t >> 3, sck = t & 7;       // 32 keys x 8 chunks of 16 comps
    bf16x8 svh0, svh1, svl0, svl1;
    float  sK0 = 0.f, sK128 = 0.f;
    int    sM = 0;
    auto ldg_tile = [&](int kt) {
        const size_t kr = (size_t)(b * N_ + kt * KT + skey);
        svh0 = *(const bf16x8*)(Xh + kr * D_ + sck * 16);
        svh1 = *(const bf16x8*)(Xh + kr * D_ + sck * 16 + 8);
        svl0 = *(const bf16x8*)(Xl + kr * D_ + sck * 16);
        svl1 = *(const bf16x8*)(Xl + kr * D_ + sck * 16 + 8);
        if (t < KT) {
            sK0   = X0g[b * N_ + kt * KT + t];
            sK128 = X128g[b * N_ + kt * KT + t];
            sM    = read_mask(mask, is8, b * N_ + kt * KT + t);
        }
    };
    auto st_tile = [&](int buf) {
        __bf16* KH = KB + buf * 8448;
        __bf16* KL = KH + 4224;
        union { bf16x8 v; ull q[2]; } u;
        u.v = svh0; *(ull*)(KH + skey * 132 + sck * 16)      = u.q[0]; *(ull*)(KH + skey * 132 + sck * 16 + 4)  = u.q[1];
        u.v = svh1; *(ull*)(KH + skey * 132 + sck * 16 + 8)  = u.q[0]; *(ull*)(KH + skey * 132 + sck * 16 + 12) = u.q[1];
        u.v = svl0; *(ull*)(KL + skey * 132 + sck * 16)      = u.q[0]; *(ull*)(KL + skey * 132 + sck * 16 + 4)  = u.q[1];
        u.v = svl1; *(ull*)(KL + skey * 132 + sck * 16 + 8)  = u.q[0]; *(ull*)(KL + skey * 132 + sck * 16 + 12) = u.q[1];
        if (t < KT) { K0s[buf][t] = sK0; K128s[buf][t] = sK128; Ms[buf][t] = sM; }
    };

    f32x16 accM[4] = {};
    float  mu128p[16] = {};

    ldg_tile(0);
    st_tile(0);

    for (int kt = 0; kt < N_ / KT; ++kt) {
        __syncthreads();                         // buffer kt&1 fully staged by all threads
        const int cur = kt & 1;
        const int ktn = (kt < 31) ? kt + 1 : 31;
        ldg_tile(ktn);                           // global loads overlap this tile's compute

        const __bf16* KH = KB + cur * 8448;
        const __bf16* KL = KH + 4224;

        // ---- phase A: S = Q . K ----
        f32x16 accS = {};
        __builtin_amdgcn_s_setprio(1);
        #pragma unroll
        for (int ks = 0; ks < 8; ++ks) {
            bf16x8 bh = ld_lds8(KH + l31 * 132 + ks * 16 + half * 8);
            bf16x8 bl = ld_lds8(KL + l31 * 132 + ks * 16 + half * 8);
            accS = MFMA(qfh[ks], bh, accS);
            accS = MFMA(qfh[ks], bl, accS);
            accS = MFMA(qfl[ks], bh, accS);
        }
        __builtin_amdgcn_s_setprio(0);
        const float k0v = K0s[cur][l31], k128v = K128s[cur][l31];
        const int   mv  = Ms[cur][l31];
        #pragma unroll
        for (int r = 0; r < 16; ++r) {
            float sc = (2.f * q0[r] * k0v - accS[r] - q128[r] * k128v) * SCALE;
            float e  = mv ? __expf(sc) : 0.f;
            mu128p[r] += e * k128v;
            __bf16 eh = (__bf16)e;
            __bf16 el = (__bf16)(e - (float)eh);
            const int qr = (r & 3) + 8 * (r >> 2) + 4 * half;
            Pb[(w * 2 + 0) * 1088 + qr * 34 + l31] = eh;
            Pb[(w * 2 + 1) * 1088 + qr * 34 + l31] = el;
        }

        // ---- phase B: mu += P . X; B-fragments = columns of KH/KL (8x u16 each, lane=comp) ----
        #pragma unroll
        for (int ks = 0; ks < 2; ++ks) {
            bf16x8 ah = ld_lds4x32(Pb + (w * 2 + 0) * 1088 + l31 * 34 + ks * 16 + half * 8);
            bf16x8 al = ld_lds4x32(Pb + (w * 2 + 1) * 1088 + l31 * 34 + ks * 16 + half * 8);
            #pragma unroll
            for (int nt = 0; nt < 4; ++nt) {
                const int cmp = nt * 32 + l31;
                bf16x8 bh, bl;
                #pragma unroll
                for (int j = 0; j < 8; ++j) {
                    const int key = ks * 16 + half * 8 + j;
                    bh[j] = KH[key * 132 + cmp];
                    bl[j] = KL[key * 132 + cmp];
                }
                __builtin_amdgcn_s_setprio(1);
                accM[nt] = MFMA(ah, bh, accM[nt]);
                accM[nt] = MFMA(ah, bl, accM[nt]);
                accM[nt] = MFMA(al, bh, accM[nt]);
                __builtin_amdgcn_s_setprio(0);
            }
        }

        st_tile(cur ^ 1);                        // write next buffer (nobody reads it this tile)
    }

    #pragma unroll
    for (int r = 0; r < 16; ++r) mu128p[r] = half_sum32(mu128p[r], half);
    float rno[16];
    #pragma unroll
    for (int r = 0; r < 16; ++r) {
        float p = 0.f;
        #pragma unroll
        for (int nt = 0; nt < 4; ++nt) p += accM[nt][r] * accM[nt][r];
        if (l31 == 0) p -= 2.f * accM[0][r] * accM[0][r];
        p = half_sum32(p, half);
        float negI = -(p + mu128p[r] * mu128p[r]);
        negI = fmaxf(negI, 1e-7f);
        rno[r] = 1.f / (SCf * sqrtf(negI));
    }
    #pragma unroll
    for (int nt = 0; nt < 4; ++nt)
        #pragma unroll
        for (int r = 0; r < 16; ++r) accM[nt][r] *= rno[r];
    #pragma unroll
    for (int r = 0; r < 16; ++r) mu128p[r] *= rno[r];

    __syncthreads();                             // done with KB/Pb; alias as MuA
    __bf16* MuA = (__bf16*)smem + w * (32 * 148);
    #pragma unroll
    for (int r = 0; r < 16; ++r) {
        const int qr = (r & 3) + 8 * (r >> 2) + 4 * half;
        #pragma unroll
        for (int nt = 0; nt < 4; ++nt)
            MuA[qr * 148 + nt * 32 + l31] = (__bf16)accM[nt][r];
        if (l31 == 0) MuA[qr * 148 + 128] = (__bf16)mu128p[r];
        if (l31 >= 1 && l31 <= 15) MuA[qr * 148 + 128 + l31] = (__bf16)0.f;
    }
    bf16x8 Ah[9];
    #pragma unroll
    for (int ks = 0; ks < 9; ++ks) Ah[ks] = ld_lds8(MuA + l31 * 148 + ks * 16 + half * 8);
    #pragma unroll
    for (int r = 0; r < 16; ++r) {
        const int qr = (r & 3) + 8 * (r >> 2) + 4 * half;
        #pragma unroll
        for (int nt = 0; nt < 4; ++nt) {
            float m = accM[nt][r];
            MuA[qr * 148 + nt * 32 + l31] = (__bf16)(m - (float)(__bf16)m);
        }
        if (l31 == 0) {
            float m = mu128p[r];
            MuA[qr * 148 + 128] = (__bf16)(m - (float)(__bf16)m);
        }
    }
    bf16x8 Al[9];
    #pragma unroll
    for (int ks = 0; ks < 9; ++ks) Al[ks] = ld_lds8(MuA + l31 * 148 + ks * 16 + half * 8);

    f32x16 accU[4] = {};
    __builtin_amdgcn_s_setprio(1);
    #pragma unroll
    for (int ks = 0; ks < 9; ++ks) {
        #pragma unroll
        for (int nt = 0; nt < 4; ++nt) {
            bf16x8 bh = *(const bf16x8*)(Woh + (size_t)(nt * 32 + l31) * 144 + ks * 16 + half * 8);
            bf16x8 bl = *(const bf16x8*)(Wol + (size_t)(nt * 32 + l31) * 144 + ks * 16 + half * 8);
            accU[nt] = MFMA(Ah[ks], bh, accU[nt]);
            accU[nt] = MFMA(Ah[ks], bl, accU[nt]);
            accU[nt] = MFMA(Al[ks], bh, accU[nt]);
        }
    }
    __builtin_amdgcn_s_setprio(0);

    float bov[4];
    #pragma unroll
    for (int nt = 0; nt < 4; ++nt) bov[nt] = bo[nt * 32 + l31];
    #pragma unroll
    for (int r = 0; r < 16; ++r) {
        float p = 0.f;
        #pragma unroll
        for (int nt = 0; nt < 4; ++nt) {
            float uv = accU[nt][r] + bov[nt];
            accU[nt][r] = uv;
            p += uv * uv;
        }
        float nn = half_sum32(p, half);
        float nu = fmaxf(sqrtf(nn), 1e-7f);
        float aa = SCf * nu;
        float cf = tanhf(aa) / aa;
        const int qr = (r & 3) + 8 * (r >> 2) + 4 * half;
        const size_t row = (size_t)(b * N_ + qb + w * 32 + qr);
        #pragma unroll
        for (int nt = 0; nt < 4; ++nt)
            Y[row * D_ + nt * 32 + l31] = accU[nt][r] * cf;
        if (l31 == 0) Y2[row] = nn * cf * cf;
    }
}

// ---------------- diagonal Gram blocks: G[b][c][i][k] = <y_i, y_k>, i,k in chunk c ----------------
__global__ __launch_bounds__(256) void k_gram(const float* __restrict__ Y,
                                              float* __restrict__ G) {
    const int c = blockIdx.x, b = blockIdx.y;
    const int t = threadIdx.x, w = t >> 6, l = t & 63;
    const int l31 = l & 31, half = l >> 5;
    const int rt = w >> 1, ct = w & 1;                 // 32x32 tile of the 64x64 block
    const size_t base = (size_t)(b * N_ + c * 64);
    const float* Ar = Y + (base + rt * 32 + l31) * D_;
    const float* Br = Y + (base + ct * 32 + l31) * D_;
    f32x16 acc = {};
    #pragma unroll
    for (int ks = 0; ks < 8; ++ks) {
        const int c0 = ks * 16 + half * 8;
        float4 a0 = *(const float4*)(Ar + c0);
        float4 a1 = *(const float4*)(Ar + c0 + 4);
        float4 b0 = *(const float4*)(Br + c0);
        float4 b1 = *(const float4*)(Br + c0 + 4);
        float av[8] = {a0.x, a0.y, a0.z, a0.w, a1.x, a1.y, a1.z, a1.w};
        float bv[8] = {b0.x, b0.y, b0.z, b0.w, b1.x, b1.y, b1.z, b1.w};
        bf16x8 ah, al, bh, bl;
        #pragma unroll
        for (int j = 0; j < 8; ++j) {
            __bf16 h = (__bf16)av[j]; ah[j] = h; al[j] = (__bf16)(av[j] - (float)h);
            __bf16 g = (__bf16)bv[j]; bh[j] = g; bl[j] = (__bf16)(bv[j] - (float)g);
        }
        acc = MFMA(ah, bh, acc);
        acc = MFMA(ah, bl, acc);
        acc = MFMA(al, bh, acc);
    }
    float* Gb = G + ((size_t)(b * 16 + c) << 12);
    #pragma unroll
    for (int r = 0; r < 16; ++r) {
        const int row = rt * 32 + (r & 3) + 8 * (r >> 2) + 4 * half;
        Gb[row * 64 + ct * 32 + l31] = acc[r];
    }
}

// ---------------- Mobius fold: Gram-scan, all per-step operands in REGISTERS ----------------
__global__ __launch_bounds__(64, 1) void k_pool(const float* __restrict__ Y,
                                                const float* __restrict__ Y2,
                                                const float* __restrict__ G,
                                                const int* __restrict__ mask,
                                                const int* __restrict__ mflag,
                                                const float* __restrict__ Wf,
                                                const float* __restrict__ bf_,
                                                float* __restrict__ out) {
    __shared__ float  prt[64][65];
    __shared__ double vb[D_];
    const int b = blockIdx.x, l = threadIdx.x;
    const int is8 = *mflag;

    int cl = 0;
    for (int i = l; i < N_; i += 64) cl += read_mask(mask, is8, b * N_ + i);
    const int cntT = (int)(wave_sum64((float)cl) + 0.5f);

    const float2* __restrict__ Yp = (const float2*)(Y + (size_t)b * N_ * D_) + l;   // lane column
    const float*  __restrict__ Gp = G + ((size_t)b << 16) + l;   // block c, row i: Gp[c*4096 + i*64]
    const float*  __restrict__ Pp = Y2 + b * N_;

    float  GA[64], GB[64];
    float  py2A, py2B;
    int    msA, msB;
    float2 yring[2][16];

    #pragma unroll
    for (int i = 0; i < 64; ++i) GA[i] = Gp[i * 64];
    py2A = Pp[l];
    msA  = read_mask(mask, is8, b * N_ + l);
    #pragma unroll
    for (int k = 0; k < 16; ++k) yring[0][k] = Yp[(size_t)k * 64];

    float U0 = 0.f, U1 = 0.f, g = 0.f, Dh = 1.f, P = 0.f;

    auto chunk = [&](int c, float (&Gc)[64], float (&Gn)[64],
                     float py2c, float& py2n, int msc, int& msn) {
        const int cn = (c < 15) ? c + 1 : 15;
        #pragma unroll
        for (int i = 0; i < 64; ++i) Gn[i] = Gp[cn * 4096 + i * 64];
        py2n = Pp[cn * 64 + l];
        msn  = read_mask(mask, is8, b * N_ + cn * 64 + l);

        #pragma unroll
        for (int q = 0; q < 4; ++q) {
            #pragma unroll
            for (int k = 0; k < 16; ++k) {
                int gs = c * 64 + (q + 1) * 16 + k;
                if (gs > N_ - 1) gs = N_ - 1;
                yring[(q + 1) & 1][k] = Yp[(size_t)gs * 64];
            }
            #pragma unroll
            for (int k = 0; k < 16; ++k) {
                const int ir = q * 16 + k;                      // compile-time lane index
                const float2 yv  = yring[q & 1][k];
                const float  Gv  = Gc[ir];
                const float  py2 = readlane_f(py2c, ir);
                const bool   m   = (__builtin_amdgcn_readlane(msc, ir) != 0);
                const float Dsq   = Dh * Dh;
                const float Bh    = fmaf(-0.1f, P, Dsq);
                const float Donep = Dh * fmaf(0.1f, py2, 1.f);
                const float tP    = (0.01f * py2) * P;
                const float puy  = readlane_f(g, ir);
                const float Ahat = fmaf(0.2f, puy, Donep);
                float dh = fmaf(Dh, fmaf(0.2f, puy, Dh), tP);
                dh = fmaxf(dh, 1e-12f * Dsq);
                const float Draw = m ? dh : Dh;
                const float Am   = m ? Ahat : 1.f;
                const float Bm   = m ? Bh   : 0.f;
                const float Pn   = fmaf(Am, fmaf(Am, P, (2.f * Bm) * puy), (Bm * Bm) * py2);
                if ((k & 3) == 3) {                 // exact 2^-e rescale every 4th step
                    const int e = ilogbf(Draw);
                    const float Aef = ldexpf(Am, -e);
                    const float Bef = ldexpf(Bm, -e);
                    Dh = ldexpf(Draw, -e);
                    P  = ldexpf(Pn, -2 * e);
                    g  = fmaf(Aef, g, Bef * Gv);
                    U0 = fmaf(Aef, U0, Bef * yv.x);
                    U1 = fmaf(Aef, U1, Bef * yv.y);
                } else {
                    Dh = Draw;
                    P  = Pn;
                    g  = fmaf(Am, g, Bm * Gv);
                    U0 = fmaf(Am, U0, Bm * yv.x);
                    U1 = fmaf(Am, U1, Bm * yv.y);
                }
            }
        }
        if (c < 15) {
            const int nb = (c + 1) * 64;
            #pragma unroll
            for (int k0 = 0; k0 < 64; k0 += 16) {
                float2 tmp[16];
                #pragma unroll
                for (int k = 0; k < 16; ++k) tmp[k] = Yp[(size_t)(nb + k0 + k) * 64];
                #pragma unroll
                for (int k = 0; k < 16; ++k)
                    prt[k0 + k][l] = fmaf(U0, tmp[k].x, U1 * tmp[k].y);
            }
            float s0 = 0.f, s1 = 0.f, s2 = 0.f, s3 = 0.f;
            #pragma unroll
            for (int p = 0; p < 64; p += 4) {
                s0 += prt[l][p];     s1 += prt[l][p + 1];
                s2 += prt[l][p + 2]; s3 += prt[l][p + 3];
            }
            g = (s0 + s1) + (s2 + s3);
        }
    };

    for (int cc = 0; cc < 8; ++cc) {
        chunk(2 * cc,     GA, GB, py2A, py2B, msA, msB);
        chunk(2 * cc + 1, GB, GA, py2B, py2A, msB, msA);
    }

    const double SCd = 0.31622776601683794;
    const double sD = 1.0 / (double)Dh;
    double a0 = sD * (double)U0, a1 = sD * (double)U1;
    double n2 = fmax((double)P * (sD * sD), 0.0);
    double n = sqrt(n2);
    double tt = SCd * n;
    tt = fmin(fmax(tt, 1e-7), 1.0 - 1e-6);
    int cm = cntT > 0 ? cntT : 1;
    float rf = (float)(1.0 / (double)cm);        // ref casts r to float32
    double r = (double)rf;
    double dv = fmax(SCd * n, 1e-7);
    double f = tanh(r * atanh(tt)) / dv;
    double p0 = a0 * f, p1 = a1 * f;
    double q2;
    if (cntT == 0) {                             // fallback: first token's y
        float2 y0v = *(const float2*)(Y + (size_t)(b * N_) * D_ + 2 * l);
        p0 = y0v.x; p1 = y0v.y;
        q2 = (double)Y2[b * N_];
    } else {
        q2 = f * f * n2;
    }
    double npn = fmax(sqrt(q2), 1e-7);
    double t2 = fmin(fmax(SCd * npn, 1e-7), 1.0 - 1e-6);
    double f2 = atanh(t2) / (SCd * npn);
    vb[2 * l]     = p0 * f2;
    vb[2 * l + 1] = p1 * f2;
    __syncthreads();

    if (l < NC_) {
        double o = (double)bf_[l];
        for (int d = 0; d < D_; ++d) o += vb[d] * (double)Wf[l * D_ + d];
        out[b * NC_ + l] = (float)o;
    }
}

extern "C" void kernel_launch(void* const* d_in, const int* in_sizes, int n_in,
                              void* d_out, int out_size, void* d_ws, size_t ws_size,
                              hipStream_t stream) {
    const int*   tok  = (const int*)d_in[0];
    const int*   mask = (const int*)d_in[1];
    const float* emb  = (const float*)d_in[2];
    const float* Wo   = (const float*)d_in[3];
    const float* bo   = (const float*)d_in[4];
    const float* Wf   = (const float*)d_in[5];
    const float* bf_  = (const float*)d_in[6];
    float* out = (float*)d_out;

    char* wsb = (char*)d_ws;
    __bf16* Xh   = (__bf16*)wsb;                              // 16,777,216 B (reused as Gram after k_attn)
    __bf16* Xl   = (__bf16*)(wsb + 16777216);                 // 16,777,216 B
    float*  X0g  = (float*)(wsb + 33554432);                  //    262,144 B
    float*  X128g= (float*)(wsb + 33816576);                  //    262,144 B
    __bf16* Woh  = (__bf16*)(wsb + 34078720);                 //     36,864 B
    __bf16* Wol  = (__bf16*)(wsb + 34115584);                 //     36,864 B
    float*  Y    = (float*)(wsb + 34152448);                  // 33,554,432 B
    float*  Y2   = (float*)(wsb + 67706880);                  //    262,144 B
    int*    flag = (int*)(wsb + 67969024);                    // total ~67.97 MB
    float*  Gram = (float*)wsb;                               // aliases Xh (dead after k_attn): 16.77 MB

    k_detect_mask<<<dim3(1), dim3(256), 0, stream>>>(mask, flag);
    k_prep_wo<<<dim3(72), dim3(256), 0, stream>>>(Wo, Woh, Wol);
    k_prep<<<dim3(B_ * N_ / 64), dim3(256), 0, stream>>>(tok, emb, Xh, Xl, X0g, X128g);
    k_attn<<<dim3(B_, N_ / QB), dim3(256), 51200, stream>>>(Xh, Xl, X0g, X128g, mask, flag,
                                                            Woh, Wol, bo, Y, Y2);
    k_gram<<<dim3(16, B_), dim3(256), 0, stream>>>(Y, Gram);
    k_pool<<<dim3(B_), dim3(64), 0, stream>>>(Y, Y2, Gram, mask, flag, Wf, bf_, out);
}

// Round 3
// 488.769 us; speedup vs baseline: 2.1875x; 1.6147x over previous
//
#include <hip/hip_runtime.h>
#include <math.h>

#define B_    64
#define N_    1024
#define D_    128
#define DP1   129
#define NC_   10
#define QB    128     // queries per block (4 waves x 32)
#define KT    32      // key tile
#define SCf   0.31622776601683794f
#define SCALE 0.08804509063256238f   // 1/sqrt(129)

typedef __bf16 bf16x8 __attribute__((ext_vector_type(8)));
typedef float  f32x16 __attribute__((ext_vector_type(16)));
typedef unsigned long long ull;

#define MFMA(a, b, c) __builtin_amdgcn_mfma_f32_32x32x16_bf16((a), (b), (c), 0, 0, 0)

static __device__ __forceinline__ float dpp_add_step(float f, int ctrl, int rmask) {
    if (ctrl == 0x111) { int t = __builtin_amdgcn_update_dpp(0, __builtin_bit_cast(int, f), 0x111, 0xf, 0xf, true); return f + __builtin_bit_cast(float, t); }
    if (ctrl == 0x112) { int t = __builtin_amdgcn_update_dpp(0, __builtin_bit_cast(int, f), 0x112, 0xf, 0xf, true); return f + __builtin_bit_cast(float, t); }
    if (ctrl == 0x114) { int t = __builtin_amdgcn_update_dpp(0, __builtin_bit_cast(int, f), 0x114, 0xf, 0xf, true); return f + __builtin_bit_cast(float, t); }
    if (ctrl == 0x118) { int t = __builtin_amdgcn_update_dpp(0, __builtin_bit_cast(int, f), 0x118, 0xf, 0xf, true); return f + __builtin_bit_cast(float, t); }
    if (ctrl == 0x142 && rmask == 0xa) { int t = __builtin_amdgcn_update_dpp(0, __builtin_bit_cast(int, f), 0x142, 0xa, 0xf, true); return f + __builtin_bit_cast(float, t); }
    { int t = __builtin_amdgcn_update_dpp(0, __builtin_bit_cast(int, f), 0x143, 0xc, 0xf, true); return f + __builtin_bit_cast(float, t); }
}

// full 64-lane sum, result broadcast to all lanes
static __device__ __forceinline__ float wave_sum64(float f) {
    f = dpp_add_step(f, 0x111, 0xf);
    f = dpp_add_step(f, 0x112, 0xf);
    f = dpp_add_step(f, 0x114, 0xf);
    f = dpp_add_step(f, 0x118, 0xf);
    f = dpp_add_step(f, 0x142, 0xa);
    f = dpp_add_step(f, 0x143, 0xc);
    return __builtin_bit_cast(float, __builtin_amdgcn_readlane(__builtin_bit_cast(int, f), 63));
}

// per-32-lane-half sum, each lane gets its half's total
static __device__ __forceinline__ float half_sum32(float f, int half) {
    f = dpp_add_step(f, 0x111, 0xf);
    f = dpp_add_step(f, 0x112, 0xf);
    f = dpp_add_step(f, 0x114, 0xf);
    f = dpp_add_step(f, 0x118, 0xf);
    f = dpp_add_step(f, 0x142, 0xa);
    float s0 = __builtin_bit_cast(float, __builtin_amdgcn_readlane(__builtin_bit_cast(int, f), 31));
    float s1 = __builtin_bit_cast(float, __builtin_amdgcn_readlane(__builtin_bit_cast(int, f), 63));
    return half ? s1 : s0;
}

static __device__ __forceinline__ float readlane_f(float v, int lane) {
    return __builtin_bit_cast(float, __builtin_amdgcn_readlane(__builtin_bit_cast(int, v), lane));
}

static __device__ __forceinline__ bf16x8 ld_lds8(const __bf16* p) {
    union { bf16x8 v; ull q[2]; } u;
    u.q[0] = *(const ull*)(p);
    u.q[1] = *(const ull*)(p + 4);
    return u.v;
}

// 16B-equivalent LDS read as 4 x b32 (only 4B alignment required; stride-34 rows)
static __device__ __forceinline__ bf16x8 ld_lds4x32(const __bf16* p) {
    union { bf16x8 v; unsigned int d[4]; } u;
    u.d[0] = *(const unsigned int*)(p);
    u.d[1] = *(const unsigned int*)(p + 2);
    u.d[2] = *(const unsigned int*)(p + 4);
    u.d[3] = *(const unsigned int*)(p + 6);
    return u.v;
}

// ---------------- mask dtype detection (int32 vs packed int8 bool) ----------------
__global__ __launch_bounds__(256) void k_detect_mask(const int* __restrict__ mask_w,
                                                     int* __restrict__ flag) {
    __shared__ int bad;
    if (threadIdx.x == 0) bad = 0;
    __syncthreads();
    int local = 0;
    for (int i = threadIdx.x; i < 16384; i += 256) {
        int v = mask_w[i];
        if (v != 0 && v != 1) local = 1;
    }
    if (local) atomicOr(&bad, 1);
    __syncthreads();
    if (threadIdx.x == 0) *flag = bad;   // 1 => data is packed int8 bools
}

static __device__ __forceinline__ int read_mask(const int* mw, int is_i8, int idx) {
    if (is_i8) return (int)((const unsigned char*)mw)[idx];
    return mw[idx];
}

// ---------------- Wo -> bf16 hi/lo, layout [o][144] (K padded 129->144 with zeros) ----------------
__global__ __launch_bounds__(256) void k_prep_wo(const float* __restrict__ Wo,
                                                 __bf16* __restrict__ Woh,
                                                 __bf16* __restrict__ Wol) {
    int idx = blockIdx.x * 256 + threadIdx.x;
    if (idx >= 128 * 144) return;
    int o = idx / 144, d = idx - o * 144;
    float v = (d < DP1) ? Wo[o * DP1 + d] : 0.f;
    __bf16 h = (__bf16)v;
    Woh[idx] = h;
    Wol[idx] = (__bf16)(v - (float)h);
}

// ---------------- embedding + Lorentz expmap0 -> bf16 hi/lo rows + comp0/comp128 f32 ----------------
__global__ __launch_bounds__(256) void k_prep(const int* __restrict__ tok,
                                              const float* __restrict__ emb,
                                              __bf16* __restrict__ Xh, __bf16* __restrict__ Xl,
                                              float* __restrict__ X0g, float* __restrict__ X128g) {
    __shared__ float Xf[64][132];
    const int t = threadIdx.x, w = t >> 6, l = t & 63;
    const int base = blockIdx.x * 64;
    for (int it = 0; it < 16; ++it) {
        const int tk = w * 16 + it;
        const int id = tok[base + tk];
        const float2 v = ((const float2*)(emb + (size_t)id * D_))[l];
        float s = wave_sum64(v.x * v.x + v.y * v.y);
        float nv = fmaxf(sqrtf(s), 1e-7f);
        float a = SCf * nv;
        float a2 = a * a;
        float shc, ch;
        if (a < 0.5f) {
            shc = 1.f + a2 * (1.f/6.f) * (1.f + a2 * (1.f/20.f) * (1.f + a2 * (1.f/42.f)));
            ch  = 1.f + a2 * 0.5f * (1.f + a2 * (1.f/12.f) * (1.f + a2 * (1.f/30.f)));
        } else {
            float ea = __expf(a), ei = 1.f / ea;
            ch = 0.5f * (ea + ei);
            shc = 0.5f * (ea - ei) / a;
        }
        Xf[tk][1 + 2 * l] = v.x * shc;
        Xf[tk][2 + 2 * l] = v.y * shc;
        if (l == 0) Xf[tk][0] = ch / SCf;
    }
    __syncthreads();
    const int tk2 = t >> 2, dg = (t & 3) * 32;
    for (int i = 0; i < 32; i += 8) {
        bf16x8 hv, lv;
        #pragma unroll
        for (int j = 0; j < 8; ++j) {
            float f = Xf[tk2][dg + i + j];
            __bf16 h = (__bf16)f;
            hv[j] = h;
            lv[j] = (__bf16)(f - (float)h);
        }
        *(bf16x8*)(Xh + (size_t)(base + tk2) * D_ + dg + i) = hv;
        *(bf16x8*)(Xl + (size_t)(base + tk2) * D_ + dg + i) = lv;
    }
    if (t < 64) {
        X0g[base + t]   = Xf[t][0];
        X128g[base + t] = Xf[t][D_];
    }
}

// ---------------- fused MFMA attention (r13) ----------------
// r10: grid x=batch -> XCD=b%8, per-XCD K working set 8x512KB=4MB=L2 (FETCH 154->35MB).
// r11/r12 POST-MORTEM: __launch_bounds__(256,3) capped VGPR 128->84 -> compiler REMATERIALIZED
//   the 64-VGPR Q-fragment array from GLOBAL inside the K-loop -> FETCH 35MB->0.76-1.27GB,
//   HBM-bound at ~490-840us. The r0 occupancy limiter was never VGPR (128 allows 4 waves/SIMD)
//   but LDS (54.5KB > 160K/3).
// r13: keep launch_bounds(256,2) (r0 codegen, VGPR 128, Q resident) and shrink LDS instead:
//   Pb stride 36->34 (reads via 4x b32, 4B-aligned; 17-dword rows, gcd(17,32)=1 conflict-free)
//   -> dynamic LDS 53760->51200 (+768 static) -> HW schedules 3 blocks/CU on its own.
//   Plus s_setprio(1) around MFMA clusters (T5).
__global__ __launch_bounds__(256, 2) void k_attn(
        const __bf16* __restrict__ Xh, const __bf16* __restrict__ Xl,
        const float* __restrict__ X0g, const float* __restrict__ X128g,
        const int* __restrict__ mask, const int* __restrict__ mflag,
        const __bf16* __restrict__ Woh, const __bf16* __restrict__ Wol,
        const float* __restrict__ bo,
        float* __restrict__ Y, float* __restrict__ Y2) {
    extern __shared__ char smem[];
    // KBUF[2]: hi 32x132 + lo 32x132 bf16 per buffer (8448 elems, 16896 B); two buffers 33792 B
    __bf16* KB = (__bf16*)smem;
    __bf16* Pb = (__bf16*)(smem + 33792);       // 17408 B (per-wave P hi/lo, rows 34-stride)
    __shared__ float K0s[2][KT];
    __shared__ float K128s[2][KT];
    __shared__ int   Ms[2][KT];

    const int b    = blockIdx.x;                // batch on x: XCD-local L2 reuse
    const int qb   = blockIdx.y * QB;
    const int t    = threadIdx.x;
    const int w    = t >> 6;
    const int l    = t & 63;
    const int l31  = l & 31;
    const int half = l >> 5;
    const int is8  = *mflag;

    // ---- Q fragments (A operand): A[m=lane&31][k=half*8+j], hi/lo, 8 k-steps over comps 0..127 ----
    const size_t qrow = (size_t)(b * N_ + qb + w * 32 + l31);
    bf16x8 qfh[8], qfl[8];
    #pragma unroll
    for (int ks = 0; ks < 8; ++ks) {
        qfh[ks] = *(const bf16x8*)(Xh + qrow * D_ + ks * 16 + half * 8);
        qfl[ks] = *(const bf16x8*)(Xl + qrow * D_ + ks * 16 + half * 8);
    }
    float q0[16], q128[16];
    #pragma unroll
    for (int r = 0; r < 16; ++r) {
        const int qr = (r & 3) + 8 * (r >> 2) + 4 * half;
        q0[r]   = X0g[b * N_ + qb + w * 32 + qr];
        q128[r] = X128g[b * N_ + qb + w * 32 + qr];
    }

    // ---- staging lambdas: global -> regs -> LDS (stride 132, b64 writes: 8B-aligned) ----
    const int skey = t >> 3, sck = t & 7;       // 32 keys x 8 chunks of 16 comps
    bf16x8 svh0, svh1, svl0, svl1;
    float  sK0 = 0.f, sK128 = 0.f;
    int    sM = 0;
    auto ldg_tile = [&](int kt) {
        const size_t kr = (size_t)(b * N_ + kt * KT + skey);
        svh0 = *(const bf16x8*)(Xh + kr * D_ + sck * 16);
        svh1 = *(const bf16x8*)(Xh + kr * D_ + sck * 16 + 8);
        svl0 = *(const bf16x8*)(Xl + kr * D_ + sck * 16);
        svl1 = *(const bf16x8*)(Xl + kr * D_ + sck * 16 + 8);
        if (t < KT) {
            sK0   = X0g[b * N_ + kt * KT + t];
            sK128 = X128g[b * N_ + kt * KT + t];
            sM    = read_mask(mask, is8, b * N_ + kt * KT + t);
        }
    };
    auto st_tile = [&](int buf) {
        __bf16* KH = KB + buf * 8448;
        __bf16* KL = KH + 4224;
        union { bf16x8 v; ull q[2]; } u;
        u.v = svh0; *(ull*)(KH + skey * 132 + sck * 16)      = u.q[0]; *(ull*)(KH + skey * 132 + sck * 16 + 4)  = u.q[1];
        u.v = svh1; *(ull*)(KH + skey * 132 + sck * 16 + 8)  = u.q[0]; *(ull*)(KH + skey * 132 + sck * 16 + 12) = u.q[1];
        u.v = svl0; *(ull*)(KL + skey * 132 + sck * 16)      = u.q[0]; *(ull*)(KL + skey * 132 + sck * 16 + 4)  = u.q[1];
        u.v = svl1; *(ull*)(KL + skey * 132 + sck * 16 + 8)  = u.q[0]; *(ull*)(KL + skey * 132 + sck * 16 + 12) = u.q[1];
        if (t < KT) { K0s[buf][t] = sK0; K128s[buf][t] = sK128; Ms[buf][t] = sM; }
    };

    f32x16 accM[4] = {};
    float  mu128p[16] = {};

    ldg_tile(0);
    st_tile(0);

    for (int kt = 0; kt < N_ / KT; ++kt) {
        __syncthreads();                         // buffer kt&1 fully staged by all threads
        const int cur = kt & 1;
        const int ktn = (kt < 31) ? kt + 1 : 31;
        ldg_tile(ktn);                           // global loads overlap this tile's compute

        const __bf16* KH = KB + cur * 8448;
        const __bf16* KL = KH + 4224;

        // ---- phase A: S = Q . K ----
        f32x16 accS = {};
        __builtin_amdgcn_s_setprio(1);
        #pragma unroll
        for (int ks = 0; ks < 8; ++ks) {
            bf16x8 bh = ld_lds8(KH + l31 * 132 + ks * 16 + half * 8);
            bf16x8 bl = ld_lds8(KL + l31 * 132 + ks * 16 + half * 8);
            accS = MFMA(qfh[ks], bh, accS);
            accS = MFMA(qfh[ks], bl, accS);
            accS = MFMA(qfl[ks], bh, accS);
        }
        __builtin_amdgcn_s_setprio(0);
        const float k0v = K0s[cur][l31], k128v = K128s[cur][l31];
        const int   mv  = Ms[cur][l31];
        #pragma unroll
        for (int r = 0; r < 16; ++r) {
            float sc = (2.f * q0[r] * k0v - accS[r] - q128[r] * k128v) * SCALE;
            float e  = mv ? __expf(sc) : 0.f;
            mu128p[r] += e * k128v;
            __bf16 eh = (__bf16)e;
            __bf16 el = (__bf16)(e - (float)eh);
            const int qr = (r & 3) + 8 * (r >> 2) + 4 * half;
            Pb[(w * 2 + 0) * 1088 + qr * 34 + l31] = eh;
            Pb[(w * 2 + 1) * 1088 + qr * 34 + l31] = el;
        }

        // ---- phase B: mu += P . X; B-fragments = columns of KH/KL (8x u16 each, lane=comp) ----
        #pragma unroll
        for (int ks = 0; ks < 2; ++ks) {
            bf16x8 ah = ld_lds4x32(Pb + (w * 2 + 0) * 1088 + l31 * 34 + ks * 16 + half * 8);
            bf16x8 al = ld_lds4x32(Pb + (w * 2 + 1) * 1088 + l31 * 34 + ks * 16 + half * 8);
            #pragma unroll
            for (int nt = 0; nt < 4; ++nt) {
                const int cmp = nt * 32 + l31;
                bf16x8 bh, bl;
                #pragma unroll
                for (int j = 0; j < 8; ++j) {
                    const int key = ks * 16 + half * 8 + j;
                    bh[j] = KH[key * 132 + cmp];
                    bl[j] = KL[key * 132 + cmp];
                }
                __builtin_amdgcn_s_setprio(1);
                accM[nt] = MFMA(ah, bh, accM[nt]);
                accM[nt] = MFMA(ah, bl, accM[nt]);
                accM[nt] = MFMA(al, bh, accM[nt]);
                __builtin_amdgcn_s_setprio(0);
            }
        }

        st_tile(cur ^ 1);                        // write next buffer (nobody reads it this tile)
    }

    #pragma unroll
    for (int r = 0; r < 16; ++r) mu128p[r] = half_sum32(mu128p[r], half);
    float rno[16];
    #pragma unroll
    for (int r = 0; r < 16; ++r) {
        float p = 0.f;
        #pragma unroll
        for (int nt = 0; nt < 4; ++nt) p += accM[nt][r] * accM[nt][r];
        if (l31 == 0) p -= 2.f * accM[0][r] * accM[0][r];
        p = half_sum32(p, half);
        float negI = -(p + mu128p[r] * mu128p[r]);
        negI = fmaxf(negI, 1e-7f);
        rno[r] = 1.f / (SCf * sqrtf(negI));
    }
    #pragma unroll
    for (int nt = 0; nt < 4; ++nt)
        #pragma unroll
        for (int r = 0; r < 16; ++r) accM[nt][r] *= rno[r];
    #pragma unroll
    for (int r = 0; r < 16; ++r) mu128p[r] *= rno[r];

    __syncthreads();                             // done with KB/Pb; alias as MuA
    __bf16* MuA = (__bf16*)smem + w * (32 * 148);
    #pragma unroll
    for (int r = 0; r < 16; ++r) {
        const int qr = (r & 3) + 8 * (r >> 2) + 4 * half;
        #pragma unroll
        for (int nt = 0; nt < 4; ++nt)
            MuA[qr * 148 + nt * 32 + l31] = (__bf16)accM[nt][r];
        if (l31 == 0) MuA[qr * 148 + 128] = (__bf16)mu128p[r];
        if (l31 >= 1 && l31 <= 15) MuA[qr * 148 + 128 + l31] = (__bf16)0.f;
    }
    bf16x8 Ah[9];
    #pragma unroll
    for (int ks = 0; ks < 9; ++ks) Ah[ks] = ld_lds8(MuA + l31 * 148 + ks * 16 + half * 8);
    #pragma unroll
    for (int r = 0; r < 16; ++r) {
        const int qr = (r & 3) + 8 * (r >> 2) + 4 * half;
        #pragma unroll
        for (int nt = 0; nt < 4; ++nt) {
            float m = accM[nt][r];
            MuA[qr * 148 + nt * 32 + l31] = (__bf16)(m - (float)(__bf16)m);
        }
        if (l31 == 0) {
            float m = mu128p[r];
            MuA[qr * 148 + 128] = (__bf16)(m - (float)(__bf16)m);
        }
    }
    bf16x8 Al[9];
    #pragma unroll
    for (int ks = 0; ks < 9; ++ks) Al[ks] = ld_lds8(MuA + l31 * 148 + ks * 16 + half * 8);

    f32x16 accU[4] = {};
    __builtin_amdgcn_s_setprio(1);
    #pragma unroll
    for (int ks = 0; ks < 9; ++ks) {
        #pragma unroll
        for (int nt = 0; nt < 4; ++nt) {
            bf16x8 bh = *(const bf16x8*)(Woh + (size_t)(nt * 32 + l31) * 144 + ks * 16 + half * 8);
            bf16x8 bl = *(const bf16x8*)(Wol + (size_t)(nt * 32 + l31) * 144 + ks * 16 + half * 8);
            accU[nt] = MFMA(Ah[ks], bh, accU[nt]);
            accU[nt] = MFMA(Ah[ks], bl, accU[nt]);
            accU[nt] = MFMA(Al[ks], bh, accU[nt]);
        }
    }
    __builtin_amdgcn_s_setprio(0);

    float bov[4];
    #pragma unroll
    for (int nt = 0; nt < 4; ++nt) bov[nt] = bo[nt * 32 + l31];
    #pragma unroll
    for (int r = 0; r < 16; ++r) {
        float p = 0.f;
        #pragma unroll
        for (int nt = 0; nt < 4; ++nt) {
            float uv = accU[nt][r] + bov[nt];
            accU[nt][r] = uv;
            p += uv * uv;
        }
        float nn = half_sum32(p, half);
        float nu = fmaxf(sqrtf(nn), 1e-7f);
        float aa = SCf * nu;
        float cf = tanhf(aa) / aa;
        const int qr = (r & 3) + 8 * (r >> 2) + 4 * half;
        const size_t row = (size_t)(b * N_ + qb + w * 32 + qr);
        #pragma unroll
        for (int nt = 0; nt < 4; ++nt)
            Y[row * D_ + nt * 32 + l31] = accU[nt][r] * cf;
        if (l31 == 0) Y2[row] = nn * cf * cf;
    }
}

// ---------------- diagonal Gram blocks: G[b][c][i][k] = <y_i, y_k>, i,k in chunk c ----------------
__global__ __launch_bounds__(256) void k_gram(const float* __restrict__ Y,
                                              float* __restrict__ G) {
    const int c = blockIdx.x, b = blockIdx.y;
    const int t = threadIdx.x, w = t >> 6, l = t & 63;
    const int l31 = l & 31, half = l >> 5;
    const int rt = w >> 1, ct = w & 1;                 // 32x32 tile of the 64x64 block
    const size_t base = (size_t)(b * N_ + c * 64);
    const float* Ar = Y + (base + rt * 32 + l31) * D_;
    const float* Br = Y + (base + ct * 32 + l31) * D_;
    f32x16 acc = {};
    #pragma unroll
    for (int ks = 0; ks < 8; ++ks) {
        const int c0 = ks * 16 + half * 8;
        float4 a0 = *(const float4*)(Ar + c0);
        float4 a1 = *(const float4*)(Ar + c0 + 4);
        float4 b0 = *(const float4*)(Br + c0);
        float4 b1 = *(const float4*)(Br + c0 + 4);
        float av[8] = {a0.x, a0.y, a0.z, a0.w, a1.x, a1.y, a1.z, a1.w};
        float bv[8] = {b0.x, b0.y, b0.z, b0.w, b1.x, b1.y, b1.z, b1.w};
        bf16x8 ah, al, bh, bl;
        #pragma unroll
        for (int j = 0; j < 8; ++j) {
            __bf16 h = (__bf16)av[j]; ah[j] = h; al[j] = (__bf16)(av[j] - (float)h);
            __bf16 g = (__bf16)bv[j]; bh[j] = g; bl[j] = (__bf16)(bv[j] - (float)g);
        }
        acc = MFMA(ah, bh, acc);
        acc = MFMA(ah, bl, acc);
        acc = MFMA(al, bh, acc);
    }
    float* Gb = G + ((size_t)(b * 16 + c) << 12);
    #pragma unroll
    for (int r = 0; r < 16; ++r) {
        const int row = rt * 32 + (r & 3) + 8 * (r >> 2) + 4 * half;
        Gb[row * 64 + ct * 32 + l31] = acc[r];
    }
}

// ---------------- Mobius fold: Gram-scan, all per-step operands in REGISTERS ----------------
__global__ __launch_bounds__(64, 1) void k_pool(const float* __restrict__ Y,
                                                const float* __restrict__ Y2,
                                                const float* __restrict__ G,
                                                const int* __restrict__ mask,
                                                const int* __restrict__ mflag,
                                                const float* __restrict__ Wf,
                                                const float* __restrict__ bf_,
                                                float* __restrict__ out) {
    __shared__ float  prt[64][65];
    __shared__ double vb[D_];
    const int b = blockIdx.x, l = threadIdx.x;
    const int is8 = *mflag;

    int cl = 0;
    for (int i = l; i < N_; i += 64) cl += read_mask(mask, is8, b * N_ + i);
    const int cntT = (int)(wave_sum64((float)cl) + 0.5f);

    const float2* __restrict__ Yp = (const float2*)(Y + (size_t)b * N_ * D_) + l;   // lane column
    const float*  __restrict__ Gp = G + ((size_t)b << 16) + l;   // block c, row i: Gp[c*4096 + i*64]
    const float*  __restrict__ Pp = Y2 + b * N_;

    float  GA[64], GB[64];
    float  py2A, py2B;
    int    msA, msB;
    float2 yring[2][16];

    #pragma unroll
    for (int i = 0; i < 64; ++i) GA[i] = Gp[i * 64];
    py2A = Pp[l];
    msA  = read_mask(mask, is8, b * N_ + l);
    #pragma unroll
    for (int k = 0; k < 16; ++k) yring[0][k] = Yp[(size_t)k * 64];

    float U0 = 0.f, U1 = 0.f, g = 0.f, Dh = 1.f, P = 0.f;

    auto chunk = [&](int c, float (&Gc)[64], float (&Gn)[64],
                     float py2c, float& py2n, int msc, int& msn) {
        const int cn = (c < 15) ? c + 1 : 15;
        #pragma unroll
        for (int i = 0; i < 64; ++i) Gn[i] = Gp[cn * 4096 + i * 64];
        py2n = Pp[cn * 64 + l];
        msn  = read_mask(mask, is8, b * N_ + cn * 64 + l);

        #pragma unroll
        for (int q = 0; q < 4; ++q) {
            #pragma unroll
            for (int k = 0; k < 16; ++k) {
                int gs = c * 64 + (q + 1) * 16 + k;
                if (gs > N_ - 1) gs = N_ - 1;
                yring[(q + 1) & 1][k] = Yp[(size_t)gs * 64];
            }
            #pragma unroll
            for (int k = 0; k < 16; ++k) {
                const int ir = q * 16 + k;                      // compile-time lane index
                const float2 yv  = yring[q & 1][k];
                const float  Gv  = Gc[ir];
                const float  py2 = readlane_f(py2c, ir);
                const bool   m   = (__builtin_amdgcn_readlane(msc, ir) != 0);
                const float Dsq   = Dh * Dh;
                const float Bh    = fmaf(-0.1f, P, Dsq);
                const float Donep = Dh * fmaf(0.1f, py2, 1.f);
                const float tP    = (0.01f * py2) * P;
                const float puy  = readlane_f(g, ir);
                const float Ahat = fmaf(0.2f, puy, Donep);
                float dh = fmaf(Dh, fmaf(0.2f, puy, Dh), tP);
                dh = fmaxf(dh, 1e-12f * Dsq);
                const float Draw = m ? dh : Dh;
                const float Am   = m ? Ahat : 1.f;
                const float Bm   = m ? Bh   : 0.f;
                const float Pn   = fmaf(Am, fmaf(Am, P, (2.f * Bm) * puy), (Bm * Bm) * py2);
                if ((k & 3) == 3) {                 // exact 2^-e rescale every 4th step
                    const int e = ilogbf(Draw);
                    const float Aef = ldexpf(Am, -e);
                    const float Bef = ldexpf(Bm, -e);
                    Dh = ldexpf(Draw, -e);
                    P  = ldexpf(Pn, -2 * e);
                    g  = fmaf(Aef, g, Bef * Gv);
                    U0 = fmaf(Aef, U0, Bef * yv.x);
                    U1 = fmaf(Aef, U1, Bef * yv.y);
                } else {
                    Dh = Draw;
                    P  = Pn;
                    g  = fmaf(Am, g, Bm * Gv);
                    U0 = fmaf(Am, U0, Bm * yv.x);
                    U1 = fmaf(Am, U1, Bm * yv.y);
                }
            }
        }
        if (c < 15) {
            const int nb = (c + 1) * 64;
            #pragma unroll
            for (int k0 = 0; k0 < 64; k0 += 16) {
                float2 tmp[16];
                #pragma unroll
                for (int k = 0; k < 16; ++k) tmp[k] = Yp[(size_t)(nb + k0 + k) * 64];
                #pragma unroll
                for (int k = 0; k < 16; ++k)
                    prt[k0 + k][l] = fmaf(U0, tmp[k].x, U1 * tmp[k].y);
            }
            float s0 = 0.f, s1 = 0.f, s2 = 0.f, s3 = 0.f;
            #pragma unroll
            for (int p = 0; p < 64; p += 4) {
                s0 += prt[l][p];     s1 += prt[l][p + 1];
                s2 += prt[l][p + 2]; s3 += prt[l][p + 3];
            }
            g = (s0 + s1) + (s2 + s3);
        }
    };

    for (int cc = 0; cc < 8; ++cc) {
        chunk(2 * cc,     GA, GB, py2A, py2B, msA, msB);
        chunk(2 * cc + 1, GB, GA, py2B, py2A, msB, msA);
    }

    const double SCd = 0.31622776601683794;
    const double sD = 1.0 / (double)Dh;
    double a0 = sD * (double)U0, a1 = sD * (double)U1;
    double n2 = fmax((double)P * (sD * sD), 0.0);
    double n = sqrt(n2);
    double tt = SCd * n;
    tt = fmin(fmax(tt, 1e-7), 1.0 - 1e-6);
    int cm = cntT > 0 ? cntT : 1;
    float rf = (float)(1.0 / (double)cm);        // ref casts r to float32
    double r = (double)rf;
    double dv = fmax(SCd * n, 1e-7);
    double f = tanh(r * atanh(tt)) / dv;
    double p0 = a0 * f, p1 = a1 * f;
    double q2;
    if (cntT == 0) {                             // fallback: first token's y
        float2 y0v = *(const float2*)(Y + (size_t)(b * N_) * D_ + 2 * l);
        p0 = y0v.x; p1 = y0v.y;
        q2 = (double)Y2[b * N_];
    } else {
        q2 = f * f * n2;
    }
    double npn = fmax(sqrt(q2), 1e-7);
    double t2 = fmin(fmax(SCd * npn, 1e-7), 1.0 - 1e-6);
    double f2 = atanh(t2) / (SCd * npn);
    vb[2 * l]     = p0 * f2;
    vb[2 * l + 1] = p1 * f2;
    __syncthreads();

    if (l < NC_) {
        double o = (double)bf_[l];
        for (int d = 0; d < D_; ++d) o += vb[d] * (double)Wf[l * D_ + d];
        out[b * NC_ + l] = (float)o;
    }
}

extern "C" void kernel_launch(void* const* d_in, const int* in_sizes, int n_in,
                              void* d_out, int out_size, void* d_ws, size_t ws_size,
                              hipStream_t stream) {
    const int*   tok  = (const int*)d_in[0];
    const int*   mask = (const int*)d_in[1];
    const float* emb  = (const float*)d_in[2];
    const float* Wo   = (const float*)d_in[3];
    const float* bo   = (const float*)d_in[4];
    const float* Wf   = (const float*)d_in[5];
    const float* bf_  = (const float*)d_in[6];
    float* out = (float*)d_out;

    char* wsb = (char*)d_ws;
    __bf16* Xh   = (__bf16*)wsb;                              // 16,777,216 B (reused as Gram after k_attn)
    __bf16* Xl   = (__bf16*)(wsb + 16777216);                 // 16,777,216 B
    float*  X0g  = (float*)(wsb + 33554432);                  //    262,144 B
    float*  X128g= (float*)(wsb + 33816576);                  //    262,144 B
    __bf16* Woh  = (__bf16*)(wsb + 34078720);                 //     36,864 B
    __bf16* Wol  = (__bf16*)(wsb + 34115584);                 //     36,864 B
    float*  Y    = (float*)(wsb + 34152448);                  // 33,554,432 B
    float*  Y2   = (float*)(wsb + 67706880);                  //    262,144 B
    int*    flag = (int*)(wsb + 67969024);                    // total ~67.97 MB
    float*  Gram = (float*)wsb;                               // aliases Xh (dead after k_attn): 16.77 MB

    k_detect_mask<<<dim3(1), dim3(256), 0, stream>>>(mask, flag);
    k_prep_wo<<<dim3(72), dim3(256), 0, stream>>>(Wo, Woh, Wol);
    k_prep<<<dim3(B_ * N_ / 64), dim3(256), 0, stream>>>(tok, emb, Xh, Xl, X0g, X128g);
    k_attn<<<dim3(B_, N_ / QB), dim3(256), 51200, stream>>>(Xh, Xl, X0g, X128g, mask, flag,
                                                            Woh, Wol, bo, Y, Y2);
    k_gram<<<dim3(16, B_), dim3(256), 0, stream>>>(Y, Gram);
    k_pool<<<dim3(B_), dim3(64), 0, stream>>>(Y, Y2, Gram, mask, flag, Wf, bf_, out);
}

// Round 4
// 440.192 us; speedup vs baseline: 2.4289x; 1.1104x over previous
//
#include <hip/hip_runtime.h>
#include <math.h>

#define B_    64
#define N_    1024
#define D_    128
#define DP1   129
#define NC_   10
#define QB    128     // queries per block (4 waves x 32)
#define KT    32      // key tile
#define SCf   0.31622776601683794f
#define SCALE 0.08804509063256238f   // 1/sqrt(129)

typedef __bf16 bf16x8 __attribute__((ext_vector_type(8)));
typedef float  f32x16 __attribute__((ext_vector_type(16)));
typedef unsigned long long ull;

#define MFMA(a, b, c) __builtin_amdgcn_mfma_f32_32x32x16_bf16((a), (b), (c), 0, 0, 0)

static __device__ __forceinline__ float dpp_add_step(float f, int ctrl, int rmask) {
    if (ctrl == 0x111) { int t = __builtin_amdgcn_update_dpp(0, __builtin_bit_cast(int, f), 0x111, 0xf, 0xf, true); return f + __builtin_bit_cast(float, t); }
    if (ctrl == 0x112) { int t = __builtin_amdgcn_update_dpp(0, __builtin_bit_cast(int, f), 0x112, 0xf, 0xf, true); return f + __builtin_bit_cast(float, t); }
    if (ctrl == 0x114) { int t = __builtin_amdgcn_update_dpp(0, __builtin_bit_cast(int, f), 0x114, 0xf, 0xf, true); return f + __builtin_bit_cast(float, t); }
    if (ctrl == 0x118) { int t = __builtin_amdgcn_update_dpp(0, __builtin_bit_cast(int, f), 0x118, 0xf, 0xf, true); return f + __builtin_bit_cast(float, t); }
    if (ctrl == 0x142 && rmask == 0xa) { int t = __builtin_amdgcn_update_dpp(0, __builtin_bit_cast(int, f), 0x142, 0xa, 0xf, true); return f + __builtin_bit_cast(float, t); }
    { int t = __builtin_amdgcn_update_dpp(0, __builtin_bit_cast(int, f), 0x143, 0xc, 0xf, true); return f + __builtin_bit_cast(float, t); }
}

// full 64-lane sum, result broadcast to all lanes
static __device__ __forceinline__ float wave_sum64(float f) {
    f = dpp_add_step(f, 0x111, 0xf);
    f = dpp_add_step(f, 0x112, 0xf);
    f = dpp_add_step(f, 0x114, 0xf);
    f = dpp_add_step(f, 0x118, 0xf);
    f = dpp_add_step(f, 0x142, 0xa);
    f = dpp_add_step(f, 0x143, 0xc);
    return __builtin_bit_cast(float, __builtin_amdgcn_readlane(__builtin_bit_cast(int, f), 63));
}

// per-32-lane-half sum, each lane gets its half's total
static __device__ __forceinline__ float half_sum32(float f, int half) {
    f = dpp_add_step(f, 0x111, 0xf);
    f = dpp_add_step(f, 0x112, 0xf);
    f = dpp_add_step(f, 0x114, 0xf);
    f = dpp_add_step(f, 0x118, 0xf);
    f = dpp_add_step(f, 0x142, 0xa);
    float s0 = __builtin_bit_cast(float, __builtin_amdgcn_readlane(__builtin_bit_cast(int, f), 31));
    float s1 = __builtin_bit_cast(float, __builtin_amdgcn_readlane(__builtin_bit_cast(int, f), 63));
    return half ? s1 : s0;
}

static __device__ __forceinline__ float readlane_f(float v, int lane) {
    return __builtin_bit_cast(float, __builtin_amdgcn_readlane(__builtin_bit_cast(int, v), lane));
}

static __device__ __forceinline__ bf16x8 ld_lds8(const __bf16* p) {
    union { bf16x8 v; ull q[2]; } u;
    u.q[0] = *(const ull*)(p);
    u.q[1] = *(const ull*)(p + 4);
    return u.v;
}

// ---------------- mask dtype detection (int32 vs packed int8 bool) ----------------
__global__ __launch_bounds__(256) void k_detect_mask(const int* __restrict__ mask_w,
                                                     int* __restrict__ flag) {
    __shared__ int bad;
    if (threadIdx.x == 0) bad = 0;
    __syncthreads();
    int local = 0;
    for (int i = threadIdx.x; i < 16384; i += 256) {
        int v = mask_w[i];
        if (v != 0 && v != 1) local = 1;
    }
    if (local) atomicOr(&bad, 1);
    __syncthreads();
    if (threadIdx.x == 0) *flag = bad;   // 1 => data is packed int8 bools
}

static __device__ __forceinline__ int read_mask(const int* mw, int is_i8, int idx) {
    if (is_i8) return (int)((const unsigned char*)mw)[idx];
    return mw[idx];
}

// ---------------- Wo -> bf16 hi/lo, layout [o][144] (K padded 129->144 with zeros) ----------------
__global__ __launch_bounds__(256) void k_prep_wo(const float* __restrict__ Wo,
                                                 __bf16* __restrict__ Woh,
                                                 __bf16* __restrict__ Wol) {
    int idx = blockIdx.x * 256 + threadIdx.x;
    if (idx >= 128 * 144) return;
    int o = idx / 144, d = idx - o * 144;
    float v = (d < DP1) ? Wo[o * DP1 + d] : 0.f;
    __bf16 h = (__bf16)v;
    Woh[idx] = h;
    Wol[idx] = (__bf16)(v - (float)h);
}

// ---------------- embedding + Lorentz expmap0 -> bf16 hi/lo rows + comp0/comp128 f32 ----------------
__global__ __launch_bounds__(256) void k_prep(const int* __restrict__ tok,
                                              const float* __restrict__ emb,
                                              __bf16* __restrict__ Xh, __bf16* __restrict__ Xl,
                                              float* __restrict__ X0g, float* __restrict__ X128g) {
    __shared__ float Xf[64][132];
    const int t = threadIdx.x, w = t >> 6, l = t & 63;
    const int base = blockIdx.x * 64;
    for (int it = 0; it < 16; ++it) {
        const int tk = w * 16 + it;
        const int id = tok[base + tk];
        const float2 v = ((const float2*)(emb + (size_t)id * D_))[l];
        float s = wave_sum64(v.x * v.x + v.y * v.y);
        float nv = fmaxf(sqrtf(s), 1e-7f);
        float a = SCf * nv;
        float a2 = a * a;
        float shc, ch;
        if (a < 0.5f) {
            shc = 1.f + a2 * (1.f/6.f) * (1.f + a2 * (1.f/20.f) * (1.f + a2 * (1.f/42.f)));
            ch  = 1.f + a2 * 0.5f * (1.f + a2 * (1.f/12.f) * (1.f + a2 * (1.f/30.f)));
        } else {
            float ea = __expf(a), ei = 1.f / ea;
            ch = 0.5f * (ea + ei);
            shc = 0.5f * (ea - ei) / a;
        }
        Xf[tk][1 + 2 * l] = v.x * shc;
        Xf[tk][2 + 2 * l] = v.y * shc;
        if (l == 0) Xf[tk][0] = ch / SCf;
    }
    __syncthreads();
    const int tk2 = t >> 2, dg = (t & 3) * 32;
    for (int i = 0; i < 32; i += 8) {
        bf16x8 hv, lv;
        #pragma unroll
        for (int j = 0; j < 8; ++j) {
            float f = Xf[tk2][dg + i + j];
            __bf16 h = (__bf16)f;
            hv[j] = h;
            lv[j] = (__bf16)(f - (float)h);
        }
        *(bf16x8*)(Xh + (size_t)(base + tk2) * D_ + dg + i) = hv;
        *(bf16x8*)(Xl + (size_t)(base + tk2) * D_ + dg + i) = lv;
    }
    if (t < 64) {
        X0g[base + t]   = Xf[t][0];
        X128g[base + t] = Xf[t][D_];
    }
}

// ---------------- fused MFMA attention (r14) ----------------
// r10: grid x=batch -> XCD=b%8, per-XCD K working set 8x512KB=4MB=L2 (FETCH 154->35MB).
// r11/r12 POST-MORTEM: launch_bounds(256,3) capped VGPR 128->84 -> compiler REMATERIALIZED
//   Q fragments from GLOBAL inside the K-loop -> FETCH 0.76-1.27GB, HBM-bound.
// r13 POST-MORTEM: grid is 512 blocks = exactly 2/CU -> 3rd block can never materialize;
//   LDS diet was pointless. 203us vs r0's 170us: s_setprio flapping (16 toggles/tile) in a
//   4-wave BARRIER-LOCKSTEP structure delays staging waves (matches m190: setprio negative
//   on lockstep GEMM). REMOVED all setprio; reverted Pb to r0 exact (stride 36, b64 reads).
// r14: accS was a 24-deep dependent MFMA chain (C-in = prev result) with only 2 waves/SIMD
//   of TLP to hide dep latency. Split into 3 independent 8-deep chains (hh/hl/lh), summed in
//   f32 at the end. +32 VGPR (128->~160), harmless: occupancy is grid-capped at 2 waves/SIMD
//   and launch_bounds(256,2) budget is 256 VGPR.
__global__ __launch_bounds__(256, 2) void k_attn(
        const __bf16* __restrict__ Xh, const __bf16* __restrict__ Xl,
        const float* __restrict__ X0g, const float* __restrict__ X128g,
        const int* __restrict__ mask, const int* __restrict__ mflag,
        const __bf16* __restrict__ Woh, const __bf16* __restrict__ Wol,
        const float* __restrict__ bo,
        float* __restrict__ Y, float* __restrict__ Y2) {
    extern __shared__ char smem[];
    // KBUF[2]: hi 32x132 + lo 32x132 bf16 per buffer (8448 elems, 16896 B); two buffers 33792 B
    __bf16* KB = (__bf16*)smem;
    __bf16* Pb = (__bf16*)(smem + 33792);       // 18432 B (per-wave P hi/lo, rows 36-stride)
    __shared__ float K0s[2][KT];
    __shared__ float K128s[2][KT];
    __shared__ int   Ms[2][KT];

    const int b    = blockIdx.x;                // batch on x: XCD-local L2 reuse
    const int qb   = blockIdx.y * QB;
    const int t    = threadIdx.x;
    const int w    = t >> 6;
    const int l    = t & 63;
    const int l31  = l & 31;
    const int half = l >> 5;
    const int is8  = *mflag;

    // ---- Q fragments (A operand): A[m=lane&31][k=half*8+j], hi/lo, 8 k-steps over comps 0..127 ----
    const size_t qrow = (size_t)(b * N_ + qb + w * 32 + l31);
    bf16x8 qfh[8], qfl[8];
    #pragma unroll
    for (int ks = 0; ks < 8; ++ks) {
        qfh[ks] = *(const bf16x8*)(Xh + qrow * D_ + ks * 16 + half * 8);
        qfl[ks] = *(const bf16x8*)(Xl + qrow * D_ + ks * 16 + half * 8);
    }
    float q0[16], q128[16];
    #pragma unroll
    for (int r = 0; r < 16; ++r) {
        const int qr = (r & 3) + 8 * (r >> 2) + 4 * half;
        q0[r]   = X0g[b * N_ + qb + w * 32 + qr];
        q128[r] = X128g[b * N_ + qb + w * 32 + qr];
    }

    // ---- staging lambdas: global -> regs -> LDS (stride 132, b64 writes: 8B-aligned) ----
    const int skey = t >> 3, sck = t & 7;       // 32 keys x 8 chunks of 16 comps
    bf16x8 svh0, svh1, svl0, svl1;
    float  sK0 = 0.f, sK128 = 0.f;
    int    sM = 0;
    auto ldg_tile = [&](int kt) {
        const size_t kr = (size_t)(b * N_ + kt * KT + skey);
        svh0 = *(const bf16x8*)(Xh + kr * D_ + sck * 16);
        svh1 = *(const bf16x8*)(Xh + kr * D_ + sck * 16 + 8);
        svl0 = *(const bf16x8*)(Xl + kr * D_ + sck * 16);
        svl1 = *(const bf16x8*)(Xl + kr * D_ + sck * 16 + 8);
        if (t < KT) {
            sK0   = X0g[b * N_ + kt * KT + t];
            sK128 = X128g[b * N_ + kt * KT + t];
            sM    = read_mask(mask, is8, b * N_ + kt * KT + t);
        }
    };
    auto st_tile = [&](int buf) {
        __bf16* KH = KB + buf * 8448;
        __bf16* KL = KH + 4224;
        union { bf16x8 v; ull q[2]; } u;
        u.v = svh0; *(ull*)(KH + skey * 132 + sck * 16)      = u.q[0]; *(ull*)(KH + skey * 132 + sck * 16 + 4)  = u.q[1];
        u.v = svh1; *(ull*)(KH + skey * 132 + sck * 16 + 8)  = u.q[0]; *(ull*)(KH + skey * 132 + sck * 16 + 12) = u.q[1];
        u.v = svl0; *(ull*)(KL + skey * 132 + sck * 16)      = u.q[0]; *(ull*)(KL + skey * 132 + sck * 16 + 4)  = u.q[1];
        u.v = svl1; *(ull*)(KL + skey * 132 + sck * 16 + 8)  = u.q[0]; *(ull*)(KL + skey * 132 + sck * 16 + 12) = u.q[1];
        if (t < KT) { K0s[buf][t] = sK0; K128s[buf][t] = sK128; Ms[buf][t] = sM; }
    };

    f32x16 accM[4] = {};
    float  mu128p[16] = {};

    ldg_tile(0);
    st_tile(0);

    for (int kt = 0; kt < N_ / KT; ++kt) {
        __syncthreads();                         // buffer kt&1 fully staged by all threads
        const int cur = kt & 1;
        const int ktn = (kt < 31) ? kt + 1 : 31;
        ldg_tile(ktn);                           // global loads overlap this tile's compute

        const __bf16* KH = KB + cur * 8448;
        const __bf16* KL = KH + 4224;

        // ---- phase A: S = Q . K  (3 independent MFMA chains: hh / hl / lh) ----
        f32x16 sA = {}, sB = {}, sC = {};
        #pragma unroll
        for (int ks = 0; ks < 8; ++ks) {
            bf16x8 bh = ld_lds8(KH + l31 * 132 + ks * 16 + half * 8);
            bf16x8 bl = ld_lds8(KL + l31 * 132 + ks * 16 + half * 8);
            sA = MFMA(qfh[ks], bh, sA);
            sB = MFMA(qfh[ks], bl, sB);
            sC = MFMA(qfl[ks], bh, sC);
        }
        const float k0v = K0s[cur][l31], k128v = K128s[cur][l31];
        const int   mv  = Ms[cur][l31];
        #pragma unroll
        for (int r = 0; r < 16; ++r) {
            float sv = sA[r] + sB[r] + sC[r];
            float sc = (2.f * q0[r] * k0v - sv - q128[r] * k128v) * SCALE;
            float e  = mv ? __expf(sc) : 0.f;
            mu128p[r] += e * k128v;
            __bf16 eh = (__bf16)e;
            __bf16 el = (__bf16)(e - (float)eh);
            const int qr = (r & 3) + 8 * (r >> 2) + 4 * half;
            Pb[(w * 2 + 0) * 1152 + qr * 36 + l31] = eh;
            Pb[(w * 2 + 1) * 1152 + qr * 36 + l31] = el;
        }

        // ---- phase B: mu += P . X; B-fragments = columns of KH/KL (8x u16 each, lane=comp) ----
        #pragma unroll
        for (int ks = 0; ks < 2; ++ks) {
            bf16x8 ah = ld_lds8(Pb + (w * 2 + 0) * 1152 + l31 * 36 + ks * 16 + half * 8);
            bf16x8 al = ld_lds8(Pb + (w * 2 + 1) * 1152 + l31 * 36 + ks * 16 + half * 8);
            #pragma unroll
            for (int nt = 0; nt < 4; ++nt) {
                const int cmp = nt * 32 + l31;
                bf16x8 bh, bl;
                #pragma unroll
                for (int j = 0; j < 8; ++j) {
                    const int key = ks * 16 + half * 8 + j;
                    bh[j] = KH[key * 132 + cmp];
                    bl[j] = KL[key * 132 + cmp];
                }
                accM[nt] = MFMA(ah, bh, accM[nt]);
                accM[nt] = MFMA(ah, bl, accM[nt]);
                accM[nt] = MFMA(al, bh, accM[nt]);
            }
        }

        st_tile(cur ^ 1);                        // write next buffer (nobody reads it this tile)
    }

    #pragma unroll
    for (int r = 0; r < 16; ++r) mu128p[r] = half_sum32(mu128p[r], half);
    float rno[16];
    #pragma unroll
    for (int r = 0; r < 16; ++r) {
        float p = 0.f;
        #pragma unroll
        for (int nt = 0; nt < 4; ++nt) p += accM[nt][r] * accM[nt][r];
        if (l31 == 0) p -= 2.f * accM[0][r] * accM[0][r];
        p = half_sum32(p, half);
        float negI = -(p + mu128p[r] * mu128p[r]);
        negI = fmaxf(negI, 1e-7f);
        rno[r] = 1.f / (SCf * sqrtf(negI));
    }
    #pragma unroll
    for (int nt = 0; nt < 4; ++nt)
        #pragma unroll
        for (int r = 0; r < 16; ++r) accM[nt][r] *= rno[r];
    #pragma unroll
    for (int r = 0; r < 16; ++r) mu128p[r] *= rno[r];

    __syncthreads();                             // done with KB/Pb; alias as MuA
    __bf16* MuA = (__bf16*)smem + w * (32 * 148);
    #pragma unroll
    for (int r = 0; r < 16; ++r) {
        const int qr = (r & 3) + 8 * (r >> 2) + 4 * half;
        #pragma unroll
        for (int nt = 0; nt < 4; ++nt)
            MuA[qr * 148 + nt * 32 + l31] = (__bf16)accM[nt][r];
        if (l31 == 0) MuA[qr * 148 + 128] = (__bf16)mu128p[r];
        if (l31 >= 1 && l31 <= 15) MuA[qr * 148 + 128 + l31] = (__bf16)0.f;
    }
    bf16x8 Ah[9];
    #pragma unroll
    for (int ks = 0; ks < 9; ++ks) Ah[ks] = ld_lds8(MuA + l31 * 148 + ks * 16 + half * 8);
    #pragma unroll
    for (int r = 0; r < 16; ++r) {
        const int qr = (r & 3) + 8 * (r >> 2) + 4 * half;
        #pragma unroll
        for (int nt = 0; nt < 4; ++nt) {
            float m = accM[nt][r];
            MuA[qr * 148 + nt * 32 + l31] = (__bf16)(m - (float)(__bf16)m);
        }
        if (l31 == 0) {
            float m = mu128p[r];
            MuA[qr * 148 + 128] = (__bf16)(m - (float)(__bf16)m);
        }
    }
    bf16x8 Al[9];
    #pragma unroll
    for (int ks = 0; ks < 9; ++ks) Al[ks] = ld_lds8(MuA + l31 * 148 + ks * 16 + half * 8);

    f32x16 accU[4] = {};
    #pragma unroll
    for (int ks = 0; ks < 9; ++ks) {
        #pragma unroll
        for (int nt = 0; nt < 4; ++nt) {
            bf16x8 bh = *(const bf16x8*)(Woh + (size_t)(nt * 32 + l31) * 144 + ks * 16 + half * 8);
            bf16x8 bl = *(const bf16x8*)(Wol + (size_t)(nt * 32 + l31) * 144 + ks * 16 + half * 8);
            accU[nt] = MFMA(Ah[ks], bh, accU[nt]);
            accU[nt] = MFMA(Ah[ks], bl, accU[nt]);
            accU[nt] = MFMA(Al[ks], bh, accU[nt]);
        }
    }

    float bov[4];
    #pragma unroll
    for (int nt = 0; nt < 4; ++nt) bov[nt] = bo[nt * 32 + l31];
    #pragma unroll
    for (int r = 0; r < 16; ++r) {
        float p = 0.f;
        #pragma unroll
        for (int nt = 0; nt < 4; ++nt) {
            float uv = accU[nt][r] + bov[nt];
            accU[nt][r] = uv;
            p += uv * uv;
        }
        float nn = half_sum32(p, half);
        float nu = fmaxf(sqrtf(nn), 1e-7f);
        float aa = SCf * nu;
        float cf = tanhf(aa) / aa;
        const int qr = (r & 3) + 8 * (r >> 2) + 4 * half;
        const size_t row = (size_t)(b * N_ + qb + w * 32 + qr);
        #pragma unroll
        for (int nt = 0; nt < 4; ++nt)
            Y[row * D_ + nt * 32 + l31] = accU[nt][r] * cf;
        if (l31 == 0) Y2[row] = nn * cf * cf;
    }
}

// ---------------- diagonal Gram blocks: G[b][c][i][k] = <y_i, y_k>, i,k in chunk c ----------------
__global__ __launch_bounds__(256) void k_gram(const float* __restrict__ Y,
                                              float* __restrict__ G) {
    const int c = blockIdx.x, b = blockIdx.y;
    const int t = threadIdx.x, w = t >> 6, l = t & 63;
    const int l31 = l & 31, half = l >> 5;
    const int rt = w >> 1, ct = w & 1;                 // 32x32 tile of the 64x64 block
    const size_t base = (size_t)(b * N_ + c * 64);
    const float* Ar = Y + (base + rt * 32 + l31) * D_;
    const float* Br = Y + (base + ct * 32 + l31) * D_;
    f32x16 acc = {};
    #pragma unroll
    for (int ks = 0; ks < 8; ++ks) {
        const int c0 = ks * 16 + half * 8;
        float4 a0 = *(const float4*)(Ar + c0);
        float4 a1 = *(const float4*)(Ar + c0 + 4);
        float4 b0 = *(const float4*)(Br + c0);
        float4 b1 = *(const float4*)(Br + c0 + 4);
        float av[8] = {a0.x, a0.y, a0.z, a0.w, a1.x, a1.y, a1.z, a1.w};
        float bv[8] = {b0.x, b0.y, b0.z, b0.w, b1.x, b1.y, b1.z, b1.w};
        bf16x8 ah, al, bh, bl;
        #pragma unroll
        for (int j = 0; j < 8; ++j) {
            __bf16 h = (__bf16)av[j]; ah[j] = h; al[j] = (__bf16)(av[j] - (float)h);
            __bf16 g = (__bf16)bv[j]; bh[j] = g; bl[j] = (__bf16)(bv[j] - (float)g);
        }
        acc = MFMA(ah, bh, acc);
        acc = MFMA(ah, bl, acc);
        acc = MFMA(al, bh, acc);
    }
    float* Gb = G + ((size_t)(b * 16 + c) << 12);
    #pragma unroll
    for (int r = 0; r < 16; ++r) {
        const int row = rt * 32 + (r & 3) + 8 * (r >> 2) + 4 * half;
        Gb[row * 64 + ct * 32 + l31] = acc[r];
    }
}

// ---------------- Mobius fold: Gram-scan, all per-step operands in REGISTERS ----------------
__global__ __launch_bounds__(64, 1) void k_pool(const float* __restrict__ Y,
                                                const float* __restrict__ Y2,
                                                const float* __restrict__ G,
                                                const int* __restrict__ mask,
                                                const int* __restrict__ mflag,
                                                const float* __restrict__ Wf,
                                                const float* __restrict__ bf_,
                                                float* __restrict__ out) {
    __shared__ float  prt[64][65];
    __shared__ double vb[D_];
    const int b = blockIdx.x, l = threadIdx.x;
    const int is8 = *mflag;

    int cl = 0;
    for (int i = l; i < N_; i += 64) cl += read_mask(mask, is8, b * N_ + i);
    const int cntT = (int)(wave_sum64((float)cl) + 0.5f);

    const float2* __restrict__ Yp = (const float2*)(Y + (size_t)b * N_ * D_) + l;   // lane column
    const float*  __restrict__ Gp = G + ((size_t)b << 16) + l;   // block c, row i: Gp[c*4096 + i*64]
    const float*  __restrict__ Pp = Y2 + b * N_;

    float  GA[64], GB[64];
    float  py2A, py2B;
    int    msA, msB;
    float2 yring[2][16];

    #pragma unroll
    for (int i = 0; i < 64; ++i) GA[i] = Gp[i * 64];
    py2A = Pp[l];
    msA  = read_mask(mask, is8, b * N_ + l);
    #pragma unroll
    for (int k = 0; k < 16; ++k) yring[0][k] = Yp[(size_t)k * 64];

    float U0 = 0.f, U1 = 0.f, g = 0.f, Dh = 1.f, P = 0.f;

    auto chunk = [&](int c, float (&Gc)[64], float (&Gn)[64],
                     float py2c, float& py2n, int msc, int& msn) {
        const int cn = (c < 15) ? c + 1 : 15;
        #pragma unroll
        for (int i = 0; i < 64; ++i) Gn[i] = Gp[cn * 4096 + i * 64];
        py2n = Pp[cn * 64 + l];
        msn  = read_mask(mask, is8, b * N_ + cn * 64 + l);

        #pragma unroll
        for (int q = 0; q < 4; ++q) {
            #pragma unroll
            for (int k = 0; k < 16; ++k) {
                int gs = c * 64 + (q + 1) * 16 + k;
                if (gs > N_ - 1) gs = N_ - 1;
                yring[(q + 1) & 1][k] = Yp[(size_t)gs * 64];
            }
            #pragma unroll
            for (int k = 0; k < 16; ++k) {
                const int ir = q * 16 + k;                      // compile-time lane index
                const float2 yv  = yring[q & 1][k];
                const float  Gv  = Gc[ir];
                const float  py2 = readlane_f(py2c, ir);
                const bool   m   = (__builtin_amdgcn_readlane(msc, ir) != 0);
                const float Dsq   = Dh * Dh;
                const float Bh    = fmaf(-0.1f, P, Dsq);
                const float Donep = Dh * fmaf(0.1f, py2, 1.f);
                const float tP    = (0.01f * py2) * P;
                const float puy  = readlane_f(g, ir);
                const float Ahat = fmaf(0.2f, puy, Donep);
                float dh = fmaf(Dh, fmaf(0.2f, puy, Dh), tP);
                dh = fmaxf(dh, 1e-12f * Dsq);
                const float Draw = m ? dh : Dh;
                const float Am   = m ? Ahat : 1.f;
                const float Bm   = m ? Bh   : 0.f;
                const float Pn   = fmaf(Am, fmaf(Am, P, (2.f * Bm) * puy), (Bm * Bm) * py2);
                if ((k & 3) == 3) {                 // exact 2^-e rescale every 4th step
                    const int e = ilogbf(Draw);
                    const float Aef = ldexpf(Am, -e);
                    const float Bef = ldexpf(Bm, -e);
                    Dh = ldexpf(Draw, -e);
                    P  = ldexpf(Pn, -2 * e);
                    g  = fmaf(Aef, g, Bef * Gv);
                    U0 = fmaf(Aef, U0, Bef * yv.x);
                    U1 = fmaf(Aef, U1, Bef * yv.y);
                } else {
                    Dh = Draw;
                    P  = Pn;
                    g  = fmaf(Am, g, Bm * Gv);
                    U0 = fmaf(Am, U0, Bm * yv.x);
                    U1 = fmaf(Am, U1, Bm * yv.y);
                }
            }
        }
        if (c < 15) {
            const int nb = (c + 1) * 64;
            #pragma unroll
            for (int k0 = 0; k0 < 64; k0 += 16) {
                float2 tmp[16];
                #pragma unroll
                for (int k = 0; k < 16; ++k) tmp[k] = Yp[(size_t)(nb + k0 + k) * 64];
                #pragma unroll
                for (int k = 0; k < 16; ++k)
                    prt[k0 + k][l] = fmaf(U0, tmp[k].x, U1 * tmp[k].y);
            }
            float s0 = 0.f, s1 = 0.f, s2 = 0.f, s3 = 0.f;
            #pragma unroll
            for (int p = 0; p < 64; p += 4) {
                s0 += prt[l][p];     s1 += prt[l][p + 1];
                s2 += prt[l][p + 2]; s3 += prt[l][p + 3];
            }
            g = (s0 + s1) + (s2 + s3);
        }
    };

    for (int cc = 0; cc < 8; ++cc) {
        chunk(2 * cc,     GA, GB, py2A, py2B, msA, msB);
        chunk(2 * cc + 1, GB, GA, py2B, py2A, msB, msA);
    }

    const double SCd = 0.31622776601683794;
    const double sD = 1.0 / (double)Dh;
    double a0 = sD * (double)U0, a1 = sD * (double)U1;
    double n2 = fmax((double)P * (sD * sD), 0.0);
    double n = sqrt(n2);
    double tt = SCd * n;
    tt = fmin(fmax(tt, 1e-7), 1.0 - 1e-6);
    int cm = cntT > 0 ? cntT : 1;
    float rf = (float)(1.0 / (double)cm);        // ref casts r to float32
    double r = (double)rf;
    double dv = fmax(SCd * n, 1e-7);
    double f = tanh(r * atanh(tt)) / dv;
    double p0 = a0 * f, p1 = a1 * f;
    double q2;
    if (cntT == 0) {                             // fallback: first token's y
        float2 y0v = *(const float2*)(Y + (size_t)(b * N_) * D_ + 2 * l);
        p0 = y0v.x; p1 = y0v.y;
        q2 = (double)Y2[b * N_];
    } else {
        q2 = f * f * n2;
    }
    double npn = fmax(sqrt(q2), 1e-7);
    double t2 = fmin(fmax(SCd * npn, 1e-7), 1.0 - 1e-6);
    double f2 = atanh(t2) / (SCd * npn);
    vb[2 * l]     = p0 * f2;
    vb[2 * l + 1] = p1 * f2;
    __syncthreads();

    if (l < NC_) {
        double o = (double)bf_[l];
        for (int d = 0; d < D_; ++d) o += vb[d] * (double)Wf[l * D_ + d];
        out[b * NC_ + l] = (float)o;
    }
}

extern "C" void kernel_launch(void* const* d_in, const int* in_sizes, int n_in,
                              void* d_out, int out_size, void* d_ws, size_t ws_size,
                              hipStream_t stream) {
    const int*   tok  = (const int*)d_in[0];
    const int*   mask = (const int*)d_in[1];
    const float* emb  = (const float*)d_in[2];
    const float* Wo   = (const float*)d_in[3];
    const float* bo   = (const float*)d_in[4];
    const float* Wf   = (const float*)d_in[5];
    const float* bf_  = (const float*)d_in[6];
    float* out = (float*)d_out;

    char* wsb = (char*)d_ws;
    __bf16* Xh   = (__bf16*)wsb;                              // 16,777,216 B (reused as Gram after k_attn)
    __bf16* Xl   = (__bf16*)(wsb + 16777216);                 // 16,777,216 B
    float*  X0g  = (float*)(wsb + 33554432);                  //    262,144 B
    float*  X128g= (float*)(wsb + 33816576);                  //    262,144 B
    __bf16* Woh  = (__bf16*)(wsb + 34078720);                 //     36,864 B
    __bf16* Wol  = (__bf16*)(wsb + 34115584);                 //     36,864 B
    float*  Y    = (float*)(wsb + 34152448);                  // 33,554,432 B
    float*  Y2   = (float*)(wsb + 67706880);                  //    262,144 B
    int*    flag = (int*)(wsb + 67969024);                    // total ~67.97 MB
    float*  Gram = (float*)wsb;                               // aliases Xh (dead after k_attn): 16.77 MB

    k_detect_mask<<<dim3(1), dim3(256), 0, stream>>>(mask, flag);
    k_prep_wo<<<dim3(72), dim3(256), 0, stream>>>(Wo, Woh, Wol);
    k_prep<<<dim3(B_ * N_ / 64), dim3(256), 0, stream>>>(tok, emb, Xh, Xl, X0g, X128g);
    k_attn<<<dim3(B_, N_ / QB), dim3(256), 53760, stream>>>(Xh, Xl, X0g, X128g, mask, flag,
                                                            Woh, Wol, bo, Y, Y2);
    k_gram<<<dim3(16, B_), dim3(256), 0, stream>>>(Y, Gram);
    k_pool<<<dim3(B_), dim3(64), 0, stream>>>(Y, Y2, Gram, mask, flag, Wf, bf_, out);
}

// Round 5
// 392.684 us; speedup vs baseline: 2.7228x; 1.1210x over previous
//
#include <hip/hip_runtime.h>
#include <math.h>

#define B_    64
#define N_    1024
#define D_    128
#define DP1   129
#define NC_   10
#define QB    128     // queries per block (4 waves x 32)
#define KT    32      // key tile
#define SCf   0.31622776601683794f
#define SCALE 0.08804509063256238f   // 1/sqrt(129)

typedef __bf16 bf16x8 __attribute__((ext_vector_type(8)));
typedef float  f32x16 __attribute__((ext_vector_type(16)));
typedef unsigned int  u32x4v __attribute__((ext_vector_type(4)));
typedef unsigned long long ull;

#define MFMA(a, b, c) __builtin_amdgcn_mfma_f32_32x32x16_bf16((a), (b), (c), 0, 0, 0)

// v_perm_b32 packers: pk_lo16(a,b) = [a.lo16, b.lo16], pk_hi16(a,b) = [a.hi16, b.hi16]
// (perm sel: bytes 0-3 = src1, 4-7 = src0)
static __device__ __forceinline__ unsigned pk_lo16(unsigned a, unsigned b) {
    return __builtin_amdgcn_perm(b, a, 0x05040100u);
}
static __device__ __forceinline__ unsigned pk_hi16(unsigned a, unsigned b) {
    return __builtin_amdgcn_perm(b, a, 0x07060302u);
}

static __device__ __forceinline__ float dpp_add_step(float f, int ctrl, int rmask) {
    if (ctrl == 0x111) { int t = __builtin_amdgcn_update_dpp(0, __builtin_bit_cast(int, f), 0x111, 0xf, 0xf, true); return f + __builtin_bit_cast(float, t); }
    if (ctrl == 0x112) { int t = __builtin_amdgcn_update_dpp(0, __builtin_bit_cast(int, f), 0x112, 0xf, 0xf, true); return f + __builtin_bit_cast(float, t); }
    if (ctrl == 0x114) { int t = __builtin_amdgcn_update_dpp(0, __builtin_bit_cast(int, f), 0x114, 0xf, 0xf, true); return f + __builtin_bit_cast(float, t); }
    if (ctrl == 0x118) { int t = __builtin_amdgcn_update_dpp(0, __builtin_bit_cast(int, f), 0x118, 0xf, 0xf, true); return f + __builtin_bit_cast(float, t); }
    if (ctrl == 0x142 && rmask == 0xa) { int t = __builtin_amdgcn_update_dpp(0, __builtin_bit_cast(int, f), 0x142, 0xa, 0xf, true); return f + __builtin_bit_cast(float, t); }
    { int t = __builtin_amdgcn_update_dpp(0, __builtin_bit_cast(int, f), 0x143, 0xc, 0xf, true); return f + __builtin_bit_cast(float, t); }
}

// full 64-lane sum, result broadcast to all lanes
static __device__ __forceinline__ float wave_sum64(float f) {
    f = dpp_add_step(f, 0x111, 0xf);
    f = dpp_add_step(f, 0x112, 0xf);
    f = dpp_add_step(f, 0x114, 0xf);
    f = dpp_add_step(f, 0x118, 0xf);
    f = dpp_add_step(f, 0x142, 0xa);
    f = dpp_add_step(f, 0x143, 0xc);
    return __builtin_bit_cast(float, __builtin_amdgcn_readlane(__builtin_bit_cast(int, f), 63));
}

// per-32-lane-half sum, each lane gets its half's total
static __device__ __forceinline__ float half_sum32(float f, int half) {
    f = dpp_add_step(f, 0x111, 0xf);
    f = dpp_add_step(f, 0x112, 0xf);
    f = dpp_add_step(f, 0x114, 0xf);
    f = dpp_add_step(f, 0x118, 0xf);
    f = dpp_add_step(f, 0x142, 0xa);
    float s0 = __builtin_bit_cast(float, __builtin_amdgcn_readlane(__builtin_bit_cast(int, f), 31));
    float s1 = __builtin_bit_cast(float, __builtin_amdgcn_readlane(__builtin_bit_cast(int, f), 63));
    return half ? s1 : s0;
}

static __device__ __forceinline__ float readlane_f(float v, int lane) {
    return __builtin_bit_cast(float, __builtin_amdgcn_readlane(__builtin_bit_cast(int, v), lane));
}

static __device__ __forceinline__ bf16x8 ld_lds8(const __bf16* p) {
    union { bf16x8 v; ull q[2]; } u;
    u.q[0] = *(const ull*)(p);
    u.q[1] = *(const ull*)(p + 4);
    return u.v;
}

// ---------------- mask dtype detection (int32 vs packed int8 bool) ----------------
__global__ __launch_bounds__(256) void k_detect_mask(const int* __restrict__ mask_w,
                                                     int* __restrict__ flag) {
    __shared__ int bad;
    if (threadIdx.x == 0) bad = 0;
    __syncthreads();
    int local = 0;
    for (int i = threadIdx.x; i < 16384; i += 256) {
        int v = mask_w[i];
        if (v != 0 && v != 1) local = 1;
    }
    if (local) atomicOr(&bad, 1);
    __syncthreads();
    if (threadIdx.x == 0) *flag = bad;   // 1 => data is packed int8 bools
}

static __device__ __forceinline__ int read_mask(const int* mw, int is_i8, int idx) {
    if (is_i8) return (int)((const unsigned char*)mw)[idx];
    return mw[idx];
}

// ---------------- Wo -> bf16 hi/lo, layout [o][144] (K padded 129->144 with zeros) ----------------
__global__ __launch_bounds__(256) void k_prep_wo(const float* __restrict__ Wo,
                                                 __bf16* __restrict__ Woh,
                                                 __bf16* __restrict__ Wol) {
    int idx = blockIdx.x * 256 + threadIdx.x;
    if (idx >= 128 * 144) return;
    int o = idx / 144, d = idx - o * 144;
    float v = (d < DP1) ? Wo[o * DP1 + d] : 0.f;
    __bf16 h = (__bf16)v;
    Woh[idx] = h;
    Wol[idx] = (__bf16)(v - (float)h);
}

// ---------------- embedding + Lorentz expmap0 -> bf16 hi/lo rows + comp0/comp128 f32 ----------------
__global__ __launch_bounds__(256) void k_prep(const int* __restrict__ tok,
                                              const float* __restrict__ emb,
                                              __bf16* __restrict__ Xh, __bf16* __restrict__ Xl,
                                              float* __restrict__ X0g, float* __restrict__ X128g) {
    __shared__ float Xf[64][132];
    const int t = threadIdx.x, w = t >> 6, l = t & 63;
    const int base = blockIdx.x * 64;
    for (int it = 0; it < 16; ++it) {
        const int tk = w * 16 + it;
        const int id = tok[base + tk];
        const float2 v = ((const float2*)(emb + (size_t)id * D_))[l];
        float s = wave_sum64(v.x * v.x + v.y * v.y);
        float nv = fmaxf(sqrtf(s), 1e-7f);
        float a = SCf * nv;
        float a2 = a * a;
        float shc, ch;
        if (a < 0.5f) {
            shc = 1.f + a2 * (1.f/6.f) * (1.f + a2 * (1.f/20.f) * (1.f + a2 * (1.f/42.f)));
            ch  = 1.f + a2 * 0.5f * (1.f + a2 * (1.f/12.f) * (1.f + a2 * (1.f/30.f)));
        } else {
            float ea = __expf(a), ei = 1.f / ea;
            ch = 0.5f * (ea + ei);
            shc = 0.5f * (ea - ei) / a;
        }
        Xf[tk][1 + 2 * l] = v.x * shc;
        Xf[tk][2 + 2 * l] = v.y * shc;
        if (l == 0) Xf[tk][0] = ch / SCf;
    }
    __syncthreads();
    const int tk2 = t >> 2, dg = (t & 3) * 32;
    for (int i = 0; i < 32; i += 8) {
        bf16x8 hv, lv;
        #pragma unroll
        for (int j = 0; j < 8; ++j) {
            float f = Xf[tk2][dg + i + j];
            __bf16 h = (__bf16)f;
            hv[j] = h;
            lv[j] = (__bf16)(f - (float)h);
        }
        *(bf16x8*)(Xh + (size_t)(base + tk2) * D_ + dg + i) = hv;
        *(bf16x8*)(Xl + (size_t)(base + tk2) * D_ + dg + i) = lv;
    }
    if (t < 64) {
        X0g[base + t]   = Xf[t][0];
        X128g[base + t] = Xf[t][D_];
    }
}

// ---------------- fused MFMA attention (r15) ----------------
// r10: grid x=batch -> XCD=b%8, K panel L2-resident (FETCH 154->35MB).
// r11/r12 POST-MORTEM: launch_bounds(,3) VGPR cap -> Q remat from global, FETCH ~1GB. Reverted.
// r13 POST-MORTEM: grid=512 blocks=2/CU exactly, 3rd block impossible; setprio flapping in
//   lockstep 4-wave structure cost 30us (matches m190). Removed.
// r14 POST-MORTEM: accS 3-chain split: compiler pinned VGPR=128 and SPILLED (WRITE +14MB,
//   FETCH +8MB, 213us). Reverted to single chain.
// r15: LDS-pipe diet (largest pipe, ~50% model): K tile + P stored HI/LO-INTERLEAVED as u32
//   (lo16=hi-part, hi16=lo-part), packed/unpacked in-register via v_perm_b32.
//   Per tile per wave: phase-B gather 128 ds_read_u16 -> 64 ds_read_b32 (one read = both
//   planes; 2-way bank alias = free); phase-A 32 b64 -> 16 b128 (stride 132 u32 = 4 mod 32:
//   8 consecutive lanes tile all banks, conflict-free); Pb 32 b16 writes -> 16 b32,
//   8 b64 reads -> 4 b128; staging 8 b64 -> 4 b128 writes. ~200 -> ~116 LDS instr.
//   Cost: +~144 v_perm per tile-wave on the 31%-busy VALU. Global layout/k_prep untouched.
__global__ __launch_bounds__(256, 2) void k_attn(
        const __bf16* __restrict__ Xh, const __bf16* __restrict__ Xl,
        const float* __restrict__ X0g, const float* __restrict__ X128g,
        const int* __restrict__ mask, const int* __restrict__ mflag,
        const __bf16* __restrict__ Woh, const __bf16* __restrict__ Wol,
        const float* __restrict__ bo,
        float* __restrict__ Y, float* __restrict__ Y2) {
    extern __shared__ char smem[];
    // KBI[2]: interleaved K tile, 32 keys x 132 u32 (4224 u32 = 16896 B) per buffer
    unsigned* KBI = (unsigned*)smem;
    // Pbi: per-wave interleaved P, 32 rows x 36 u32 (1152 u32 = 4608 B) per wave
    unsigned* Pbi = (unsigned*)(smem + 33792);
    __shared__ float K0s[2][KT];
    __shared__ float K128s[2][KT];
    __shared__ int   Ms[2][KT];

    const int b    = blockIdx.x;                // batch on x: XCD-local L2 reuse
    const int qb   = blockIdx.y * QB;
    const int t    = threadIdx.x;
    const int w    = t >> 6;
    const int l    = t & 63;
    const int l31  = l & 31;
    const int half = l >> 5;
    const int is8  = *mflag;

    // ---- Q fragments (A operand): A[m=lane&31][k=half*8+j], hi/lo, 8 k-steps over comps 0..127 ----
    const size_t qrow = (size_t)(b * N_ + qb + w * 32 + l31);
    bf16x8 qfh[8], qfl[8];
    #pragma unroll
    for (int ks = 0; ks < 8; ++ks) {
        qfh[ks] = *(const bf16x8*)(Xh + qrow * D_ + ks * 16 + half * 8);
        qfl[ks] = *(const bf16x8*)(Xl + qrow * D_ + ks * 16 + half * 8);
    }
    float q0[16], q128[16];
    #pragma unroll
    for (int r = 0; r < 16; ++r) {
        const int qr = (r & 3) + 8 * (r >> 2) + 4 * half;
        q0[r]   = X0g[b * N_ + qb + w * 32 + qr];
        q128[r] = X128g[b * N_ + qb + w * 32 + qr];
    }

    // ---- staging: global hi/lo bf16x8 -> regs; interleave to u32 at store time ----
    const int skey = t >> 3, sck = t & 7;       // 32 keys x 8 chunks of 16 comps
    bf16x8 svh0, svh1, svl0, svl1;
    float  sK0 = 0.f, sK128 = 0.f;
    int    sM = 0;
    auto ldg_tile = [&](int kt) {
        const size_t kr = (size_t)(b * N_ + kt * KT + skey);
        svh0 = *(const bf16x8*)(Xh + kr * D_ + sck * 16);
        svh1 = *(const bf16x8*)(Xh + kr * D_ + sck * 16 + 8);
        svl0 = *(const bf16x8*)(Xl + kr * D_ + sck * 16);
        svl1 = *(const bf16x8*)(Xl + kr * D_ + sck * 16 + 8);
        if (t < KT) {
            sK0   = X0g[b * N_ + kt * KT + t];
            sK128 = X128g[b * N_ + kt * KT + t];
            sM    = read_mask(mask, is8, b * N_ + kt * KT + t);
        }
    };
    auto st_tile = [&](int buf) {
        unsigned* KI = KBI + buf * 4224;
        union { bf16x8 v; unsigned d[4]; } H0, H1, L0, L1;
        H0.v = svh0; H1.v = svh1; L0.v = svl0; L1.v = svl1;
        u32x4v o0 = { pk_lo16(H0.d[0], L0.d[0]), pk_hi16(H0.d[0], L0.d[0]),
                      pk_lo16(H0.d[1], L0.d[1]), pk_hi16(H0.d[1], L0.d[1]) };
        u32x4v o1 = { pk_lo16(H0.d[2], L0.d[2]), pk_hi16(H0.d[2], L0.d[2]),
                      pk_lo16(H0.d[3], L0.d[3]), pk_hi16(H0.d[3], L0.d[3]) };
        u32x4v o2 = { pk_lo16(H1.d[0], L1.d[0]), pk_hi16(H1.d[0], L1.d[0]),
                      pk_lo16(H1.d[1], L1.d[1]), pk_hi16(H1.d[1], L1.d[1]) };
        u32x4v o3 = { pk_lo16(H1.d[2], L1.d[2]), pk_hi16(H1.d[2], L1.d[2]),
                      pk_lo16(H1.d[3], L1.d[3]), pk_hi16(H1.d[3], L1.d[3]) };
        u32x4v* dst = (u32x4v*)(KI + skey * 132 + sck * 16);
        dst[0] = o0; dst[1] = o1; dst[2] = o2; dst[3] = o3;
        if (t < KT) { K0s[buf][t] = sK0; K128s[buf][t] = sK128; Ms[buf][t] = sM; }
    };

    f32x16 accM[4] = {};
    float  mu128p[16] = {};

    ldg_tile(0);
    st_tile(0);

    for (int kt = 0; kt < N_ / KT; ++kt) {
        __syncthreads();                         // buffer kt&1 fully staged by all threads
        const int cur = kt & 1;
        const int ktn = (kt < 31) ? kt + 1 : 31;
        ldg_tile(ktn);                           // global loads overlap this tile's compute

        const unsigned* KI = KBI + cur * 4224;

        // ---- phase A: S = Q . K (b128 row reads + perm unpack) ----
        f32x16 accS = {};
        #pragma unroll
        for (int ks = 0; ks < 8; ++ks) {
            const unsigned* p = KI + l31 * 132 + ks * 16 + half * 8;
            u32x4v ua = *(const u32x4v*)(p);
            u32x4v ub = *(const u32x4v*)(p + 4);
            union { bf16x8 v; unsigned d[4]; } BH, BL;
            BH.d[0] = pk_lo16(ua[0], ua[1]); BL.d[0] = pk_hi16(ua[0], ua[1]);
            BH.d[1] = pk_lo16(ua[2], ua[3]); BL.d[1] = pk_hi16(ua[2], ua[3]);
            BH.d[2] = pk_lo16(ub[0], ub[1]); BL.d[2] = pk_hi16(ub[0], ub[1]);
            BH.d[3] = pk_lo16(ub[2], ub[3]); BL.d[3] = pk_hi16(ub[2], ub[3]);
            accS = MFMA(qfh[ks], BH.v, accS);
            accS = MFMA(qfh[ks], BL.v, accS);
            accS = MFMA(qfl[ks], BH.v, accS);
        }
        const float k0v = K0s[cur][l31], k128v = K128s[cur][l31];
        const int   mv  = Ms[cur][l31];
        #pragma unroll
        for (int r = 0; r < 16; ++r) {
            float sc = (2.f * q0[r] * k0v - accS[r] - q128[r] * k128v) * SCALE;
            float e  = mv ? __expf(sc) : 0.f;
            mu128p[r] += e * k128v;
            __bf16 eh = (__bf16)e;
            __bf16 el = (__bf16)(e - (float)eh);
            unsigned pw = (unsigned)__builtin_bit_cast(unsigned short, eh)
                        | ((unsigned)__builtin_bit_cast(unsigned short, el) << 16);
            const int qr = (r & 3) + 8 * (r >> 2) + 4 * half;
            Pbi[w * 1152 + qr * 36 + l31] = pw;
        }

        // ---- phase B: mu += P . X; b32 column gather (one read = hi+lo) + perm unpack ----
        #pragma unroll
        for (int ks = 0; ks < 2; ++ks) {
            const unsigned* pp = Pbi + w * 1152 + l31 * 36 + ks * 16 + half * 8;
            u32x4v pa = *(const u32x4v*)(pp);
            u32x4v pb = *(const u32x4v*)(pp + 4);
            union { bf16x8 v; unsigned d[4]; } AH, AL;
            AH.d[0] = pk_lo16(pa[0], pa[1]); AL.d[0] = pk_hi16(pa[0], pa[1]);
            AH.d[1] = pk_lo16(pa[2], pa[3]); AL.d[1] = pk_hi16(pa[2], pa[3]);
            AH.d[2] = pk_lo16(pb[0], pb[1]); AL.d[2] = pk_hi16(pb[0], pb[1]);
            AH.d[3] = pk_lo16(pb[2], pb[3]); AL.d[3] = pk_hi16(pb[2], pb[3]);
            #pragma unroll
            for (int nt = 0; nt < 4; ++nt) {
                const unsigned* kb = KI + (ks * 16 + half * 8) * 132 + nt * 32 + l31;
                unsigned u[8];
                #pragma unroll
                for (int j = 0; j < 8; ++j) u[j] = kb[j * 132];
                union { bf16x8 v; unsigned d[4]; } BH, BL;
                BH.d[0] = pk_lo16(u[0], u[1]); BL.d[0] = pk_hi16(u[0], u[1]);
                BH.d[1] = pk_lo16(u[2], u[3]); BL.d[1] = pk_hi16(u[2], u[3]);
                BH.d[2] = pk_lo16(u[4], u[5]); BL.d[2] = pk_hi16(u[4], u[5]);
                BH.d[3] = pk_lo16(u[6], u[7]); BL.d[3] = pk_hi16(u[6], u[7]);
                accM[nt] = MFMA(AH.v, BH.v, accM[nt]);
                accM[nt] = MFMA(AH.v, BL.v, accM[nt]);
                accM[nt] = MFMA(AL.v, BH.v, accM[nt]);
            }
        }

        st_tile(cur ^ 1);                        // write next buffer (nobody reads it this tile)
    }

    #pragma unroll
    for (int r = 0; r < 16; ++r) mu128p[r] = half_sum32(mu128p[r], half);
    float rno[16];
    #pragma unroll
    for (int r = 0; r < 16; ++r) {
        float p = 0.f;
        #pragma unroll
        for (int nt = 0; nt < 4; ++nt) p += accM[nt][r] * accM[nt][r];
        if (l31 == 0) p -= 2.f * accM[0][r] * accM[0][r];
        p = half_sum32(p, half);
        float negI = -(p + mu128p[r] * mu128p[r]);
        negI = fmaxf(negI, 1e-7f);
        rno[r] = 1.f / (SCf * sqrtf(negI));
    }
    #pragma unroll
    for (int nt = 0; nt < 4; ++nt)
        #pragma unroll
        for (int r = 0; r < 16; ++r) accM[nt][r] *= rno[r];
    #pragma unroll
    for (int r = 0; r < 16; ++r) mu128p[r] *= rno[r];

    __syncthreads();                             // done with KBI/Pbi; alias as MuA
    __bf16* MuA = (__bf16*)smem + w * (32 * 148);
    #pragma unroll
    for (int r = 0; r < 16; ++r) {
        const int qr = (r & 3) + 8 * (r >> 2) + 4 * half;
        #pragma unroll
        for (int nt = 0; nt < 4; ++nt)
            MuA[qr * 148 + nt * 32 + l31] = (__bf16)accM[nt][r];
        if (l31 == 0) MuA[qr * 148 + 128] = (__bf16)mu128p[r];
        if (l31 >= 1 && l31 <= 15) MuA[qr * 148 + 128 + l31] = (__bf16)0.f;
    }
    bf16x8 Ah[9];
    #pragma unroll
    for (int ks = 0; ks < 9; ++ks) Ah[ks] = ld_lds8(MuA + l31 * 148 + ks * 16 + half * 8);
    #pragma unroll
    for (int r = 0; r < 16; ++r) {
        const int qr = (r & 3) + 8 * (r >> 2) + 4 * half;
        #pragma unroll
        for (int nt = 0; nt < 4; ++nt) {
            float m = accM[nt][r];
            MuA[qr * 148 + nt * 32 + l31] = (__bf16)(m - (float)(__bf16)m);
        }
        if (l31 == 0) {
            float m = mu128p[r];
            MuA[qr * 148 + 128] = (__bf16)(m - (float)(__bf16)m);
        }
    }
    bf16x8 Al[9];
    #pragma unroll
    for (int ks = 0; ks < 9; ++ks) Al[ks] = ld_lds8(MuA + l31 * 148 + ks * 16 + half * 8);

    f32x16 accU[4] = {};
    #pragma unroll
    for (int ks = 0; ks < 9; ++ks) {
        #pragma unroll
        for (int nt = 0; nt < 4; ++nt) {
            bf16x8 bh = *(const bf16x8*)(Woh + (size_t)(nt * 32 + l31) * 144 + ks * 16 + half * 8);
            bf16x8 bl = *(const bf16x8*)(Wol + (size_t)(nt * 32 + l31) * 144 + ks * 16 + half * 8);
            accU[nt] = MFMA(Ah[ks], bh, accU[nt]);
            accU[nt] = MFMA(Ah[ks], bl, accU[nt]);
            accU[nt] = MFMA(Al[ks], bh, accU[nt]);
        }
    }

    float bov[4];
    #pragma unroll
    for (int nt = 0; nt < 4; ++nt) bov[nt] = bo[nt * 32 + l31];
    #pragma unroll
    for (int r = 0; r < 16; ++r) {
        float p = 0.f;
        #pragma unroll
        for (int nt = 0; nt < 4; ++nt) {
            float uv = accU[nt][r] + bov[nt];
            accU[nt][r] = uv;
            p += uv * uv;
        }
        float nn = half_sum32(p, half);
        float nu = fmaxf(sqrtf(nn), 1e-7f);
        float aa = SCf * nu;
        float cf = tanhf(aa) / aa;
        const int qr = (r & 3) + 8 * (r >> 2) + 4 * half;
        const size_t row = (size_t)(b * N_ + qb + w * 32 + qr);
        #pragma unroll
        for (int nt = 0; nt < 4; ++nt)
            Y[row * D_ + nt * 32 + l31] = accU[nt][r] * cf;
        if (l31 == 0) Y2[row] = nn * cf * cf;
    }
}

// ---------------- diagonal Gram blocks: G[b][c][i][k] = <y_i, y_k>, i,k in chunk c ----------------
__global__ __launch_bounds__(256) void k_gram(const float* __restrict__ Y,
                                              float* __restrict__ G) {
    const int c = blockIdx.x, b = blockIdx.y;
    const int t = threadIdx.x, w = t >> 6, l = t & 63;
    const int l31 = l & 31, half = l >> 5;
    const int rt = w >> 1, ct = w & 1;                 // 32x32 tile of the 64x64 block
    const size_t base = (size_t)(b * N_ + c * 64);
    const float* Ar = Y + (base + rt * 32 + l31) * D_;
    const float* Br = Y + (base + ct * 32 + l31) * D_;
    f32x16 acc = {};
    #pragma unroll
    for (int ks = 0; ks < 8; ++ks) {
        const int c0 = ks * 16 + half * 8;
        float4 a0 = *(const float4*)(Ar + c0);
        float4 a1 = *(const float4*)(Ar + c0 + 4);
        float4 b0 = *(const float4*)(Br + c0);
        float4 b1 = *(const float4*)(Br + c0 + 4);
        float av[8] = {a0.x, a0.y, a0.z, a0.w, a1.x, a1.y, a1.z, a1.w};
        float bv[8] = {b0.x, b0.y, b0.z, b0.w, b1.x, b1.y, b1.z, b1.w};
        bf16x8 ah, al, bh, bl;
        #pragma unroll
        for (int j = 0; j < 8; ++j) {
            __bf16 h = (__bf16)av[j]; ah[j] = h; al[j] = (__bf16)(av[j] - (float)h);
            __bf16 g = (__bf16)bv[j]; bh[j] = g; bl[j] = (__bf16)(bv[j] - (float)g);
        }
        acc = MFMA(ah, bh, acc);
        acc = MFMA(ah, bl, acc);
        acc = MFMA(al, bh, acc);
    }
    float* Gb = G + ((size_t)(b * 16 + c) << 12);
    #pragma unroll
    for (int r = 0; r < 16; ++r) {
        const int row = rt * 32 + (r & 3) + 8 * (r >> 2) + 4 * half;
        Gb[row * 64 + ct * 32 + l31] = acc[r];
    }
}

// ---------------- Mobius fold: Gram-scan, all per-step operands in REGISTERS ----------------
__global__ __launch_bounds__(64, 1) void k_pool(const float* __restrict__ Y,
                                                const float* __restrict__ Y2,
                                                const float* __restrict__ G,
                                                const int* __restrict__ mask,
                                                const int* __restrict__ mflag,
                                                const float* __restrict__ Wf,
                                                const float* __restrict__ bf_,
                                                float* __restrict__ out) {
    __shared__ float  prt[64][65];
    __shared__ double vb[D_];
    const int b = blockIdx.x, l = threadIdx.x;
    const int is8 = *mflag;

    int cl = 0;
    for (int i = l; i < N_; i += 64) cl += read_mask(mask, is8, b * N_ + i);
    const int cntT = (int)(wave_sum64((float)cl) + 0.5f);

    const float2* __restrict__ Yp = (const float2*)(Y + (size_t)b * N_ * D_) + l;   // lane column
    const float*  __restrict__ Gp = G + ((size_t)b << 16) + l;   // block c, row i: Gp[c*4096 + i*64]
    const float*  __restrict__ Pp = Y2 + b * N_;

    float  GA[64], GB[64];
    float  py2A, py2B;
    int    msA, msB;
    float2 yring[2][16];

    #pragma unroll
    for (int i = 0; i < 64; ++i) GA[i] = Gp[i * 64];
    py2A = Pp[l];
    msA  = read_mask(mask, is8, b * N_ + l);
    #pragma unroll
    for (int k = 0; k < 16; ++k) yring[0][k] = Yp[(size_t)k * 64];

    float U0 = 0.f, U1 = 0.f, g = 0.f, Dh = 1.f, P = 0.f;

    auto chunk = [&](int c, float (&Gc)[64], float (&Gn)[64],
                     float py2c, float& py2n, int msc, int& msn) {
        const int cn = (c < 15) ? c + 1 : 15;
        #pragma unroll
        for (int i = 0; i < 64; ++i) Gn[i] = Gp[cn * 4096 + i * 64];
        py2n = Pp[cn * 64 + l];
        msn  = read_mask(mask, is8, b * N_ + cn * 64 + l);

        #pragma unroll
        for (int q = 0; q < 4; ++q) {
            #pragma unroll
            for (int k = 0; k < 16; ++k) {
                int gs = c * 64 + (q + 1) * 16 + k;
                if (gs > N_ - 1) gs = N_ - 1;
                yring[(q + 1) & 1][k] = Yp[(size_t)gs * 64];
            }
            #pragma unroll
            for (int k = 0; k < 16; ++k) {
                const int ir = q * 16 + k;                      // compile-time lane index
                const float2 yv  = yring[q & 1][k];
                const float  Gv  = Gc[ir];
                const float  py2 = readlane_f(py2c, ir);
                const bool   m   = (__builtin_amdgcn_readlane(msc, ir) != 0);
                const float Dsq   = Dh * Dh;
                const float Bh    = fmaf(-0.1f, P, Dsq);
                const float Donep = Dh * fmaf(0.1f, py2, 1.f);
                const float tP    = (0.01f * py2) * P;
                const float puy  = readlane_f(g, ir);
                const float Ahat = fmaf(0.2f, puy, Donep);
                float dh = fmaf(Dh, fmaf(0.2f, puy, Dh), tP);
                dh = fmaxf(dh, 1e-12f * Dsq);
                const float Draw = m ? dh : Dh;
                const float Am   = m ? Ahat : 1.f;
                const float Bm   = m ? Bh   : 0.f;
                const float Pn   = fmaf(Am, fmaf(Am, P, (2.f * Bm) * puy), (Bm * Bm) * py2);
                if ((k & 3) == 3) {                 // exact 2^-e rescale every 4th step
                    const int e = ilogbf(Draw);
                    const float Aef = ldexpf(Am, -e);
                    const float Bef = ldexpf(Bm, -e);
                    Dh = ldexpf(Draw, -e);
                    P  = ldexpf(Pn, -2 * e);
                    g  = fmaf(Aef, g, Bef * Gv);
                    U0 = fmaf(Aef, U0, Bef * yv.x);
                    U1 = fmaf(Aef, U1, Bef * yv.y);
                } else {
                    Dh = Draw;
                    P  = Pn;
                    g  = fmaf(Am, g, Bm * Gv);
                    U0 = fmaf(Am, U0, Bm * yv.x);
                    U1 = fmaf(Am, U1, Bm * yv.y);
                }
            }
        }
        if (c < 15) {
            const int nb = (c + 1) * 64;
            #pragma unroll
            for (int k0 = 0; k0 < 64; k0 += 16) {
                float2 tmp[16];
                #pragma unroll
                for (int k = 0; k < 16; ++k) tmp[k] = Yp[(size_t)(nb + k0 + k) * 64];
                #pragma unroll
                for (int k = 0; k < 16; ++k)
                    prt[k0 + k][l] = fmaf(U0, tmp[k].x, U1 * tmp[k].y);
            }
            float s0 = 0.f, s1 = 0.f, s2 = 0.f, s3 = 0.f;
            #pragma unroll
            for (int p = 0; p < 64; p += 4) {
                s0 += prt[l][p];     s1 += prt[l][p + 1];
                s2 += prt[l][p + 2]; s3 += prt[l][p + 3];
            }
            g = (s0 + s1) + (s2 + s3);
        }
    };

    for (int cc = 0; cc < 8; ++cc) {
        chunk(2 * cc,     GA, GB, py2A, py2B, msA, msB);
        chunk(2 * cc + 1, GB, GA, py2B, py2A, msB, msA);
    }

    const double SCd = 0.31622776601683794;
    const double sD = 1.0 / (double)Dh;
    double a0 = sD * (double)U0, a1 = sD * (double)U1;
    double n2 = fmax((double)P * (sD * sD), 0.0);
    double n = sqrt(n2);
    double tt = SCd * n;
    tt = fmin(fmax(tt, 1e-7), 1.0 - 1e-6);
    int cm = cntT > 0 ? cntT : 1;
    float rf = (float)(1.0 / (double)cm);        // ref casts r to float32
    double r = (double)rf;
    double dv = fmax(SCd * n, 1e-7);
    double f = tanh(r * atanh(tt)) / dv;
    double p0 = a0 * f, p1 = a1 * f;
    double q2;
    if (cntT == 0) {                             // fallback: first token's y
        float2 y0v = *(const float2*)(Y + (size_t)(b * N_) * D_ + 2 * l);
        p0 = y0v.x; p1 = y0v.y;
        q2 = (double)Y2[b * N_];
    } else {
        q2 = f * f * n2;
    }
    double npn = fmax(sqrt(q2), 1e-7);
    double t2 = fmin(fmax(SCd * npn, 1e-7), 1.0 - 1e-6);
    double f2 = atanh(t2) / (SCd * npn);
    vb[2 * l]     = p0 * f2;
    vb[2 * l + 1] = p1 * f2;
    __syncthreads();

    if (l < NC_) {
        double o = (double)bf_[l];
        for (int d = 0; d < D_; ++d) o += vb[d] * (double)Wf[l * D_ + d];
        out[b * NC_ + l] = (float)o;
    }
}

extern "C" void kernel_launch(void* const* d_in, const int* in_sizes, int n_in,
                              void* d_out, int out_size, void* d_ws, size_t ws_size,
                              hipStream_t stream) {
    const int*   tok  = (const int*)d_in[0];
    const int*   mask = (const int*)d_in[1];
    const float* emb  = (const float*)d_in[2];
    const float* Wo   = (const float*)d_in[3];
    const float* bo   = (const float*)d_in[4];
    const float* Wf   = (const float*)d_in[5];
    const float* bf_  = (const float*)d_in[6];
    float* out = (float*)d_out;

    char* wsb = (char*)d_ws;
    __bf16* Xh   = (__bf16*)wsb;                              // 16,777,216 B (reused as Gram after k_attn)
    __bf16* Xl   = (__bf16*)(wsb + 16777216);                 // 16,777,216 B
    float*  X0g  = (float*)(wsb + 33554432);                  //    262,144 B
    float*  X128g= (float*)(wsb + 33816576);                  //    262,144 B
    __bf16* Woh  = (__bf16*)(wsb + 34078720);                 //     36,864 B
    __bf16* Wol  = (__bf16*)(wsb + 34115584);                 //     36,864 B
    float*  Y    = (float*)(wsb + 34152448);                  // 33,554,432 B
    float*  Y2   = (float*)(wsb + 67706880);                  //    262,144 B
    int*    flag = (int*)(wsb + 67969024);                    // total ~67.97 MB
    float*  Gram = (float*)wsb;                               // aliases Xh (dead after k_attn): 16.77 MB

    k_detect_mask<<<dim3(1), dim3(256), 0, stream>>>(mask, flag);
    k_prep_wo<<<dim3(72), dim3(256), 0, stream>>>(Wo, Woh, Wol);
    k_prep<<<dim3(B_ * N_ / 64), dim3(256), 0, stream>>>(tok, emb, Xh, Xl, X0g, X128g);
    k_attn<<<dim3(B_, N_ / QB), dim3(256), 52224, stream>>>(Xh, Xl, X0g, X128g, mask, flag,
                                                            Woh, Wol, bo, Y, Y2);
    k_gram<<<dim3(16, B_), dim3(256), 0, stream>>>(Y, Gram);
    k_pool<<<dim3(B_), dim3(64), 0, stream>>>(Y, Y2, Gram, mask, flag, Wf, bf_, out);
}

// Round 6
// 387.973 us; speedup vs baseline: 2.7559x; 1.0121x over previous
//
#include <hip/hip_runtime.h>
#include <math.h>

#define B_    64
#define N_    1024
#define D_    128
#define DP1   129
#define NC_   10
#define QB    128     // queries per block (4 waves x 32)
#define KT    32      // key tile
#define SCf   0.31622776601683794f
#define SCALE 0.08804509063256238f   // 1/sqrt(129)

typedef __bf16 bf16x8 __attribute__((ext_vector_type(8)));
typedef float  f32x16 __attribute__((ext_vector_type(16)));
typedef unsigned int  u32x4v __attribute__((ext_vector_type(4)));
typedef unsigned long long ull;

#define MFMA(a, b, c) __builtin_amdgcn_mfma_f32_32x32x16_bf16((a), (b), (c), 0, 0, 0)

// v_perm_b32 packers: pk_lo16(a,b) = [a.lo16, b.lo16], pk_hi16(a,b) = [a.hi16, b.hi16]
static __device__ __forceinline__ unsigned pk_lo16(unsigned a, unsigned b) {
    return __builtin_amdgcn_perm(b, a, 0x05040100u);
}
static __device__ __forceinline__ unsigned pk_hi16(unsigned a, unsigned b) {
    return __builtin_amdgcn_perm(b, a, 0x07060302u);
}

static __device__ __forceinline__ float dpp_add_step(float f, int ctrl, int rmask) {
    if (ctrl == 0x111) { int t = __builtin_amdgcn_update_dpp(0, __builtin_bit_cast(int, f), 0x111, 0xf, 0xf, true); return f + __builtin_bit_cast(float, t); }
    if (ctrl == 0x112) { int t = __builtin_amdgcn_update_dpp(0, __builtin_bit_cast(int, f), 0x112, 0xf, 0xf, true); return f + __builtin_bit_cast(float, t); }
    if (ctrl == 0x114) { int t = __builtin_amdgcn_update_dpp(0, __builtin_bit_cast(int, f), 0x114, 0xf, 0xf, true); return f + __builtin_bit_cast(float, t); }
    if (ctrl == 0x118) { int t = __builtin_amdgcn_update_dpp(0, __builtin_bit_cast(int, f), 0x118, 0xf, 0xf, true); return f + __builtin_bit_cast(float, t); }
    if (ctrl == 0x142 && rmask == 0xa) { int t = __builtin_amdgcn_update_dpp(0, __builtin_bit_cast(int, f), 0x142, 0xa, 0xf, true); return f + __builtin_bit_cast(float, t); }
    { int t = __builtin_amdgcn_update_dpp(0, __builtin_bit_cast(int, f), 0x143, 0xc, 0xf, true); return f + __builtin_bit_cast(float, t); }
}

// full 64-lane sum, result broadcast to all lanes
static __device__ __forceinline__ float wave_sum64(float f) {
    f = dpp_add_step(f, 0x111, 0xf);
    f = dpp_add_step(f, 0x112, 0xf);
    f = dpp_add_step(f, 0x114, 0xf);
    f = dpp_add_step(f, 0x118, 0xf);
    f = dpp_add_step(f, 0x142, 0xa);
    f = dpp_add_step(f, 0x143, 0xc);
    return __builtin_bit_cast(float, __builtin_amdgcn_readlane(__builtin_bit_cast(int, f), 63));
}

// per-32-lane-half sum, each lane gets its half's total
static __device__ __forceinline__ float half_sum32(float f, int half) {
    f = dpp_add_step(f, 0x111, 0xf);
    f = dpp_add_step(f, 0x112, 0xf);
    f = dpp_add_step(f, 0x114, 0xf);
    f = dpp_add_step(f, 0x118, 0xf);
    f = dpp_add_step(f, 0x142, 0xa);
    float s0 = __builtin_bit_cast(float, __builtin_amdgcn_readlane(__builtin_bit_cast(int, f), 31));
    float s1 = __builtin_bit_cast(float, __builtin_amdgcn_readlane(__builtin_bit_cast(int, f), 63));
    return half ? s1 : s0;
}

static __device__ __forceinline__ float readlane_f(float v, int lane) {
    return __builtin_bit_cast(float, __builtin_amdgcn_readlane(__builtin_bit_cast(int, v), lane));
}

static __device__ __forceinline__ bf16x8 ld_lds8(const __bf16* p) {
    union { bf16x8 v; ull q[2]; } u;
    u.q[0] = *(const ull*)(p);
    u.q[1] = *(const ull*)(p + 4);
    return u.v;
}

static __device__ __forceinline__ int read_mask(const int* mw, int is_i8, int idx) {
    if (is_i8) return (int)((const unsigned char*)mw)[idx];
    return mw[idx];
}

// ---------------- merged prologue: prep (blocks 0..1023) + Wo (1024..1095) + mask-detect (1096) ----------------
__global__ __launch_bounds__(256) void k_pre(const int* __restrict__ tok,
                                             const float* __restrict__ emb,
                                             __bf16* __restrict__ Xh, __bf16* __restrict__ Xl,
                                             float* __restrict__ X0g, float* __restrict__ X128g,
                                             const int* __restrict__ mask_w, int* __restrict__ flag,
                                             const float* __restrict__ Wo,
                                             __bf16* __restrict__ Woh, __bf16* __restrict__ Wol) {
    const int t = threadIdx.x;
    if (blockIdx.x >= 1024) {
        if (blockIdx.x == 1096) {                    // mask dtype detect (int32 vs packed int8)
            __shared__ int bad;
            if (t == 0) bad = 0;
            __syncthreads();
            int local = 0;
            for (int i = t; i < 16384; i += 256) {
                int v = mask_w[i];
                if (v != 0 && v != 1) local = 1;
            }
            if (local) atomicOr(&bad, 1);
            __syncthreads();
            if (t == 0) *flag = bad;
        } else {                                     // Wo -> bf16 hi/lo [o][144]
            int idx = (blockIdx.x - 1024) * 256 + t;
            if (idx < 128 * 144) {
                int o = idx / 144, d = idx - o * 144;
                float v = (d < DP1) ? Wo[o * DP1 + d] : 0.f;
                __bf16 h = (__bf16)v;
                Woh[idx] = h;
                Wol[idx] = (__bf16)(v - (float)h);
            }
        }
        return;
    }
    // ---- embedding + Lorentz expmap0 -> bf16 hi/lo rows + comp0/comp128 f32 ----
    __shared__ float Xf[64][132];
    const int w = t >> 6, l = t & 63;
    const int base = blockIdx.x * 64;
    for (int it = 0; it < 16; ++it) {
        const int tk = w * 16 + it;
        const int id = tok[base + tk];
        const float2 v = ((const float2*)(emb + (size_t)id * D_))[l];
        float s = wave_sum64(v.x * v.x + v.y * v.y);
        float nv = fmaxf(sqrtf(s), 1e-7f);
        float a = SCf * nv;
        float a2 = a * a;
        float shc, ch;
        if (a < 0.5f) {
            shc = 1.f + a2 * (1.f/6.f) * (1.f + a2 * (1.f/20.f) * (1.f + a2 * (1.f/42.f)));
            ch  = 1.f + a2 * 0.5f * (1.f + a2 * (1.f/12.f) * (1.f + a2 * (1.f/30.f)));
        } else {
            float ea = __expf(a), ei = 1.f / ea;
            ch = 0.5f * (ea + ei);
            shc = 0.5f * (ea - ei) / a;
        }
        Xf[tk][1 + 2 * l] = v.x * shc;
        Xf[tk][2 + 2 * l] = v.y * shc;
        if (l == 0) Xf[tk][0] = ch / SCf;
    }
    __syncthreads();
    const int tk2 = t >> 2, dg = (t & 3) * 32;
    for (int i = 0; i < 32; i += 8) {
        bf16x8 hv, lv;
        #pragma unroll
        for (int j = 0; j < 8; ++j) {
            float f = Xf[tk2][dg + i + j];
            __bf16 h = (__bf16)f;
            hv[j] = h;
            lv[j] = (__bf16)(f - (float)h);
        }
        *(bf16x8*)(Xh + (size_t)(base + tk2) * D_ + dg + i) = hv;
        *(bf16x8*)(Xl + (size_t)(base + tk2) * D_ + dg + i) = lv;
    }
    if (t < 64) {
        X0g[base + t]   = Xf[t][0];
        X128g[base + t] = Xf[t][D_];
    }
}

// ---------------- fused MFMA attention (r16) ----------------
// r10: grid x=batch -> XCD=b%8, K panel L2-resident (FETCH 154->35MB).
// r11-r14 POST-MORTEMS: launch_bounds(,3) -> Q remat (FETCH ~1GB); grid=512=2/CU exactly so
//   3rd block impossible; setprio negative in lockstep structure; accS chain-split -> spill.
// r15: hi/lo-interleaved u32 K/P in LDS + v_perm unpack: -2us (kept; best measured).
// r16: OPTIONAL Gram fusion (template FG): each block's 128 Y rows = Gram chunks 2y,2y+1.
//   Stage each 64-row chunk as f32 into LDS (aliases dead K buffers), compute 64x64 Gram
//   with the IDENTICAL split/MFMA sequence as k_gram (bit-identical G), write to a
//   NON-ALIASED G buffer. Eliminates the k_gram dispatch + its full Y re-read.
//   FG=0 path is exactly r15 (used when workspace can't fit the separate G).
template<int FG>
__global__ __launch_bounds__(256, 2) void k_attn(
        const __bf16* __restrict__ Xh, const __bf16* __restrict__ Xl,
        const float* __restrict__ X0g, const float* __restrict__ X128g,
        const int* __restrict__ mask, const int* __restrict__ mflag,
        const __bf16* __restrict__ Woh, const __bf16* __restrict__ Wol,
        const float* __restrict__ bo,
        float* __restrict__ Y, float* __restrict__ Y2,
        float* __restrict__ G) {
    extern __shared__ char smem[];
    // KBI[2]: interleaved K tile, 32 keys x 132 u32 (4224 u32 = 16896 B) per buffer
    unsigned* KBI = (unsigned*)smem;
    // Pbi: per-wave interleaved P, 32 rows x 36 u32 (1152 u32 = 4608 B) per wave
    unsigned* Pbi = (unsigned*)(smem + 33792);
    __shared__ float K0s[2][KT];
    __shared__ float K128s[2][KT];
    __shared__ int   Ms[2][KT];

    const int b    = blockIdx.x;                // batch on x: XCD-local L2 reuse
    const int qb   = blockIdx.y * QB;
    const int t    = threadIdx.x;
    const int w    = t >> 6;
    const int l    = t & 63;
    const int l31  = l & 31;
    const int half = l >> 5;
    const int is8  = *mflag;

    // ---- Q fragments (A operand): A[m=lane&31][k=half*8+j], hi/lo, 8 k-steps over comps 0..127 ----
    const size_t qrow = (size_t)(b * N_ + qb + w * 32 + l31);
    bf16x8 qfh[8], qfl[8];
    #pragma unroll
    for (int ks = 0; ks < 8; ++ks) {
        qfh[ks] = *(const bf16x8*)(Xh + qrow * D_ + ks * 16 + half * 8);
        qfl[ks] = *(const bf16x8*)(Xl + qrow * D_ + ks * 16 + half * 8);
    }
    float q0[16], q128[16];
    #pragma unroll
    for (int r = 0; r < 16; ++r) {
        const int qr = (r & 3) + 8 * (r >> 2) + 4 * half;
        q0[r]   = X0g[b * N_ + qb + w * 32 + qr];
        q128[r] = X128g[b * N_ + qb + w * 32 + qr];
    }

    // ---- staging: global hi/lo bf16x8 -> regs; interleave to u32 at store time ----
    const int skey = t >> 3, sck = t & 7;       // 32 keys x 8 chunks of 16 comps
    bf16x8 svh0, svh1, svl0, svl1;
    float  sK0 = 0.f, sK128 = 0.f;
    int    sM = 0;
    auto ldg_tile = [&](int kt) {
        const size_t kr = (size_t)(b * N_ + kt * KT + skey);
        svh0 = *(const bf16x8*)(Xh + kr * D_ + sck * 16);
        svh1 = *(const bf16x8*)(Xh + kr * D_ + sck * 16 + 8);
        svl0 = *(const bf16x8*)(Xl + kr * D_ + sck * 16);
        svl1 = *(const bf16x8*)(Xl + kr * D_ + sck * 16 + 8);
        if (t < KT) {
            sK0   = X0g[b * N_ + kt * KT + t];
            sK128 = X128g[b * N_ + kt * KT + t];
            sM    = read_mask(mask, is8, b * N_ + kt * KT + t);
        }
    };
    auto st_tile = [&](int buf) {
        unsigned* KI = KBI + buf * 4224;
        union { bf16x8 v; unsigned d[4]; } H0, H1, L0, L1;
        H0.v = svh0; H1.v = svh1; L0.v = svl0; L1.v = svl1;
        u32x4v o0 = { pk_lo16(H0.d[0], L0.d[0]), pk_hi16(H0.d[0], L0.d[0]),
                      pk_lo16(H0.d[1], L0.d[1]), pk_hi16(H0.d[1], L0.d[1]) };
        u32x4v o1 = { pk_lo16(H0.d[2], L0.d[2]), pk_hi16(H0.d[2], L0.d[2]),
                      pk_lo16(H0.d[3], L0.d[3]), pk_hi16(H0.d[3], L0.d[3]) };
        u32x4v o2 = { pk_lo16(H1.d[0], L1.d[0]), pk_hi16(H1.d[0], L1.d[0]),
                      pk_lo16(H1.d[1], L1.d[1]), pk_hi16(H1.d[1], L1.d[1]) };
        u32x4v o3 = { pk_lo16(H1.d[2], L1.d[2]), pk_hi16(H1.d[2], L1.d[2]),
                      pk_lo16(H1.d[3], L1.d[3]), pk_hi16(H1.d[3], L1.d[3]) };
        u32x4v* dst = (u32x4v*)(KI + skey * 132 + sck * 16);
        dst[0] = o0; dst[1] = o1; dst[2] = o2; dst[3] = o3;
        if (t < KT) { K0s[buf][t] = sK0; K128s[buf][t] = sK128; Ms[buf][t] = sM; }
    };

    f32x16 accM[4] = {};
    float  mu128p[16] = {};

    ldg_tile(0);
    st_tile(0);

    for (int kt = 0; kt < N_ / KT; ++kt) {
        __syncthreads();                         // buffer kt&1 fully staged by all threads
        const int cur = kt & 1;
        const int ktn = (kt < 31) ? kt + 1 : 31;
        ldg_tile(ktn);                           // global loads overlap this tile's compute

        const unsigned* KI = KBI + cur * 4224;

        // ---- phase A: S = Q . K (b128 row reads + perm unpack) ----
        f32x16 accS = {};
        #pragma unroll
        for (int ks = 0; ks < 8; ++ks) {
            const unsigned* p = KI + l31 * 132 + ks * 16 + half * 8;
            u32x4v ua = *(const u32x4v*)(p);
            u32x4v ub = *(const u32x4v*)(p + 4);
            union { bf16x8 v; unsigned d[4]; } BH, BL;
            BH.d[0] = pk_lo16(ua[0], ua[1]); BL.d[0] = pk_hi16(ua[0], ua[1]);
            BH.d[1] = pk_lo16(ua[2], ua[3]); BL.d[1] = pk_hi16(ua[2], ua[3]);
            BH.d[2] = pk_lo16(ub[0], ub[1]); BL.d[2] = pk_hi16(ub[0], ub[1]);
            BH.d[3] = pk_lo16(ub[2], ub[3]); BL.d[3] = pk_hi16(ub[2], ub[3]);
            accS = MFMA(qfh[ks], BH.v, accS);
            accS = MFMA(qfh[ks], BL.v, accS);
            accS = MFMA(qfl[ks], BH.v, accS);
        }
        const float k0v = K0s[cur][l31], k128v = K128s[cur][l31];
        const int   mv  = Ms[cur][l31];
        #pragma unroll
        for (int r = 0; r < 16; ++r) {
            float sc = (2.f * q0[r] * k0v - accS[r] - q128[r] * k128v) * SCALE;
            float e  = mv ? __expf(sc) : 0.f;
            mu128p[r] += e * k128v;
            __bf16 eh = (__bf16)e;
            __bf16 el = (__bf16)(e - (float)eh);
            unsigned pw = (unsigned)__builtin_bit_cast(unsigned short, eh)
                        | ((unsigned)__builtin_bit_cast(unsigned short, el) << 16);
            const int qr = (r & 3) + 8 * (r >> 2) + 4 * half;
            Pbi[w * 1152 + qr * 36 + l31] = pw;
        }

        // ---- phase B: mu += P . X; b32 column gather (one read = hi+lo) + perm unpack ----
        #pragma unroll
        for (int ks = 0; ks < 2; ++ks) {
            const unsigned* pp = Pbi + w * 1152 + l31 * 36 + ks * 16 + half * 8;
            u32x4v pa = *(const u32x4v*)(pp);
            u32x4v pb = *(const u32x4v*)(pp + 4);
            union { bf16x8 v; unsigned d[4]; } AH, AL;
            AH.d[0] = pk_lo16(pa[0], pa[1]); AL.d[0] = pk_hi16(pa[0], pa[1]);
            AH.d[1] = pk_lo16(pa[2], pa[3]); AL.d[1] = pk_hi16(pa[2], pa[3]);
            AH.d[2] = pk_lo16(pb[0], pb[1]); AL.d[2] = pk_hi16(pb[0], pb[1]);
            AH.d[3] = pk_lo16(pb[2], pb[3]); AL.d[3] = pk_hi16(pb[2], pb[3]);
            #pragma unroll
            for (int nt = 0; nt < 4; ++nt) {
                const unsigned* kb = KI + (ks * 16 + half * 8) * 132 + nt * 32 + l31;
                unsigned u[8];
                #pragma unroll
                for (int j = 0; j < 8; ++j) u[j] = kb[j * 132];
                union { bf16x8 v; unsigned d[4]; } BH, BL;
                BH.d[0] = pk_lo16(u[0], u[1]); BL.d[0] = pk_hi16(u[0], u[1]);
                BH.d[1] = pk_lo16(u[2], u[3]); BL.d[1] = pk_hi16(u[2], u[3]);
                BH.d[2] = pk_lo16(u[4], u[5]); BL.d[2] = pk_hi16(u[4], u[5]);
                BH.d[3] = pk_lo16(u[6], u[7]); BL.d[3] = pk_hi16(u[6], u[7]);
                accM[nt] = MFMA(AH.v, BH.v, accM[nt]);
                accM[nt] = MFMA(AH.v, BL.v, accM[nt]);
                accM[nt] = MFMA(AL.v, BH.v, accM[nt]);
            }
        }

        st_tile(cur ^ 1);                        // write next buffer (nobody reads it this tile)
    }

    #pragma unroll
    for (int r = 0; r < 16; ++r) mu128p[r] = half_sum32(mu128p[r], half);
    float rno[16];
    #pragma unroll
    for (int r = 0; r < 16; ++r) {
        float p = 0.f;
        #pragma unroll
        for (int nt = 0; nt < 4; ++nt) p += accM[nt][r] * accM[nt][r];
        if (l31 == 0) p -= 2.f * accM[0][r] * accM[0][r];
        p = half_sum32(p, half);
        float negI = -(p + mu128p[r] * mu128p[r]);
        negI = fmaxf(negI, 1e-7f);
        rno[r] = 1.f / (SCf * sqrtf(negI));
    }
    #pragma unroll
    for (int nt = 0; nt < 4; ++nt)
        #pragma unroll
        for (int r = 0; r < 16; ++r) accM[nt][r] *= rno[r];
    #pragma unroll
    for (int r = 0; r < 16; ++r) mu128p[r] *= rno[r];

    __syncthreads();                             // done with KBI/Pbi; alias as MuA
    __bf16* MuA = (__bf16*)smem + w * (32 * 148);
    #pragma unroll
    for (int r = 0; r < 16; ++r) {
        const int qr = (r & 3) + 8 * (r >> 2) + 4 * half;
        #pragma unroll
        for (int nt = 0; nt < 4; ++nt)
            MuA[qr * 148 + nt * 32 + l31] = (__bf16)accM[nt][r];
        if (l31 == 0) MuA[qr * 148 + 128] = (__bf16)mu128p[r];
        if (l31 >= 1 && l31 <= 15) MuA[qr * 148 + 128 + l31] = (__bf16)0.f;
    }
    bf16x8 Ah[9];
    #pragma unroll
    for (int ks = 0; ks < 9; ++ks) Ah[ks] = ld_lds8(MuA + l31 * 148 + ks * 16 + half * 8);
    #pragma unroll
    for (int r = 0; r < 16; ++r) {
        const int qr = (r & 3) + 8 * (r >> 2) + 4 * half;
        #pragma unroll
        for (int nt = 0; nt < 4; ++nt) {
            float m = accM[nt][r];
            MuA[qr * 148 + nt * 32 + l31] = (__bf16)(m - (float)(__bf16)m);
        }
        if (l31 == 0) {
            float m = mu128p[r];
            MuA[qr * 148 + 128] = (__bf16)(m - (float)(__bf16)m);
        }
    }
    bf16x8 Al[9];
    #pragma unroll
    for (int ks = 0; ks < 9; ++ks) Al[ks] = ld_lds8(MuA + l31 * 148 + ks * 16 + half * 8);

    f32x16 accU[4] = {};
    #pragma unroll
    for (int ks = 0; ks < 9; ++ks) {
        #pragma unroll
        for (int nt = 0; nt < 4; ++nt) {
            bf16x8 bh = *(const bf16x8*)(Woh + (size_t)(nt * 32 + l31) * 144 + ks * 16 + half * 8);
            bf16x8 bl = *(const bf16x8*)(Wol + (size_t)(nt * 32 + l31) * 144 + ks * 16 + half * 8);
            accU[nt] = MFMA(Ah[ks], bh, accU[nt]);
            accU[nt] = MFMA(Ah[ks], bl, accU[nt]);
            accU[nt] = MFMA(Al[ks], bh, accU[nt]);
        }
    }

    float bov[4];
    #pragma unroll
    for (int nt = 0; nt < 4; ++nt) bov[nt] = bo[nt * 32 + l31];
    #pragma unroll
    for (int r = 0; r < 16; ++r) {
        float p = 0.f;
        #pragma unroll
        for (int nt = 0; nt < 4; ++nt) {
            float uv = accU[nt][r] + bov[nt];
            accU[nt][r] = uv;
            p += uv * uv;
        }
        float nn = half_sum32(p, half);
        float nu = fmaxf(sqrtf(nn), 1e-7f);
        float aa = SCf * nu;
        float cf = tanhf(aa) / aa;
        const int qr = (r & 3) + 8 * (r >> 2) + 4 * half;
        const size_t row = (size_t)(b * N_ + qb + w * 32 + qr);
        #pragma unroll
        for (int nt = 0; nt < 4; ++nt) {
            float yv = accU[nt][r] * cf;         // identical to the stored value
            accU[nt][r] = yv;                    // keep scaled Y in regs for the gram phase
            Y[row * D_ + nt * 32 + l31] = yv;
        }
        if (l31 == 0) Y2[row] = nn * cf * cf;
    }

    // ---- fused Gram: chunks 2y (waves 0,1 rows) and 2y+1 (waves 2,3 rows) ----
    if (FG) {
        float* Yt = (float*)smem;                // 64 x 132 f32 = 33792 B (aliases dead buffers)
        const int rt = w >> 1, ct = w & 1;       // 32x32 tile of the 64x64 gram block
        #pragma unroll
        for (int ph = 0; ph < 2; ++ph) {
            __syncthreads();                     // prior phase's LDS reads complete
            if ((w >> 1) == ph) {
                const int rloc = (w & 1) * 32;
                #pragma unroll
                for (int r = 0; r < 16; ++r) {
                    const int qr = (r & 3) + 8 * (r >> 2) + 4 * half;
                    #pragma unroll
                    for (int nt = 0; nt < 4; ++nt)
                        Yt[(rloc + qr) * 132 + nt * 32 + l31] = accU[nt][r];
                }
            }
            __syncthreads();
            f32x16 gacc = {};
            #pragma unroll
            for (int ks = 0; ks < 8; ++ks) {
                const int c0 = ks * 16 + half * 8;
                const float* Ar = Yt + (rt * 32 + l31) * 132 + c0;
                const float* Br = Yt + (ct * 32 + l31) * 132 + c0;
                float4 a0 = *(const float4*)(Ar);
                float4 a1 = *(const float4*)(Ar + 4);
                float4 b0 = *(const float4*)(Br);
                float4 b1 = *(const float4*)(Br + 4);
                float av[8] = {a0.x, a0.y, a0.z, a0.w, a1.x, a1.y, a1.z, a1.w};
                float bv[8] = {b0.x, b0.y, b0.z, b0.w, b1.x, b1.y, b1.z, b1.w};
                bf16x8 ah, al, bh, bl;
                #pragma unroll
                for (int j = 0; j < 8; ++j) {
                    __bf16 h = (__bf16)av[j]; ah[j] = h; al[j] = (__bf16)(av[j] - (float)h);
                    __bf16 g2 = (__bf16)bv[j]; bh[j] = g2; bl[j] = (__bf16)(bv[j] - (float)g2);
                }
                gacc = MFMA(ah, bh, gacc);
                gacc = MFMA(ah, bl, gacc);
                gacc = MFMA(al, bh, gacc);
            }
            float* Gb = G + ((size_t)(b * 16 + 2 * blockIdx.y + ph) << 12);
            #pragma unroll
            for (int r = 0; r < 16; ++r) {
                const int row = rt * 32 + (r & 3) + 8 * (r >> 2) + 4 * half;
                Gb[row * 64 + ct * 32 + l31] = gacc[r];
            }
        }
    }
}

// ---------------- standalone Gram (fallback when workspace can't fit separate G) ----------------
__global__ __launch_bounds__(256) void k_gram(const float* __restrict__ Y,
                                              float* __restrict__ G) {
    const int c = blockIdx.x, b = blockIdx.y;
    const int t = threadIdx.x, w = t >> 6, l = t & 63;
    const int l31 = l & 31, half = l >> 5;
    const int rt = w >> 1, ct = w & 1;                 // 32x32 tile of the 64x64 block
    const size_t base = (size_t)(b * N_ + c * 64);
    const float* Ar = Y + (base + rt * 32 + l31) * D_;
    const float* Br = Y + (base + ct * 32 + l31) * D_;
    f32x16 acc = {};
    #pragma unroll
    for (int ks = 0; ks < 8; ++ks) {
        const int c0 = ks * 16 + half * 8;
        float4 a0 = *(const float4*)(Ar + c0);
        float4 a1 = *(const float4*)(Ar + c0 + 4);
        float4 b0 = *(const float4*)(Br + c0);
        float4 b1 = *(const float4*)(Br + c0 + 4);
        float av[8] = {a0.x, a0.y, a0.z, a0.w, a1.x, a1.y, a1.z, a1.w};
        float bv[8] = {b0.x, b0.y, b0.z, b0.w, b1.x, b1.y, b1.z, b1.w};
        bf16x8 ah, al, bh, bl;
        #pragma unroll
        for (int j = 0; j < 8; ++j) {
            __bf16 h = (__bf16)av[j]; ah[j] = h; al[j] = (__bf16)(av[j] - (float)h);
            __bf16 g = (__bf16)bv[j]; bh[j] = g; bl[j] = (__bf16)(bv[j] - (float)g);
        }
        acc = MFMA(ah, bh, acc);
        acc = MFMA(ah, bl, acc);
        acc = MFMA(al, bh, acc);
    }
    float* Gb = G + ((size_t)(b * 16 + c) << 12);
    #pragma unroll
    for (int r = 0; r < 16; ++r) {
        const int row = rt * 32 + (r & 3) + 8 * (r >> 2) + 4 * half;
        Gb[row * 64 + ct * 32 + l31] = acc[r];
    }
}

// ---------------- Mobius fold: Gram-scan, all per-step operands in REGISTERS ----------------
__global__ __launch_bounds__(64, 1) void k_pool(const float* __restrict__ Y,
                                                const float* __restrict__ Y2,
                                                const float* __restrict__ G,
                                                const int* __restrict__ mask,
                                                const int* __restrict__ mflag,
                                                const float* __restrict__ Wf,
                                                const float* __restrict__ bf_,
                                                float* __restrict__ out) {
    __shared__ float  prt[64][65];
    __shared__ double vb[D_];
    const int b = blockIdx.x, l = threadIdx.x;
    const int is8 = *mflag;

    int cl = 0;
    for (int i = l; i < N_; i += 64) cl += read_mask(mask, is8, b * N_ + i);
    const int cntT = (int)(wave_sum64((float)cl) + 0.5f);

    const float2* __restrict__ Yp = (const float2*)(Y + (size_t)b * N_ * D_) + l;   // lane column
    const float*  __restrict__ Gp = G + ((size_t)b << 16) + l;   // block c, row i: Gp[c*4096 + i*64]
    const float*  __restrict__ Pp = Y2 + b * N_;

    float  GA[64], GB[64];
    float  py2A, py2B;
    int    msA, msB;
    float2 yring[2][16];

    #pragma unroll
    for (int i = 0; i < 64; ++i) GA[i] = Gp[i * 64];
    py2A = Pp[l];
    msA  = read_mask(mask, is8, b * N_ + l);
    #pragma unroll
    for (int k = 0; k < 16; ++k) yring[0][k] = Yp[(size_t)k * 64];

    float U0 = 0.f, U1 = 0.f, g = 0.f, Dh = 1.f, P = 0.f;

    auto chunk = [&](int c, float (&Gc)[64], float (&Gn)[64],
                     float py2c, float& py2n, int msc, int& msn) {
        const int cn = (c < 15) ? c + 1 : 15;
        #pragma unroll
        for (int i = 0; i < 64; ++i) Gn[i] = Gp[cn * 4096 + i * 64];
        py2n = Pp[cn * 64 + l];
        msn  = read_mask(mask, is8, b * N_ + cn * 64 + l);

        #pragma unroll
        for (int q = 0; q < 4; ++q) {
            #pragma unroll
            for (int k = 0; k < 16; ++k) {
                int gs = c * 64 + (q + 1) * 16 + k;
                if (gs > N_ - 1) gs = N_ - 1;
                yring[(q + 1) & 1][k] = Yp[(size_t)gs * 64];
            }
            #pragma unroll
            for (int k = 0; k < 16; ++k) {
                const int ir = q * 16 + k;                      // compile-time lane index
                const float2 yv  = yring[q & 1][k];
                const float  Gv  = Gc[ir];
                const float  py2 = readlane_f(py2c, ir);
                const bool   m   = (__builtin_amdgcn_readlane(msc, ir) != 0);
                const float Dsq   = Dh * Dh;
                const float Bh    = fmaf(-0.1f, P, Dsq);
                const float Donep = Dh * fmaf(0.1f, py2, 1.f);
                const float tP    = (0.01f * py2) * P;
                const float puy  = readlane_f(g, ir);
                const float Ahat = fmaf(0.2f, puy, Donep);
                float dh = fmaf(Dh, fmaf(0.2f, puy, Dh), tP);
                dh = fmaxf(dh, 1e-12f * Dsq);
                const float Draw = m ? dh : Dh;
                const float Am   = m ? Ahat : 1.f;
                const float Bm   = m ? Bh   : 0.f;
                const float Pn   = fmaf(Am, fmaf(Am, P, (2.f * Bm) * puy), (Bm * Bm) * py2);
                if ((k & 3) == 3) {                 // exact 2^-e rescale every 4th step
                    const int e = ilogbf(Draw);
                    const float Aef = ldexpf(Am, -e);
                    const float Bef = ldexpf(Bm, -e);
                    Dh = ldexpf(Draw, -e);
                    P  = ldexpf(Pn, -2 * e);
                    g  = fmaf(Aef, g, Bef * Gv);
                    U0 = fmaf(Aef, U0, Bef * yv.x);
                    U1 = fmaf(Aef, U1, Bef * yv.y);
                } else {
                    Dh = Draw;
                    P  = Pn;
                    g  = fmaf(Am, g, Bm * Gv);
                    U0 = fmaf(Am, U0, Bm * yv.x);
                    U1 = fmaf(Am, U1, Bm * yv.y);
                }
            }
        }
        if (c < 15) {
            const int nb = (c + 1) * 64;
            #pragma unroll
            for (int k0 = 0; k0 < 64; k0 += 16) {
                float2 tmp[16];
                #pragma unroll
                for (int k = 0; k < 16; ++k) tmp[k] = Yp[(size_t)(nb + k0 + k) * 64];
                #pragma unroll
                for (int k = 0; k < 16; ++k)
                    prt[k0 + k][l] = fmaf(U0, tmp[k].x, U1 * tmp[k].y);
            }
            float s0 = 0.f, s1 = 0.f, s2 = 0.f, s3 = 0.f;
            #pragma unroll
            for (int p = 0; p < 64; p += 4) {
                s0 += prt[l][p];     s1 += prt[l][p + 1];
                s2 += prt[l][p + 2]; s3 += prt[l][p + 3];
            }
            g = (s0 + s1) + (s2 + s3);
        }
    };

    for (int cc = 0; cc < 8; ++cc) {
        chunk(2 * cc,     GA, GB, py2A, py2B, msA, msB);
        chunk(2 * cc + 1, GB, GA, py2B, py2A, msB, msA);
    }

    const double SCd = 0.31622776601683794;
    const double sD = 1.0 / (double)Dh;
    double a0 = sD * (double)U0, a1 = sD * (double)U1;
    double n2 = fmax((double)P * (sD * sD), 0.0);
    double n = sqrt(n2);
    double tt = SCd * n;
    tt = fmin(fmax(tt, 1e-7), 1.0 - 1e-6);
    int cm = cntT > 0 ? cntT : 1;
    float rf = (float)(1.0 / (double)cm);        // ref casts r to float32
    double r = (double)rf;
    double dv = fmax(SCd * n, 1e-7);
    double f = tanh(r * atanh(tt)) / dv;
    double p0 = a0 * f, p1 = a1 * f;
    double q2;
    if (cntT == 0) {                             // fallback: first token's y
        float2 y0v = *(const float2*)(Y + (size_t)(b * N_) * D_ + 2 * l);
        p0 = y0v.x; p1 = y0v.y;
        q2 = (double)Y2[b * N_];
    } else {
        q2 = f * f * n2;
    }
    double npn = fmax(sqrt(q2), 1e-7);
    double t2 = fmin(fmax(SCd * npn, 1e-7), 1.0 - 1e-6);
    double f2 = atanh(t2) / (SCd * npn);
    vb[2 * l]     = p0 * f2;
    vb[2 * l + 1] = p1 * f2;
    __syncthreads();

    if (l < NC_) {
        double o = (double)bf_[l];
        for (int d = 0; d < D_; ++d) o += vb[d] * (double)Wf[l * D_ + d];
        out[b * NC_ + l] = (float)o;
    }
}

extern "C" void kernel_launch(void* const* d_in, const int* in_sizes, int n_in,
                              void* d_out, int out_size, void* d_ws, size_t ws_size,
                              hipStream_t stream) {
    const int*   tok  = (const int*)d_in[0];
    const int*   mask = (const int*)d_in[1];
    const float* emb  = (const float*)d_in[2];
    const float* Wo   = (const float*)d_in[3];
    const float* bo   = (const float*)d_in[4];
    const float* Wf   = (const float*)d_in[5];
    const float* bf_  = (const float*)d_in[6];
    float* out = (float*)d_out;

    char* wsb = (char*)d_ws;
    __bf16* Xh   = (__bf16*)wsb;                              // 16,777,216 B
    __bf16* Xl   = (__bf16*)(wsb + 16777216);                 // 16,777,216 B
    float*  X0g  = (float*)(wsb + 33554432);                  //    262,144 B
    float*  X128g= (float*)(wsb + 33816576);                  //    262,144 B
    __bf16* Woh  = (__bf16*)(wsb + 34078720);                 //     36,864 B
    __bf16* Wol  = (__bf16*)(wsb + 34115584);                 //     36,864 B
    float*  Y    = (float*)(wsb + 34152448);                  // 33,554,432 B
    float*  Y2   = (float*)(wsb + 67706880);                  //    262,144 B
    int*    flag = (int*)(wsb + 67969024);                    // 4 B; base usage ~67.97 MB
    float*  GramA= (float*)wsb;                               // FALLBACK G: aliases Xh (dead only after ALL k_attn blocks)
    float*  GramF= (float*)(wsb + 67973120);                  // FUSED G: separate 16,777,216 B region

    const bool fg = ws_size >= 67973120ull + 16777216ull;     // room for non-aliased G?

    k_pre<<<dim3(1097), dim3(256), 0, stream>>>(tok, emb, Xh, Xl, X0g, X128g,
                                                mask, flag, Wo, Woh, Wol);
    if (fg) {
        k_attn<1><<<dim3(B_, N_ / QB), dim3(256), 52224, stream>>>(Xh, Xl, X0g, X128g, mask, flag,
                                                                   Woh, Wol, bo, Y, Y2, GramF);
        k_pool<<<dim3(B_), dim3(64), 0, stream>>>(Y, Y2, GramF, mask, flag, Wf, bf_, out);
    } else {
        k_attn<0><<<dim3(B_, N_ / QB), dim3(256), 52224, stream>>>(Xh, Xl, X0g, X128g, mask, flag,
                                                                   Woh, Wol, bo, Y, Y2, GramA);
        k_gram<<<dim3(16, B_), dim3(256), 0, stream>>>(Y, GramA);
        k_pool<<<dim3(B_), dim3(64), 0, stream>>>(Y, Y2, GramA, mask, flag, Wf, bf_, out);
    }
}

// Round 7
// 359.064 us; speedup vs baseline: 2.9777x; 1.0805x over previous
//
#include <hip/hip_runtime.h>
#include <math.h>

#define B_    64
#define N_    1024
#define D_    128
#define DP1   129
#define NC_   10
#define QB    256     // queries per block (8 waves x 32)
#define KT    32      // key tile
#define SCf   0.31622776601683794f
#define SCALE 0.08804509063256238f   // 1/sqrt(129)

typedef __bf16 bf16x8 __attribute__((ext_vector_type(8)));
typedef float  f32x16 __attribute__((ext_vector_type(16)));
typedef unsigned int  u32x4v __attribute__((ext_vector_type(4)));
typedef unsigned long long ull;

#define MFMA(a, b, c) __builtin_amdgcn_mfma_f32_32x32x16_bf16((a), (b), (c), 0, 0, 0)

// v_perm_b32 packers: pk_lo16(a,b) = [a.lo16, b.lo16], pk_hi16(a,b) = [a.hi16, b.hi16]
static __device__ __forceinline__ unsigned pk_lo16(unsigned a, unsigned b) {
    return __builtin_amdgcn_perm(b, a, 0x05040100u);
}
static __device__ __forceinline__ unsigned pk_hi16(unsigned a, unsigned b) {
    return __builtin_amdgcn_perm(b, a, 0x07060302u);
}

static __device__ __forceinline__ float dpp_add_step(float f, int ctrl, int rmask) {
    if (ctrl == 0x111) { int t = __builtin_amdgcn_update_dpp(0, __builtin_bit_cast(int, f), 0x111, 0xf, 0xf, true); return f + __builtin_bit_cast(float, t); }
    if (ctrl == 0x112) { int t = __builtin_amdgcn_update_dpp(0, __builtin_bit_cast(int, f), 0x112, 0xf, 0xf, true); return f + __builtin_bit_cast(float, t); }
    if (ctrl == 0x114) { int t = __builtin_amdgcn_update_dpp(0, __builtin_bit_cast(int, f), 0x114, 0xf, 0xf, true); return f + __builtin_bit_cast(float, t); }
    if (ctrl == 0x118) { int t = __builtin_amdgcn_update_dpp(0, __builtin_bit_cast(int, f), 0x118, 0xf, 0xf, true); return f + __builtin_bit_cast(float, t); }
    if (ctrl == 0x142 && rmask == 0xa) { int t = __builtin_amdgcn_update_dpp(0, __builtin_bit_cast(int, f), 0x142, 0xa, 0xf, true); return f + __builtin_bit_cast(float, t); }
    { int t = __builtin_amdgcn_update_dpp(0, __builtin_bit_cast(int, f), 0x143, 0xc, 0xf, true); return f + __builtin_bit_cast(float, t); }
}

// full 64-lane sum, result broadcast to all lanes
static __device__ __forceinline__ float wave_sum64(float f) {
    f = dpp_add_step(f, 0x111, 0xf);
    f = dpp_add_step(f, 0x112, 0xf);
    f = dpp_add_step(f, 0x114, 0xf);
    f = dpp_add_step(f, 0x118, 0xf);
    f = dpp_add_step(f, 0x142, 0xa);
    f = dpp_add_step(f, 0x143, 0xc);
    return __builtin_bit_cast(float, __builtin_amdgcn_readlane(__builtin_bit_cast(int, f), 63));
}

// per-32-lane-half sum, each lane gets its half's total
static __device__ __forceinline__ float half_sum32(float f, int half) {
    f = dpp_add_step(f, 0x111, 0xf);
    f = dpp_add_step(f, 0x112, 0xf);
    f = dpp_add_step(f, 0x114, 0xf);
    f = dpp_add_step(f, 0x118, 0xf);
    f = dpp_add_step(f, 0x142, 0xa);
    float s0 = __builtin_bit_cast(float, __builtin_amdgcn_readlane(__builtin_bit_cast(int, f), 31));
    float s1 = __builtin_bit_cast(float, __builtin_amdgcn_readlane(__builtin_bit_cast(int, f), 63));
    return half ? s1 : s0;
}

static __device__ __forceinline__ float readlane_f(float v, int lane) {
    return __builtin_bit_cast(float, __builtin_amdgcn_readlane(__builtin_bit_cast(int, v), lane));
}

static __device__ __forceinline__ bf16x8 ld_lds8(const __bf16* p) {
    union { bf16x8 v; ull q[2]; } u;
    u.q[0] = *(const ull*)(p);
    u.q[1] = *(const ull*)(p + 4);
    return u.v;
}

static __device__ __forceinline__ int read_mask(const int* mw, int is_i8, int idx) {
    if (is_i8) return (int)((const unsigned char*)mw)[idx];
    return mw[idx];
}

// ---------------- merged prologue: prep (blocks 0..1023) + Wo (1024..1095) + mask-detect (1096) ----------------
__global__ __launch_bounds__(256) void k_pre(const int* __restrict__ tok,
                                             const float* __restrict__ emb,
                                             __bf16* __restrict__ Xh, __bf16* __restrict__ Xl,
                                             float* __restrict__ X0g, float* __restrict__ X128g,
                                             const int* __restrict__ mask_w, int* __restrict__ flag,
                                             const float* __restrict__ Wo,
                                             __bf16* __restrict__ Woh, __bf16* __restrict__ Wol) {
    const int t = threadIdx.x;
    if (blockIdx.x >= 1024) {
        if (blockIdx.x == 1096) {                    // mask dtype detect (int32 vs packed int8)
            __shared__ int bad;
            if (t == 0) bad = 0;
            __syncthreads();
            int local = 0;
            for (int i = t; i < 16384; i += 256) {
                int v = mask_w[i];
                if (v != 0 && v != 1) local = 1;
            }
            if (local) atomicOr(&bad, 1);
            __syncthreads();
            if (t == 0) *flag = bad;
        } else {                                     // Wo -> bf16 hi/lo [o][144]
            int idx = (blockIdx.x - 1024) * 256 + t;
            if (idx < 128 * 144) {
                int o = idx / 144, d = idx - o * 144;
                float v = (d < DP1) ? Wo[o * DP1 + d] : 0.f;
                __bf16 h = (__bf16)v;
                Woh[idx] = h;
                Wol[idx] = (__bf16)(v - (float)h);
            }
        }
        return;
    }
    // ---- embedding + Lorentz expmap0 -> bf16 hi/lo rows + comp0/comp128 f32 ----
    __shared__ float Xf[64][132];
    const int w = t >> 6, l = t & 63;
    const int base = blockIdx.x * 64;
    for (int it = 0; it < 16; ++it) {
        const int tk = w * 16 + it;
        const int id = tok[base + tk];
        const float2 v = ((const float2*)(emb + (size_t)id * D_))[l];
        float s = wave_sum64(v.x * v.x + v.y * v.y);
        float nv = fmaxf(sqrtf(s), 1e-7f);
        float a = SCf * nv;
        float a2 = a * a;
        float shc, ch;
        if (a < 0.5f) {
            shc = 1.f + a2 * (1.f/6.f) * (1.f + a2 * (1.f/20.f) * (1.f + a2 * (1.f/42.f)));
            ch  = 1.f + a2 * 0.5f * (1.f + a2 * (1.f/12.f) * (1.f + a2 * (1.f/30.f)));
        } else {
            float ea = __expf(a), ei = 1.f / ea;
            ch = 0.5f * (ea + ei);
            shc = 0.5f * (ea - ei) / a;
        }
        Xf[tk][1 + 2 * l] = v.x * shc;
        Xf[tk][2 + 2 * l] = v.y * shc;
        if (l == 0) Xf[tk][0] = ch / SCf;
    }
    __syncthreads();
    const int tk2 = t >> 2, dg = (t & 3) * 32;
    for (int i = 0; i < 32; i += 8) {
        bf16x8 hv, lv;
        #pragma unroll
        for (int j = 0; j < 8; ++j) {
            float f = Xf[tk2][dg + i + j];
            __bf16 h = (__bf16)f;
            hv[j] = h;
            lv[j] = (__bf16)(f - (float)h);
        }
        *(bf16x8*)(Xh + (size_t)(base + tk2) * D_ + dg + i) = hv;
        *(bf16x8*)(Xl + (size_t)(base + tk2) * D_ + dg + i) = lv;
    }
    if (t < 64) {
        X0g[base + t]   = Xf[t][0];
        X128g[base + t] = Xf[t][D_];
    }
}

// ---------------- fused MFMA attention (r17) ----------------
// r10: grid x=batch -> XCD=b%8, K panel L2-resident.
// r11-r14: launch-bound VGPR caps cause Q remat / spill (FETCH+WRITE tripwires). Avoided.
// r15: hi/lo-interleaved u32 K/P in LDS + v_perm unpack (kept).
// r16: fused Gram epilogue (kept; reworked for 8 waves).
// r17: QB 128->256 (512 threads, 8 waves, grid 64x4 = 256 blocks = 1/CU). Same 8 waves/CU
//   (2/SIMD, TLP unchanged) but the K panel is staged ONCE per CU instead of twice: per-wave
//   staging work halves (2 global b128 loads + 8 perms + 2 b128 LDS writes per thread-tile,
//   was 4/16/4). Pbi -> stride-34 u32 rows (b64 reads, 2-way-free banks). Dynamic LDS 75776B
//   (>64KB: allowed on gfx950 per m201's 128KB template; attribute set defensively).
template<int FG>
__global__ __launch_bounds__(512, 2) void k_attn(
        const __bf16* __restrict__ Xh, const __bf16* __restrict__ Xl,
        const float* __restrict__ X0g, const float* __restrict__ X128g,
        const int* __restrict__ mask, const int* __restrict__ mflag,
        const __bf16* __restrict__ Woh, const __bf16* __restrict__ Wol,
        const float* __restrict__ bo,
        float* __restrict__ Y, float* __restrict__ Y2,
        float* __restrict__ G) {
    extern __shared__ char smem[];
    // KBI[2]: interleaved K tile, 32 keys x 132 u32 (16896 B) per buffer -> 33792 B
    unsigned* KBI = (unsigned*)smem;
    // Pbi: per-wave interleaved P, 32 rows x 34 u32 stride (4352 B/wave x 8 = 34816 B)
    unsigned* Pbi = (unsigned*)(smem + 33792);
    __shared__ float K0s[2][KT];
    __shared__ float K128s[2][KT];
    __shared__ int   Ms[2][KT];

    const int b    = blockIdx.x;                // batch on x: XCD-local L2 reuse
    const int qb   = blockIdx.y * QB;
    const int t    = threadIdx.x;
    const int w    = t >> 6;                    // 0..7
    const int l    = t & 63;
    const int l31  = l & 31;
    const int half = l >> 5;
    const int is8  = *mflag;

    // ---- Q fragments (A operand): A[m=lane&31][k=half*8+j], hi/lo, 8 k-steps over comps 0..127 ----
    const size_t qrow = (size_t)(b * N_ + qb + w * 32 + l31);
    bf16x8 qfh[8], qfl[8];
    #pragma unroll
    for (int ks = 0; ks < 8; ++ks) {
        qfh[ks] = *(const bf16x8*)(Xh + qrow * D_ + ks * 16 + half * 8);
        qfl[ks] = *(const bf16x8*)(Xl + qrow * D_ + ks * 16 + half * 8);
    }
    float q0[16], q128[16];
    #pragma unroll
    for (int r = 0; r < 16; ++r) {
        const int qr = (r & 3) + 8 * (r >> 2) + 4 * half;
        q0[r]   = X0g[b * N_ + qb + w * 32 + qr];
        q128[r] = X128g[b * N_ + qb + w * 32 + qr];
    }

    // ---- staging: 512 threads, each stages 8 comps (one bf16x8 hi + lo) of one key ----
    const int skey = t >> 4, sck = t & 15;      // 32 keys x 16 granules of 8 comps
    bf16x8 svh, svl;
    float  sK0 = 0.f, sK128 = 0.f;
    int    sM = 0;
    auto ldg_tile = [&](int kt) {
        const size_t kr = (size_t)(b * N_ + kt * KT + skey);
        svh = *(const bf16x8*)(Xh + kr * D_ + sck * 8);
        svl = *(const bf16x8*)(Xl + kr * D_ + sck * 8);
        if (t < KT) {
            sK0   = X0g[b * N_ + kt * KT + t];
            sK128 = X128g[b * N_ + kt * KT + t];
            sM    = read_mask(mask, is8, b * N_ + kt * KT + t);
        }
    };
    auto st_tile = [&](int buf) {
        unsigned* KI = KBI + buf * 4224;
        union { bf16x8 v; unsigned d[4]; } H, L;
        H.v = svh; L.v = svl;
        u32x4v o0 = { pk_lo16(H.d[0], L.d[0]), pk_hi16(H.d[0], L.d[0]),
                      pk_lo16(H.d[1], L.d[1]), pk_hi16(H.d[1], L.d[1]) };
        u32x4v o1 = { pk_lo16(H.d[2], L.d[2]), pk_hi16(H.d[2], L.d[2]),
                      pk_lo16(H.d[3], L.d[3]), pk_hi16(H.d[3], L.d[3]) };
        u32x4v* dst = (u32x4v*)(KI + skey * 132 + sck * 8);
        dst[0] = o0; dst[1] = o1;
        if (t < KT) { K0s[buf][t] = sK0; K128s[buf][t] = sK128; Ms[buf][t] = sM; }
    };

    f32x16 accM[4] = {};
    float  mu128p[16] = {};

    ldg_tile(0);
    st_tile(0);

    for (int kt = 0; kt < N_ / KT; ++kt) {
        __syncthreads();                         // buffer kt&1 fully staged by all threads
        const int cur = kt & 1;
        const int ktn = (kt < 31) ? kt + 1 : 31;
        ldg_tile(ktn);                           // global loads overlap this tile's compute

        const unsigned* KI = KBI + cur * 4224;

        // ---- phase A: S = Q . K (b128 row reads + perm unpack) ----
        f32x16 accS = {};
        #pragma unroll
        for (int ks = 0; ks < 8; ++ks) {
            const unsigned* p = KI + l31 * 132 + ks * 16 + half * 8;
            u32x4v ua = *(const u32x4v*)(p);
            u32x4v ub = *(const u32x4v*)(p + 4);
            union { bf16x8 v; unsigned d[4]; } BH, BL;
            BH.d[0] = pk_lo16(ua[0], ua[1]); BL.d[0] = pk_hi16(ua[0], ua[1]);
            BH.d[1] = pk_lo16(ua[2], ua[3]); BL.d[1] = pk_hi16(ua[2], ua[3]);
            BH.d[2] = pk_lo16(ub[0], ub[1]); BL.d[2] = pk_hi16(ub[0], ub[1]);
            BH.d[3] = pk_lo16(ub[2], ub[3]); BL.d[3] = pk_hi16(ub[2], ub[3]);
            accS = MFMA(qfh[ks], BH.v, accS);
            accS = MFMA(qfh[ks], BL.v, accS);
            accS = MFMA(qfl[ks], BH.v, accS);
        }
        const float k0v = K0s[cur][l31], k128v = K128s[cur][l31];
        const int   mv  = Ms[cur][l31];
        #pragma unroll
        for (int r = 0; r < 16; ++r) {
            float sc = (2.f * q0[r] * k0v - accS[r] - q128[r] * k128v) * SCALE;
            float e  = mv ? __expf(sc) : 0.f;
            mu128p[r] += e * k128v;
            __bf16 eh = (__bf16)e;
            __bf16 el = (__bf16)(e - (float)eh);
            unsigned pw = (unsigned)__builtin_bit_cast(unsigned short, eh)
                        | ((unsigned)__builtin_bit_cast(unsigned short, el) << 16);
            const int qr = (r & 3) + 8 * (r >> 2) + 4 * half;
            Pbi[w * 1088 + qr * 34 + l31] = pw;
        }

        // ---- phase B: mu += P . X; b32 column gather (one read = hi+lo) + perm unpack ----
        #pragma unroll
        for (int ks = 0; ks < 2; ++ks) {
            const unsigned* pp = Pbi + w * 1088 + l31 * 34 + ks * 16 + half * 8;
            union { unsigned u[8]; ull q[4]; } P;
            const ull* pq = (const ull*)pp;
            P.q[0] = pq[0]; P.q[1] = pq[1]; P.q[2] = pq[2]; P.q[3] = pq[3];
            union { bf16x8 v; unsigned d[4]; } AH, AL;
            AH.d[0] = pk_lo16(P.u[0], P.u[1]); AL.d[0] = pk_hi16(P.u[0], P.u[1]);
            AH.d[1] = pk_lo16(P.u[2], P.u[3]); AL.d[1] = pk_hi16(P.u[2], P.u[3]);
            AH.d[2] = pk_lo16(P.u[4], P.u[5]); AL.d[2] = pk_hi16(P.u[4], P.u[5]);
            AH.d[3] = pk_lo16(P.u[6], P.u[7]); AL.d[3] = pk_hi16(P.u[6], P.u[7]);
            #pragma unroll
            for (int nt = 0; nt < 4; ++nt) {
                const unsigned* kb = KI + (ks * 16 + half * 8) * 132 + nt * 32 + l31;
                unsigned u[8];
                #pragma unroll
                for (int j = 0; j < 8; ++j) u[j] = kb[j * 132];
                union { bf16x8 v; unsigned d[4]; } BH, BL;
                BH.d[0] = pk_lo16(u[0], u[1]); BL.d[0] = pk_hi16(u[0], u[1]);
                BH.d[1] = pk_lo16(u[2], u[3]); BL.d[1] = pk_hi16(u[2], u[3]);
                BH.d[2] = pk_lo16(u[4], u[5]); BL.d[2] = pk_hi16(u[4], u[5]);
                BH.d[3] = pk_lo16(u[6], u[7]); BL.d[3] = pk_hi16(u[6], u[7]);
                accM[nt] = MFMA(AH.v, BH.v, accM[nt]);
                accM[nt] = MFMA(AH.v, BL.v, accM[nt]);
                accM[nt] = MFMA(AL.v, BH.v, accM[nt]);
            }
        }

        st_tile(cur ^ 1);                        // write next buffer (nobody reads it this tile)
    }

    #pragma unroll
    for (int r = 0; r < 16; ++r) mu128p[r] = half_sum32(mu128p[r], half);
    float rno[16];
    #pragma unroll
    for (int r = 0; r < 16; ++r) {
        float p = 0.f;
        #pragma unroll
        for (int nt = 0; nt < 4; ++nt) p += accM[nt][r] * accM[nt][r];
        if (l31 == 0) p -= 2.f * accM[0][r] * accM[0][r];
        p = half_sum32(p, half);
        float negI = -(p + mu128p[r] * mu128p[r]);
        negI = fmaxf(negI, 1e-7f);
        rno[r] = 1.f / (SCf * sqrtf(negI));
    }
    #pragma unroll
    for (int nt = 0; nt < 4; ++nt)
        #pragma unroll
        for (int r = 0; r < 16; ++r) accM[nt][r] *= rno[r];
    #pragma unroll
    for (int r = 0; r < 16; ++r) mu128p[r] *= rno[r];

    __syncthreads();                             // done with KBI/Pbi; alias as MuA (9472 B/wave x 8 = 75776)
    __bf16* MuA = (__bf16*)smem + w * (32 * 148);
    #pragma unroll
    for (int r = 0; r < 16; ++r) {
        const int qr = (r & 3) + 8 * (r >> 2) + 4 * half;
        #pragma unroll
        for (int nt = 0; nt < 4; ++nt)
            MuA[qr * 148 + nt * 32 + l31] = (__bf16)accM[nt][r];
        if (l31 == 0) MuA[qr * 148 + 128] = (__bf16)mu128p[r];
        if (l31 >= 1 && l31 <= 15) MuA[qr * 148 + 128 + l31] = (__bf16)0.f;
    }
    bf16x8 Ah[9];
    #pragma unroll
    for (int ks = 0; ks < 9; ++ks) Ah[ks] = ld_lds8(MuA + l31 * 148 + ks * 16 + half * 8);
    #pragma unroll
    for (int r = 0; r < 16; ++r) {
        const int qr = (r & 3) + 8 * (r >> 2) + 4 * half;
        #pragma unroll
        for (int nt = 0; nt < 4; ++nt) {
            float m = accM[nt][r];
            MuA[qr * 148 + nt * 32 + l31] = (__bf16)(m - (float)(__bf16)m);
        }
        if (l31 == 0) {
            float m = mu128p[r];
            MuA[qr * 148 + 128] = (__bf16)(m - (float)(__bf16)m);
        }
    }
    bf16x8 Al[9];
    #pragma unroll
    for (int ks = 0; ks < 9; ++ks) Al[ks] = ld_lds8(MuA + l31 * 148 + ks * 16 + half * 8);

    f32x16 accU[4] = {};
    #pragma unroll
    for (int ks = 0; ks < 9; ++ks) {
        #pragma unroll
        for (int nt = 0; nt < 4; ++nt) {
            bf16x8 bh = *(const bf16x8*)(Woh + (size_t)(nt * 32 + l31) * 144 + ks * 16 + half * 8);
            bf16x8 bl = *(const bf16x8*)(Wol + (size_t)(nt * 32 + l31) * 144 + ks * 16 + half * 8);
            accU[nt] = MFMA(Ah[ks], bh, accU[nt]);
            accU[nt] = MFMA(Ah[ks], bl, accU[nt]);
            accU[nt] = MFMA(Al[ks], bh, accU[nt]);
        }
    }

    float bov[4];
    #pragma unroll
    for (int nt = 0; nt < 4; ++nt) bov[nt] = bo[nt * 32 + l31];
    #pragma unroll
    for (int r = 0; r < 16; ++r) {
        float p = 0.f;
        #pragma unroll
        for (int nt = 0; nt < 4; ++nt) {
            float uv = accU[nt][r] + bov[nt];
            accU[nt][r] = uv;
            p += uv * uv;
        }
        float nn = half_sum32(p, half);
        float nu = fmaxf(sqrtf(nn), 1e-7f);
        float aa = SCf * nu;
        float cf = tanhf(aa) / aa;
        const int qr = (r & 3) + 8 * (r >> 2) + 4 * half;
        const size_t row = (size_t)(b * N_ + qb + w * 32 + qr);
        #pragma unroll
        for (int nt = 0; nt < 4; ++nt) {
            float yv = accU[nt][r] * cf;
            accU[nt][r] = yv;                    // keep scaled Y in regs for the gram phase
            Y[row * D_ + nt * 32 + l31] = yv;
        }
        if (l31 == 0) Y2[row] = nn * cf * cf;
    }

    // ---- fused Gram: 4 chunks (4y..4y+3); 2 rounds x 2 parallel 4-wave groups ----
    if (FG) {
        float* Yt0 = (float*)smem;               // 64 x 132 f32 = 33792 B
        float* Yt1 = (float*)(smem + 33792);     // second buffer
        const int g  = w >> 2;                   // wave group: 0 (waves 0-3), 1 (waves 4-7)
        const int lw = w & 3;
        const int rt = lw >> 1, ct = lw & 1;     // 32x32 tile of the 64x64 gram block
        float* Ytg = g ? Yt1 : Yt0;
        #pragma unroll
        for (int ph = 0; ph < 2; ++ph) {
            __syncthreads();                     // prior phase's LDS reads complete
            if ((lw >> 1) == ph) {               // staging waves: {4g+2ph, 4g+2ph+1}
                const int rloc = (w & 1) * 32;
                #pragma unroll
                for (int r = 0; r < 16; ++r) {
                    const int qr = (r & 3) + 8 * (r >> 2) + 4 * half;
                    #pragma unroll
                    for (int nt = 0; nt < 4; ++nt)
                        Ytg[(rloc + qr) * 132 + nt * 32 + l31] = accU[nt][r];
                }
            }
            __syncthreads();
            f32x16 gacc = {};
            #pragma unroll
            for (int ks = 0; ks < 8; ++ks) {
                const int c0 = ks * 16 + half * 8;
                const float* Ar = Ytg + (rt * 32 + l31) * 132 + c0;
                const float* Br = Ytg + (ct * 32 + l31) * 132 + c0;
                float4 a0 = *(const float4*)(Ar);
                float4 a1 = *(const float4*)(Ar + 4);
                float4 b0 = *(const float4*)(Br);
                float4 b1 = *(const float4*)(Br + 4);
                float av[8] = {a0.x, a0.y, a0.z, a0.w, a1.x, a1.y, a1.z, a1.w};
                float bv[8] = {b0.x, b0.y, b0.z, b0.w, b1.x, b1.y, b1.z, b1.w};
                bf16x8 ah, al, bh, bl;
                #pragma unroll
                for (int j = 0; j < 8; ++j) {
                    __bf16 h = (__bf16)av[j]; ah[j] = h; al[j] = (__bf16)(av[j] - (float)h);
                    __bf16 g2 = (__bf16)bv[j]; bh[j] = g2; bl[j] = (__bf16)(bv[j] - (float)g2);
                }
                gacc = MFMA(ah, bh, gacc);
                gacc = MFMA(ah, bl, gacc);
                gacc = MFMA(al, bh, gacc);
            }
            float* Gb = G + ((size_t)(b * 16 + 4 * blockIdx.y + 2 * g + ph) << 12);
            #pragma unroll
            for (int r = 0; r < 16; ++r) {
                const int row = rt * 32 + (r & 3) + 8 * (r >> 2) + 4 * half;
                Gb[row * 64 + ct * 32 + l31] = gacc[r];
            }
        }
    }
}

// ---------------- standalone Gram (fallback when workspace can't fit separate G) ----------------
__global__ __launch_bounds__(256) void k_gram(const float* __restrict__ Y,
                                              float* __restrict__ G) {
    const int c = blockIdx.x, b = blockIdx.y;
    const int t = threadIdx.x, w = t >> 6, l = t & 63;
    const int l31 = l & 31, half = l >> 5;
    const int rt = w >> 1, ct = w & 1;                 // 32x32 tile of the 64x64 block
    const size_t base = (size_t)(b * N_ + c * 64);
    const float* Ar = Y + (base + rt * 32 + l31) * D_;
    const float* Br = Y + (base + ct * 32 + l31) * D_;
    f32x16 acc = {};
    #pragma unroll
    for (int ks = 0; ks < 8; ++ks) {
        const int c0 = ks * 16 + half * 8;
        float4 a0 = *(const float4*)(Ar + c0);
        float4 a1 = *(const float4*)(Ar + c0 + 4);
        float4 b0 = *(const float4*)(Br + c0);
        float4 b1 = *(const float4*)(Br + c0 + 4);
        float av[8] = {a0.x, a0.y, a0.z, a0.w, a1.x, a1.y, a1.z, a1.w};
        float bv[8] = {b0.x, b0.y, b0.z, b0.w, b1.x, b1.y, b1.z, b1.w};
        bf16x8 ah, al, bh, bl;
        #pragma unroll
        for (int j = 0; j < 8; ++j) {
            __bf16 h = (__bf16)av[j]; ah[j] = h; al[j] = (__bf16)(av[j] - (float)h);
            __bf16 g = (__bf16)bv[j]; bh[j] = g; bl[j] = (__bf16)(bv[j] - (float)g);
        }
        acc = MFMA(ah, bh, acc);
        acc = MFMA(ah, bl, acc);
        acc = MFMA(al, bh, acc);
    }
    float* Gb = G + ((size_t)(b * 16 + c) << 12);
    #pragma unroll
    for (int r = 0; r < 16; ++r) {
        const int row = rt * 32 + (r & 3) + 8 * (r >> 2) + 4 * half;
        Gb[row * 64 + ct * 32 + l31] = acc[r];
    }
}

// ---------------- Mobius fold: Gram-scan, all per-step operands in REGISTERS ----------------
__global__ __launch_bounds__(64, 1) void k_pool(const float* __restrict__ Y,
                                                const float* __restrict__ Y2,
                                                const float* __restrict__ G,
                                                const int* __restrict__ mask,
                                                const int* __restrict__ mflag,
                                                const float* __restrict__ Wf,
                                                const float* __restrict__ bf_,
                                                float* __restrict__ out) {
    __shared__ float  prt[64][65];
    __shared__ double vb[D_];
    const int b = blockIdx.x, l = threadIdx.x;
    const int is8 = *mflag;

    int cl = 0;
    for (int i = l; i < N_; i += 64) cl += read_mask(mask, is8, b * N_ + i);
    const int cntT = (int)(wave_sum64((float)cl) + 0.5f);

    const float2* __restrict__ Yp = (const float2*)(Y + (size_t)b * N_ * D_) + l;   // lane column
    const float*  __restrict__ Gp = G + ((size_t)b << 16) + l;   // block c, row i: Gp[c*4096 + i*64]
    const float*  __restrict__ Pp = Y2 + b * N_;

    float  GA[64], GB[64];
    float  py2A, py2B;
    int    msA, msB;
    float2 yring[2][16];

    #pragma unroll
    for (int i = 0; i < 64; ++i) GA[i] = Gp[i * 64];
    py2A = Pp[l];
    msA  = read_mask(mask, is8, b * N_ + l);
    #pragma unroll
    for (int k = 0; k < 16; ++k) yring[0][k] = Yp[(size_t)k * 64];

    float U0 = 0.f, U1 = 0.f, g = 0.f, Dh = 1.f, P = 0.f;

    auto chunk = [&](int c, float (&Gc)[64], float (&Gn)[64],
                     float py2c, float& py2n, int msc, int& msn) {
        const int cn = (c < 15) ? c + 1 : 15;
        #pragma unroll
        for (int i = 0; i < 64; ++i) Gn[i] = Gp[cn * 4096 + i * 64];
        py2n = Pp[cn * 64 + l];
        msn  = read_mask(mask, is8, b * N_ + cn * 64 + l);

        #pragma unroll
        for (int q = 0; q < 4; ++q) {
            #pragma unroll
            for (int k = 0; k < 16; ++k) {
                int gs = c * 64 + (q + 1) * 16 + k;
                if (gs > N_ - 1) gs = N_ - 1;
                yring[(q + 1) & 1][k] = Yp[(size_t)gs * 64];
            }
            #pragma unroll
            for (int k = 0; k < 16; ++k) {
                const int ir = q * 16 + k;                      // compile-time lane index
                const float2 yv  = yring[q & 1][k];
                const float  Gv  = Gc[ir];
                const float  py2 = readlane_f(py2c, ir);
                const bool   m   = (__builtin_amdgcn_readlane(msc, ir) != 0);
                const float Dsq   = Dh * Dh;
                const float Bh    = fmaf(-0.1f, P, Dsq);
                const float Donep = Dh * fmaf(0.1f, py2, 1.f);
                const float tP    = (0.01f * py2) * P;
                const float puy  = readlane_f(g, ir);
                const float Ahat = fmaf(0.2f, puy, Donep);
                float dh = fmaf(Dh, fmaf(0.2f, puy, Dh), tP);
                dh = fmaxf(dh, 1e-12f * Dsq);
                const float Draw = m ? dh : Dh;
                const float Am   = m ? Ahat : 1.f;
                const float Bm   = m ? Bh   : 0.f;
                const float Pn   = fmaf(Am, fmaf(Am, P, (2.f * Bm) * puy), (Bm * Bm) * py2);
                if ((k & 3) == 3) {                 // exact 2^-e rescale every 4th step
                    const int e = ilogbf(Draw);
                    const float Aef = ldexpf(Am, -e);
                    const float Bef = ldexpf(Bm, -e);
                    Dh = ldexpf(Draw, -e);
                    P  = ldexpf(Pn, -2 * e);
                    g  = fmaf(Aef, g, Bef * Gv);
                    U0 = fmaf(Aef, U0, Bef * yv.x);
                    U1 = fmaf(Aef, U1, Bef * yv.y);
                } else {
                    Dh = Draw;
                    P  = Pn;
                    g  = fmaf(Am, g, Bm * Gv);
                    U0 = fmaf(Am, U0, Bm * yv.x);
                    U1 = fmaf(Am, U1, Bm * yv.y);
                }
            }
        }
        if (c < 15) {
            const int nb = (c + 1) * 64;
            #pragma unroll
            for (int k0 = 0; k0 < 64; k0 += 16) {
                float2 tmp[16];
                #pragma unroll
                for (int k = 0; k < 16; ++k) tmp[k] = Yp[(size_t)(nb + k0 + k) * 64];
                #pragma unroll
                for (int k = 0; k < 16; ++k)
                    prt[k0 + k][l] = fmaf(U0, tmp[k].x, U1 * tmp[k].y);
            }
            float s0 = 0.f, s1 = 0.f, s2 = 0.f, s3 = 0.f;
            #pragma unroll
            for (int p = 0; p < 64; p += 4) {
                s0 += prt[l][p];     s1 += prt[l][p + 1];
                s2 += prt[l][p + 2]; s3 += prt[l][p + 3];
            }
            g = (s0 + s1) + (s2 + s3);
        }
    };

    for (int cc = 0; cc < 8; ++cc) {
        chunk(2 * cc,     GA, GB, py2A, py2B, msA, msB);
        chunk(2 * cc + 1, GB, GA, py2B, py2A, msB, msA);
    }

    const double SCd = 0.31622776601683794;
    const double sD = 1.0 / (double)Dh;
    double a0 = sD * (double)U0, a1 = sD * (double)U1;
    double n2 = fmax((double)P * (sD * sD), 0.0);
    double n = sqrt(n2);
    double tt = SCd * n;
    tt = fmin(fmax(tt, 1e-7), 1.0 - 1e-6);
    int cm = cntT > 0 ? cntT : 1;
    float rf = (float)(1.0 / (double)cm);        // ref casts r to float32
    double r = (double)rf;
    double dv = fmax(SCd * n, 1e-7);
    double f = tanh(r * atanh(tt)) / dv;
    double p0 = a0 * f, p1 = a1 * f;
    double q2;
    if (cntT == 0) {                             // fallback: first token's y
        float2 y0v = *(const float2*)(Y + (size_t)(b * N_) * D_ + 2 * l);
        p0 = y0v.x; p1 = y0v.y;
        q2 = (double)Y2[b * N_];
    } else {
        q2 = f * f * n2;
    }
    double npn = fmax(sqrt(q2), 1e-7);
    double t2 = fmin(fmax(SCd * npn, 1e-7), 1.0 - 1e-6);
    double f2 = atanh(t2) / (SCd * npn);
    vb[2 * l]     = p0 * f2;
    vb[2 * l + 1] = p1 * f2;
    __syncthreads();

    if (l < NC_) {
        double o = (double)bf_[l];
        for (int d = 0; d < D_; ++d) o += vb[d] * (double)Wf[l * D_ + d];
        out[b * NC_ + l] = (float)o;
    }
}

extern "C" void kernel_launch(void* const* d_in, const int* in_sizes, int n_in,
                              void* d_out, int out_size, void* d_ws, size_t ws_size,
                              hipStream_t stream) {
    const int*   tok  = (const int*)d_in[0];
    const int*   mask = (const int*)d_in[1];
    const float* emb  = (const float*)d_in[2];
    const float* Wo   = (const float*)d_in[3];
    const float* bo   = (const float*)d_in[4];
    const float* Wf   = (const float*)d_in[5];
    const float* bf_  = (const float*)d_in[6];
    float* out = (float*)d_out;

    char* wsb = (char*)d_ws;
    __bf16* Xh   = (__bf16*)wsb;                              // 16,777,216 B
    __bf16* Xl   = (__bf16*)(wsb + 16777216);                 // 16,777,216 B
    float*  X0g  = (float*)(wsb + 33554432);                  //    262,144 B
    float*  X128g= (float*)(wsb + 33816576);                  //    262,144 B
    __bf16* Woh  = (__bf16*)(wsb + 34078720);                 //     36,864 B
    __bf16* Wol  = (__bf16*)(wsb + 34115584);                 //     36,864 B
    float*  Y    = (float*)(wsb + 34152448);                  // 33,554,432 B
    float*  Y2   = (float*)(wsb + 67706880);                  //    262,144 B
    int*    flag = (int*)(wsb + 67969024);                    // 4 B; base usage ~67.97 MB
    float*  GramA= (float*)wsb;                               // FALLBACK G: aliases Xh (dead only after ALL k_attn blocks)
    float*  GramF= (float*)(wsb + 67973120);                  // FUSED G: separate 16,777,216 B region

    const bool fg = ws_size >= 67973120ull + 16777216ull;     // room for non-aliased G?

    static bool attr_done = false;                            // >64KB dynamic LDS opt-in (host-side, capture-safe)
    if (!attr_done) {
        hipFuncSetAttribute((const void*)(k_attn<1>), hipFuncAttributeMaxDynamicSharedMemorySize, 76800);
        hipFuncSetAttribute((const void*)(k_attn<0>), hipFuncAttributeMaxDynamicSharedMemorySize, 76800);
        attr_done = true;
    }

    k_pre<<<dim3(1097), dim3(256), 0, stream>>>(tok, emb, Xh, Xl, X0g, X128g,
                                                mask, flag, Wo, Woh, Wol);
    if (fg) {
        k_attn<1><<<dim3(B_, N_ / QB), dim3(512), 75776, stream>>>(Xh, Xl, X0g, X128g, mask, flag,
                                                                   Woh, Wol, bo, Y, Y2, GramF);
        k_pool<<<dim3(B_), dim3(64), 0, stream>>>(Y, Y2, GramF, mask, flag, Wf, bf_, out);
    } else {
        k_attn<0><<<dim3(B_, N_ / QB), dim3(512), 75776, stream>>>(Xh, Xl, X0g, X128g, mask, flag,
                                                                   Woh, Wol, bo, Y, Y2, GramA);
        k_gram<<<dim3(16, B_), dim3(256), 0, stream>>>(Y, GramA);
        k_pool<<<dim3(B_), dim3(64), 0, stream>>>(Y, Y2, GramA, mask, flag, Wf, bf_, out);
    }
}

// Round 8
// 357.989 us; speedup vs baseline: 2.9867x; 1.0030x over previous
//
#include <hip/hip_runtime.h>
#include <math.h>

#define B_    64
#define N_    1024
#define D_    128
#define DP1   129
#define NC_   10
#define QB    256     // queries per block (8 waves x 32)
#define KT    32      // key tile
#define SCf   0.31622776601683794f
#define SCALE 0.08804509063256238f   // 1/sqrt(129)

typedef __bf16 bf16x8 __attribute__((ext_vector_type(8)));
typedef float  f32x16 __attribute__((ext_vector_type(16)));
typedef unsigned int  u32x4v __attribute__((ext_vector_type(4)));
typedef unsigned long long ull;

#define MFMA(a, b, c) __builtin_amdgcn_mfma_f32_32x32x16_bf16((a), (b), (c), 0, 0, 0)

// v_perm_b32 packers: pk_lo16(a,b) = [a.lo16, b.lo16], pk_hi16(a,b) = [a.hi16, b.hi16]
static __device__ __forceinline__ unsigned pk_lo16(unsigned a, unsigned b) {
    return __builtin_amdgcn_perm(b, a, 0x05040100u);
}
static __device__ __forceinline__ unsigned pk_hi16(unsigned a, unsigned b) {
    return __builtin_amdgcn_perm(b, a, 0x07060302u);
}

static __device__ __forceinline__ float dpp_add_step(float f, int ctrl, int rmask) {
    if (ctrl == 0x111) { int t = __builtin_amdgcn_update_dpp(0, __builtin_bit_cast(int, f), 0x111, 0xf, 0xf, true); return f + __builtin_bit_cast(float, t); }
    if (ctrl == 0x112) { int t = __builtin_amdgcn_update_dpp(0, __builtin_bit_cast(int, f), 0x112, 0xf, 0xf, true); return f + __builtin_bit_cast(float, t); }
    if (ctrl == 0x114) { int t = __builtin_amdgcn_update_dpp(0, __builtin_bit_cast(int, f), 0x114, 0xf, 0xf, true); return f + __builtin_bit_cast(float, t); }
    if (ctrl == 0x118) { int t = __builtin_amdgcn_update_dpp(0, __builtin_bit_cast(int, f), 0x118, 0xf, 0xf, true); return f + __builtin_bit_cast(float, t); }
    if (ctrl == 0x142 && rmask == 0xa) { int t = __builtin_amdgcn_update_dpp(0, __builtin_bit_cast(int, f), 0x142, 0xa, 0xf, true); return f + __builtin_bit_cast(float, t); }
    { int t = __builtin_amdgcn_update_dpp(0, __builtin_bit_cast(int, f), 0x143, 0xc, 0xf, true); return f + __builtin_bit_cast(float, t); }
}

// full 64-lane sum, result broadcast to all lanes
static __device__ __forceinline__ float wave_sum64(float f) {
    f = dpp_add_step(f, 0x111, 0xf);
    f = dpp_add_step(f, 0x112, 0xf);
    f = dpp_add_step(f, 0x114, 0xf);
    f = dpp_add_step(f, 0x118, 0xf);
    f = dpp_add_step(f, 0x142, 0xa);
    f = dpp_add_step(f, 0x143, 0xc);
    return __builtin_bit_cast(float, __builtin_amdgcn_readlane(__builtin_bit_cast(int, f), 63));
}

// per-32-lane-half sum, each lane gets its half's total
static __device__ __forceinline__ float half_sum32(float f, int half) {
    f = dpp_add_step(f, 0x111, 0xf);
    f = dpp_add_step(f, 0x112, 0xf);
    f = dpp_add_step(f, 0x114, 0xf);
    f = dpp_add_step(f, 0x118, 0xf);
    f = dpp_add_step(f, 0x142, 0xa);
    float s0 = __builtin_bit_cast(float, __builtin_amdgcn_readlane(__builtin_bit_cast(int, f), 31));
    float s1 = __builtin_bit_cast(float, __builtin_amdgcn_readlane(__builtin_bit_cast(int, f), 63));
    return half ? s1 : s0;
}

static __device__ __forceinline__ float readlane_f(float v, int lane) {
    return __builtin_bit_cast(float, __builtin_amdgcn_readlane(__builtin_bit_cast(int, v), lane));
}

static __device__ __forceinline__ bf16x8 ld_lds8(const __bf16* p) {
    union { bf16x8 v; ull q[2]; } u;
    u.q[0] = *(const ull*)(p);
    u.q[1] = *(const ull*)(p + 4);
    return u.v;
}

static __device__ __forceinline__ int read_mask(const int* mw, int is_i8, int idx) {
    if (is_i8) return (int)((const unsigned char*)mw)[idx];
    return mw[idx];
}

// ---------------- merged prologue: prep (blocks 0..1023) + Wo (1024..1095) + mask-detect (1096) ----------------
__global__ __launch_bounds__(256) void k_pre(const int* __restrict__ tok,
                                             const float* __restrict__ emb,
                                             __bf16* __restrict__ Xh, __bf16* __restrict__ Xl,
                                             float* __restrict__ X0g, float* __restrict__ X128g,
                                             const int* __restrict__ mask_w, int* __restrict__ flag,
                                             const float* __restrict__ Wo,
                                             __bf16* __restrict__ Woh, __bf16* __restrict__ Wol) {
    const int t = threadIdx.x;
    if (blockIdx.x >= 1024) {
        if (blockIdx.x == 1096) {                    // mask dtype detect (int32 vs packed int8)
            __shared__ int bad;
            if (t == 0) bad = 0;
            __syncthreads();
            int local = 0;
            for (int i = t; i < 16384; i += 256) {
                int v = mask_w[i];
                if (v != 0 && v != 1) local = 1;
            }
            if (local) atomicOr(&bad, 1);
            __syncthreads();
            if (t == 0) *flag = bad;
        } else {                                     // Wo -> bf16 hi/lo [o][144]
            int idx = (blockIdx.x - 1024) * 256 + t;
            if (idx < 128 * 144) {
                int o = idx / 144, d = idx - o * 144;
                float v = (d < DP1) ? Wo[o * DP1 + d] : 0.f;
                __bf16 h = (__bf16)v;
                Woh[idx] = h;
                Wol[idx] = (__bf16)(v - (float)h);
            }
        }
        return;
    }
    // ---- embedding + Lorentz expmap0 -> bf16 hi/lo rows + comp0/comp128 f32 ----
    __shared__ float Xf[64][132];
    const int w = t >> 6, l = t & 63;
    const int base = blockIdx.x * 64;
    for (int it = 0; it < 16; ++it) {
        const int tk = w * 16 + it;
        const int id = tok[base + tk];
        const float2 v = ((const float2*)(emb + (size_t)id * D_))[l];
        float s = wave_sum64(v.x * v.x + v.y * v.y);
        float nv = fmaxf(sqrtf(s), 1e-7f);
        float a = SCf * nv;
        float a2 = a * a;
        float shc, ch;
        if (a < 0.5f) {
            shc = 1.f + a2 * (1.f/6.f) * (1.f + a2 * (1.f/20.f) * (1.f + a2 * (1.f/42.f)));
            ch  = 1.f + a2 * 0.5f * (1.f + a2 * (1.f/12.f) * (1.f + a2 * (1.f/30.f)));
        } else {
            float ea = __expf(a), ei = 1.f / ea;
            ch = 0.5f * (ea + ei);
            shc = 0.5f * (ea - ei) / a;
        }
        Xf[tk][1 + 2 * l] = v.x * shc;
        Xf[tk][2 + 2 * l] = v.y * shc;
        if (l == 0) Xf[tk][0] = ch / SCf;
    }
    __syncthreads();
    const int tk2 = t >> 2, dg = (t & 3) * 32;
    for (int i = 0; i < 32; i += 8) {
        bf16x8 hv, lv;
        #pragma unroll
        for (int j = 0; j < 8; ++j) {
            float f = Xf[tk2][dg + i + j];
            __bf16 h = (__bf16)f;
            hv[j] = h;
            lv[j] = (__bf16)(f - (float)h);
        }
        *(bf16x8*)(Xh + (size_t)(base + tk2) * D_ + dg + i) = hv;
        *(bf16x8*)(Xl + (size_t)(base + tk2) * D_ + dg + i) = lv;
    }
    if (t < 64) {
        X0g[base + t]   = Xf[t][0];
        X128g[base + t] = Xf[t][D_];
    }
}

// ---------------- fused MFMA attention (r17) ----------------
// r10: grid x=batch -> XCD=b%8, K panel L2-resident.
// r11-r14: launch-bound VGPR caps cause Q remat / spill (FETCH+WRITE tripwires). Avoided.
// r15: hi/lo-interleaved u32 K/P in LDS + v_perm unpack (kept).
// r16: fused Gram epilogue (kept; reworked for 8 waves).
// r17: QB 128->256 (512 threads, 8 waves, grid 64x4 = 256 blocks = 1/CU). Same 8 waves/CU
//   (2/SIMD, TLP unchanged) but the K panel is staged ONCE per CU instead of twice: per-wave
//   staging work halves (2 global b128 loads + 8 perms + 2 b128 LDS writes per thread-tile,
//   was 4/16/4). Pbi -> stride-34 u32 rows (b64 reads, 2-way-free banks). Dynamic LDS 75776B
//   (>64KB: allowed on gfx950 per m201's 128KB template; attribute set defensively).
template<int FG>
__global__ __launch_bounds__(512, 2) void k_attn(
        const __bf16* __restrict__ Xh, const __bf16* __restrict__ Xl,
        const float* __restrict__ X0g, const float* __restrict__ X128g,
        const int* __restrict__ mask, const int* __restrict__ mflag,
        const __bf16* __restrict__ Woh, const __bf16* __restrict__ Wol,
        const float* __restrict__ bo,
        float* __restrict__ Y, float* __restrict__ Y2,
        float* __restrict__ G) {
    extern __shared__ char smem[];
    // KBI[2]: interleaved K tile, 32 keys x 132 u32 (16896 B) per buffer -> 33792 B
    unsigned* KBI = (unsigned*)smem;
    // Pbi: per-wave interleaved P, 32 rows x 34 u32 stride (4352 B/wave x 8 = 34816 B)
    unsigned* Pbi = (unsigned*)(smem + 33792);
    __shared__ float K0s[2][KT];
    __shared__ float K128s[2][KT];
    __shared__ int   Ms[2][KT];

    const int b    = blockIdx.x;                // batch on x: XCD-local L2 reuse
    const int qb   = blockIdx.y * QB;
    const int t    = threadIdx.x;
    const int w    = t >> 6;                    // 0..7
    const int l    = t & 63;
    const int l31  = l & 31;
    const int half = l >> 5;
    const int is8  = *mflag;

    // ---- Q fragments (A operand): A[m=lane&31][k=half*8+j], hi/lo, 8 k-steps over comps 0..127 ----
    const size_t qrow = (size_t)(b * N_ + qb + w * 32 + l31);
    bf16x8 qfh[8], qfl[8];
    #pragma unroll
    for (int ks = 0; ks < 8; ++ks) {
        qfh[ks] = *(const bf16x8*)(Xh + qrow * D_ + ks * 16 + half * 8);
        qfl[ks] = *(const bf16x8*)(Xl + qrow * D_ + ks * 16 + half * 8);
    }
    float q0[16], q128[16];
    #pragma unroll
    for (int r = 0; r < 16; ++r) {
        const int qr = (r & 3) + 8 * (r >> 2) + 4 * half;
        q0[r]   = X0g[b * N_ + qb + w * 32 + qr];
        q128[r] = X128g[b * N_ + qb + w * 32 + qr];
    }

    // ---- staging: 512 threads, each stages 8 comps (one bf16x8 hi + lo) of one key ----
    const int skey = t >> 4, sck = t & 15;      // 32 keys x 16 granules of 8 comps
    bf16x8 svh, svl;
    float  sK0 = 0.f, sK128 = 0.f;
    int    sM = 0;
    auto ldg_tile = [&](int kt) {
        const size_t kr = (size_t)(b * N_ + kt * KT + skey);
        svh = *(const bf16x8*)(Xh + kr * D_ + sck * 8);
        svl = *(const bf16x8*)(Xl + kr * D_ + sck * 8);
        if (t < KT) {
            sK0   = X0g[b * N_ + kt * KT + t];
            sK128 = X128g[b * N_ + kt * KT + t];
            sM    = read_mask(mask, is8, b * N_ + kt * KT + t);
        }
    };
    auto st_tile = [&](int buf) {
        unsigned* KI = KBI + buf * 4224;
        union { bf16x8 v; unsigned d[4]; } H, L;
        H.v = svh; L.v = svl;
        u32x4v o0 = { pk_lo16(H.d[0], L.d[0]), pk_hi16(H.d[0], L.d[0]),
                      pk_lo16(H.d[1], L.d[1]), pk_hi16(H.d[1], L.d[1]) };
        u32x4v o1 = { pk_lo16(H.d[2], L.d[2]), pk_hi16(H.d[2], L.d[2]),
                      pk_lo16(H.d[3], L.d[3]), pk_hi16(H.d[3], L.d[3]) };
        u32x4v* dst = (u32x4v*)(KI + skey * 132 + sck * 8);
        dst[0] = o0; dst[1] = o1;
        if (t < KT) { K0s[buf][t] = sK0; K128s[buf][t] = sK128; Ms[buf][t] = sM; }
    };

    f32x16 accM[4] = {};
    float  mu128p[16] = {};

    ldg_tile(0);
    st_tile(0);

    for (int kt = 0; kt < N_ / KT; ++kt) {
        __syncthreads();                         // buffer kt&1 fully staged by all threads
        const int cur = kt & 1;
        const int ktn = (kt < 31) ? kt + 1 : 31;
        ldg_tile(ktn);                           // global loads overlap this tile's compute

        const unsigned* KI = KBI + cur * 4224;

        // ---- phase A: S = Q . K (b128 row reads + perm unpack) ----
        f32x16 accS = {};
        #pragma unroll
        for (int ks = 0; ks < 8; ++ks) {
            const unsigned* p = KI + l31 * 132 + ks * 16 + half * 8;
            u32x4v ua = *(const u32x4v*)(p);
            u32x4v ub = *(const u32x4v*)(p + 4);
            union { bf16x8 v; unsigned d[4]; } BH, BL;
            BH.d[0] = pk_lo16(ua[0], ua[1]); BL.d[0] = pk_hi16(ua[0], ua[1]);
            BH.d[1] = pk_lo16(ua[2], ua[3]); BL.d[1] = pk_hi16(ua[2], ua[3]);
            BH.d[2] = pk_lo16(ub[0], ub[1]); BL.d[2] = pk_hi16(ub[0], ub[1]);
            BH.d[3] = pk_lo16(ub[2], ub[3]); BL.d[3] = pk_hi16(ub[2], ub[3]);
            accS = MFMA(qfh[ks], BH.v, accS);
            accS = MFMA(qfh[ks], BL.v, accS);
            accS = MFMA(qfl[ks], BH.v, accS);
        }
        const float k0v = K0s[cur][l31], k128v = K128s[cur][l31];
        const int   mv  = Ms[cur][l31];
        #pragma unroll
        for (int r = 0; r < 16; ++r) {
            float sc = (2.f * q0[r] * k0v - accS[r] - q128[r] * k128v) * SCALE;
            float e  = mv ? __expf(sc) : 0.f;
            mu128p[r] += e * k128v;
            __bf16 eh = (__bf16)e;
            __bf16 el = (__bf16)(e - (float)eh);
            unsigned pw = (unsigned)__builtin_bit_cast(unsigned short, eh)
                        | ((unsigned)__builtin_bit_cast(unsigned short, el) << 16);
            const int qr = (r & 3) + 8 * (r >> 2) + 4 * half;
            Pbi[w * 1088 + qr * 34 + l31] = pw;
        }

        // ---- phase B: mu += P . X; b32 column gather (one read = hi+lo) + perm unpack ----
        #pragma unroll
        for (int ks = 0; ks < 2; ++ks) {
            const unsigned* pp = Pbi + w * 1088 + l31 * 34 + ks * 16 + half * 8;
            union { unsigned u[8]; ull q[4]; } P;
            const ull* pq = (const ull*)pp;
            P.q[0] = pq[0]; P.q[1] = pq[1]; P.q[2] = pq[2]; P.q[3] = pq[3];
            union { bf16x8 v; unsigned d[4]; } AH, AL;
            AH.d[0] = pk_lo16(P.u[0], P.u[1]); AL.d[0] = pk_hi16(P.u[0], P.u[1]);
            AH.d[1] = pk_lo16(P.u[2], P.u[3]); AL.d[1] = pk_hi16(P.u[2], P.u[3]);
            AH.d[2] = pk_lo16(P.u[4], P.u[5]); AL.d[2] = pk_hi16(P.u[4], P.u[5]);
            AH.d[3] = pk_lo16(P.u[6], P.u[7]); AL.d[3] = pk_hi16(P.u[6], P.u[7]);
            #pragma unroll
            for (int nt = 0; nt < 4; ++nt) {
                const unsigned* kb = KI + (ks * 16 + half * 8) * 132 + nt * 32 + l31;
                unsigned u[8];
                #pragma unroll
                for (int j = 0; j < 8; ++j) u[j] = kb[j * 132];
                union { bf16x8 v; unsigned d[4]; } BH, BL;
                BH.d[0] = pk_lo16(u[0], u[1]); BL.d[0] = pk_hi16(u[0], u[1]);
                BH.d[1] = pk_lo16(u[2], u[3]); BL.d[1] = pk_hi16(u[2], u[3]);
                BH.d[2] = pk_lo16(u[4], u[5]); BL.d[2] = pk_hi16(u[4], u[5]);
                BH.d[3] = pk_lo16(u[6], u[7]); BL.d[3] = pk_hi16(u[6], u[7]);
                accM[nt] = MFMA(AH.v, BH.v, accM[nt]);
                accM[nt] = MFMA(AH.v, BL.v, accM[nt]);
                accM[nt] = MFMA(AL.v, BH.v, accM[nt]);
            }
        }

        st_tile(cur ^ 1);                        // write next buffer (nobody reads it this tile)
    }

    #pragma unroll
    for (int r = 0; r < 16; ++r) mu128p[r] = half_sum32(mu128p[r], half);
    float rno[16];
    #pragma unroll
    for (int r = 0; r < 16; ++r) {
        float p = 0.f;
        #pragma unroll
        for (int nt = 0; nt < 4; ++nt) p += accM[nt][r] * accM[nt][r];
        if (l31 == 0) p -= 2.f * accM[0][r] * accM[0][r];
        p = half_sum32(p, half);
        float negI = -(p + mu128p[r] * mu128p[r]);
        negI = fmaxf(negI, 1e-7f);
        rno[r] = 1.f / (SCf * sqrtf(negI));
    }
    #pragma unroll
    for (int nt = 0; nt < 4; ++nt)
        #pragma unroll
        for (int r = 0; r < 16; ++r) accM[nt][r] *= rno[r];
    #pragma unroll
    for (int r = 0; r < 16; ++r) mu128p[r] *= rno[r];

    __syncthreads();                             // done with KBI/Pbi; alias as MuA (9472 B/wave x 8 = 75776)
    __bf16* MuA = (__bf16*)smem + w * (32 * 148);
    #pragma unroll
    for (int r = 0; r < 16; ++r) {
        const int qr = (r & 3) + 8 * (r >> 2) + 4 * half;
        #pragma unroll
        for (int nt = 0; nt < 4; ++nt)
            MuA[qr * 148 + nt * 32 + l31] = (__bf16)accM[nt][r];
        if (l31 == 0) MuA[qr * 148 + 128] = (__bf16)mu128p[r];
        if (l31 >= 1 && l31 <= 15) MuA[qr * 148 + 128 + l31] = (__bf16)0.f;
    }
    bf16x8 Ah[9];
    #pragma unroll
    for (int ks = 0; ks < 9; ++ks) Ah[ks] = ld_lds8(MuA + l31 * 148 + ks * 16 + half * 8);
    #pragma unroll
    for (int r = 0; r < 16; ++r) {
        const int qr = (r & 3) + 8 * (r >> 2) + 4 * half;
        #pragma unroll
        for (int nt = 0; nt < 4; ++nt) {
            float m = accM[nt][r];
            MuA[qr * 148 + nt * 32 + l31] = (__bf16)(m - (float)(__bf16)m);
        }
        if (l31 == 0) {
            float m = mu128p[r];
            MuA[qr * 148 + 128] = (__bf16)(m - (float)(__bf16)m);
        }
    }
    bf16x8 Al[9];
    #pragma unroll
    for (int ks = 0; ks < 9; ++ks) Al[ks] = ld_lds8(MuA + l31 * 148 + ks * 16 + half * 8);

    f32x16 accU[4] = {};
    #pragma unroll
    for (int ks = 0; ks < 9; ++ks) {
        #pragma unroll
        for (int nt = 0; nt < 4; ++nt) {
            bf16x8 bh = *(const bf16x8*)(Woh + (size_t)(nt * 32 + l31) * 144 + ks * 16 + half * 8);
            bf16x8 bl = *(const bf16x8*)(Wol + (size_t)(nt * 32 + l31) * 144 + ks * 16 + half * 8);
            accU[nt] = MFMA(Ah[ks], bh, accU[nt]);
            accU[nt] = MFMA(Ah[ks], bl, accU[nt]);
            accU[nt] = MFMA(Al[ks], bh, accU[nt]);
        }
    }

    float bov[4];
    #pragma unroll
    for (int nt = 0; nt < 4; ++nt) bov[nt] = bo[nt * 32 + l31];
    #pragma unroll
    for (int r = 0; r < 16; ++r) {
        float p = 0.f;
        #pragma unroll
        for (int nt = 0; nt < 4; ++nt) {
            float uv = accU[nt][r] + bov[nt];
            accU[nt][r] = uv;
            p += uv * uv;
        }
        float nn = half_sum32(p, half);
        float nu = fmaxf(sqrtf(nn), 1e-7f);
        float aa = SCf * nu;
        float cf = tanhf(aa) / aa;
        const int qr = (r & 3) + 8 * (r >> 2) + 4 * half;
        const size_t row = (size_t)(b * N_ + qb + w * 32 + qr);
        #pragma unroll
        for (int nt = 0; nt < 4; ++nt) {
            float yv = accU[nt][r] * cf;
            accU[nt][r] = yv;                    // keep scaled Y in regs for the gram phase
            Y[row * D_ + nt * 32 + l31] = yv;
        }
        if (l31 == 0) Y2[row] = nn * cf * cf;
    }

    // ---- fused Gram: 4 chunks (4y..4y+3); 2 rounds x 2 parallel 4-wave groups ----
    if (FG) {
        float* Yt0 = (float*)smem;               // 64 x 132 f32 = 33792 B
        float* Yt1 = (float*)(smem + 33792);     // second buffer
        const int g  = w >> 2;                   // wave group: 0 (waves 0-3), 1 (waves 4-7)
        const int lw = w & 3;
        const int rt = lw >> 1, ct = lw & 1;     // 32x32 tile of the 64x64 gram block
        float* Ytg = g ? Yt1 : Yt0;
        #pragma unroll
        for (int ph = 0; ph < 2; ++ph) {
            __syncthreads();                     // prior phase's LDS reads complete
            if ((lw >> 1) == ph) {               // staging waves: {4g+2ph, 4g+2ph+1}
                const int rloc = (w & 1) * 32;
                #pragma unroll
                for (int r = 0; r < 16; ++r) {
                    const int qr = (r & 3) + 8 * (r >> 2) + 4 * half;
                    #pragma unroll
                    for (int nt = 0; nt < 4; ++nt)
                        Ytg[(rloc + qr) * 132 + nt * 32 + l31] = accU[nt][r];
                }
            }
            __syncthreads();
            f32x16 gacc = {};
            #pragma unroll
            for (int ks = 0; ks < 8; ++ks) {
                const int c0 = ks * 16 + half * 8;
                const float* Ar = Ytg + (rt * 32 + l31) * 132 + c0;
                const float* Br = Ytg + (ct * 32 + l31) * 132 + c0;
                float4 a0 = *(const float4*)(Ar);
                float4 a1 = *(const float4*)(Ar + 4);
                float4 b0 = *(const float4*)(Br);
                float4 b1 = *(const float4*)(Br + 4);
                float av[8] = {a0.x, a0.y, a0.z, a0.w, a1.x, a1.y, a1.z, a1.w};
                float bv[8] = {b0.x, b0.y, b0.z, b0.w, b1.x, b1.y, b1.z, b1.w};
                bf16x8 ah, al, bh, bl;
                #pragma unroll
                for (int j = 0; j < 8; ++j) {
                    __bf16 h = (__bf16)av[j]; ah[j] = h; al[j] = (__bf16)(av[j] - (float)h);
                    __bf16 g2 = (__bf16)bv[j]; bh[j] = g2; bl[j] = (__bf16)(bv[j] - (float)g2);
                }
                gacc = MFMA(ah, bh, gacc);
                gacc = MFMA(ah, bl, gacc);
                gacc = MFMA(al, bh, gacc);
            }
            float* Gb = G + ((size_t)(b * 16 + 4 * blockIdx.y + 2 * g + ph) << 12);
            #pragma unroll
            for (int r = 0; r < 16; ++r) {
                const int row = rt * 32 + (r & 3) + 8 * (r >> 2) + 4 * half;
                Gb[row * 64 + ct * 32 + l31] = gacc[r];
            }
        }
    }
}

// ---------------- standalone Gram (fallback when workspace can't fit separate G) ----------------
__global__ __launch_bounds__(256) void k_gram(const float* __restrict__ Y,
                                              float* __restrict__ G) {
    const int c = blockIdx.x, b = blockIdx.y;
    const int t = threadIdx.x, w = t >> 6, l = t & 63;
    const int l31 = l & 31, half = l >> 5;
    const int rt = w >> 1, ct = w & 1;                 // 32x32 tile of the 64x64 block
    const size_t base = (size_t)(b * N_ + c * 64);
    const float* Ar = Y + (base + rt * 32 + l31) * D_;
    const float* Br = Y + (base + ct * 32 + l31) * D_;
    f32x16 acc = {};
    #pragma unroll
    for (int ks = 0; ks < 8; ++ks) {
        const int c0 = ks * 16 + half * 8;
        float4 a0 = *(const float4*)(Ar + c0);
        float4 a1 = *(const float4*)(Ar + c0 + 4);
        float4 b0 = *(const float4*)(Br + c0);
        float4 b1 = *(const float4*)(Br + c0 + 4);
        float av[8] = {a0.x, a0.y, a0.z, a0.w, a1.x, a1.y, a1.z, a1.w};
        float bv[8] = {b0.x, b0.y, b0.z, b0.w, b1.x, b1.y, b1.z, b1.w};
        bf16x8 ah, al, bh, bl;
        #pragma unroll
        for (int j = 0; j < 8; ++j) {
            __bf16 h = (__bf16)av[j]; ah[j] = h; al[j] = (__bf16)(av[j] - (float)h);
            __bf16 g = (__bf16)bv[j]; bh[j] = g; bl[j] = (__bf16)(bv[j] - (float)g);
        }
        acc = MFMA(ah, bh, acc);
        acc = MFMA(ah, bl, acc);
        acc = MFMA(al, bh, acc);
    }
    float* Gb = G + ((size_t)(b * 16 + c) << 12);
    #pragma unroll
    for (int r = 0; r < 16; ++r) {
        const int row = rt * 32 + (r & 3) + 8 * (r >> 2) + 4 * half;
        Gb[row * 64 + ct * 32 + l31] = acc[r];
    }
}

// ---------------- Mobius fold: Gram-scan, all per-step operands in REGISTERS ----------------
__global__ __launch_bounds__(64, 1) void k_pool(const float* __restrict__ Y,
                                                const float* __restrict__ Y2,
                                                const float* __restrict__ G,
                                                const int* __restrict__ mask,
                                                const int* __restrict__ mflag,
                                                const float* __restrict__ Wf,
                                                const float* __restrict__ bf_,
                                                float* __restrict__ out) {
    __shared__ float  prt[64][65];
    __shared__ double vb[D_];
    const int b = blockIdx.x, l = threadIdx.x;
    const int is8 = *mflag;

    int cl = 0;
    for (int i = l; i < N_; i += 64) cl += read_mask(mask, is8, b * N_ + i);
    const int cntT = (int)(wave_sum64((float)cl) + 0.5f);

    const float2* __restrict__ Yp = (const float2*)(Y + (size_t)b * N_ * D_) + l;   // lane column
    const float*  __restrict__ Gp = G + ((size_t)b << 16) + l;   // block c, row i: Gp[c*4096 + i*64]
    const float*  __restrict__ Pp = Y2 + b * N_;

    float  GA[64], GB[64];
    float  py2A, py2B;
    int    msA, msB;
    float2 yring[2][16];

    #pragma unroll
    for (int i = 0; i < 64; ++i) GA[i] = Gp[i * 64];
    py2A = Pp[l];
    msA  = read_mask(mask, is8, b * N_ + l);
    #pragma unroll
    for (int k = 0; k < 16; ++k) yring[0][k] = Yp[(size_t)k * 64];

    float U0 = 0.f, U1 = 0.f, g = 0.f, Dh = 1.f, P = 0.f;

    auto chunk = [&](int c, float (&Gc)[64], float (&Gn)[64],
                     float py2c, float& py2n, int msc, int& msn) {
        const int cn = (c < 15) ? c + 1 : 15;
        #pragma unroll
        for (int i = 0; i < 64; ++i) Gn[i] = Gp[cn * 4096 + i * 64];
        py2n = Pp[cn * 64 + l];
        msn  = read_mask(mask, is8, b * N_ + cn * 64 + l);

        #pragma unroll
        for (int q = 0; q < 4; ++q) {
            #pragma unroll
            for (int k = 0; k < 16; ++k) {
                int gs = c * 64 + (q + 1) * 16 + k;
                if (gs > N_ - 1) gs = N_ - 1;
                yring[(q + 1) & 1][k] = Yp[(size_t)gs * 64];
            }
            #pragma unroll
            for (int k = 0; k < 16; ++k) {
                const int ir = q * 16 + k;                      // compile-time lane index
                const float2 yv  = yring[q & 1][k];
                const float  Gv  = Gc[ir];
                const float  py2 = readlane_f(py2c, ir);
                const bool   m   = (__builtin_amdgcn_readlane(msc, ir) != 0);
                const float Dsq   = Dh * Dh;
                const float Bh    = fmaf(-0.1f, P, Dsq);
                const float Donep = Dh * fmaf(0.1f, py2, 1.f);
                const float tP    = (0.01f * py2) * P;
                const float puy  = readlane_f(g, ir);
                const float Ahat = fmaf(0.2f, puy, Donep);
                float dh = fmaf(Dh, fmaf(0.2f, puy, Dh), tP);
                dh = fmaxf(dh, 1e-12f * Dsq);
                const float Draw = m ? dh : Dh;
                const float Am   = m ? Ahat : 1.f;
                const float Bm   = m ? Bh   : 0.f;
                const float Pn   = fmaf(Am, fmaf(Am, P, (2.f * Bm) * puy), (Bm * Bm) * py2);
                if ((k & 3) == 3) {                 // exact 2^-e rescale every 4th step
                    const int e = ilogbf(Draw);
                    const float Aef = ldexpf(Am, -e);
                    const float Bef = ldexpf(Bm, -e);
                    Dh = ldexpf(Draw, -e);
                    P  = ldexpf(Pn, -2 * e);
                    g  = fmaf(Aef, g, Bef * Gv);
                    U0 = fmaf(Aef, U0, Bef * yv.x);
                    U1 = fmaf(Aef, U1, Bef * yv.y);
                } else {
                    Dh = Draw;
                    P  = Pn;
                    g  = fmaf(Am, g, Bm * Gv);
                    U0 = fmaf(Am, U0, Bm * yv.x);
                    U1 = fmaf(Am, U1, Bm * yv.y);
                }
            }
        }
        if (c < 15) {
            const int nb = (c + 1) * 64;
            #pragma unroll
            for (int k0 = 0; k0 < 64; k0 += 16) {
                float2 tmp[16];
                #pragma unroll
                for (int k = 0; k < 16; ++k) tmp[k] = Yp[(size_t)(nb + k0 + k) * 64];
                #pragma unroll
                for (int k = 0; k < 16; ++k)
                    prt[k0 + k][l] = fmaf(U0, tmp[k].x, U1 * tmp[k].y);
            }
            float s0 = 0.f, s1 = 0.f, s2 = 0.f, s3 = 0.f;
            #pragma unroll
            for (int p = 0; p < 64; p += 4) {
                s0 += prt[l][p];     s1 += prt[l][p + 1];
                s2 += prt[l][p + 2]; s3 += prt[l][p + 3];
            }
            g = (s0 + s1) + (s2 + s3);
        }
    };

    for (int cc = 0; cc < 8; ++cc) {
        chunk(2 * cc,     GA, GB, py2A, py2B, msA, msB);
        chunk(2 * cc + 1, GB, GA, py2B, py2A, msB, msA);
    }

    const double SCd = 0.31622776601683794;
    const double sD = 1.0 / (double)Dh;
    double a0 = sD * (double)U0, a1 = sD * (double)U1;
    double n2 = fmax((double)P * (sD * sD), 0.0);
    double n = sqrt(n2);
    double tt = SCd * n;
    tt = fmin(fmax(tt, 1e-7), 1.0 - 1e-6);
    int cm = cntT > 0 ? cntT : 1;
    float rf = (float)(1.0 / (double)cm);        // ref casts r to float32
    double r = (double)rf;
    double dv = fmax(SCd * n, 1e-7);
    double f = tanh(r * atanh(tt)) / dv;
    double p0 = a0 * f, p1 = a1 * f;
    double q2;
    if (cntT == 0) {                             // fallback: first token's y
        float2 y0v = *(const float2*)(Y + (size_t)(b * N_) * D_ + 2 * l);
        p0 = y0v.x; p1 = y0v.y;
        q2 = (double)Y2[b * N_];
    } else {
        q2 = f * f * n2;
    }
    double npn = fmax(sqrt(q2), 1e-7);
    double t2 = fmin(fmax(SCd * npn, 1e-7), 1.0 - 1e-6);
    double f2 = atanh(t2) / (SCd * npn);
    vb[2 * l]     = p0 * f2;
    vb[2 * l + 1] = p1 * f2;
    __syncthreads();

    if (l < NC_) {
        double o = (double)bf_[l];
        for (int d = 0; d < D_; ++d) o += vb[d] * (double)Wf[l * D_ + d];
        out[b * NC_ + l] = (float)o;
    }
}

extern "C" void kernel_launch(void* const* d_in, const int* in_sizes, int n_in,
                              void* d_out, int out_size, void* d_ws, size_t ws_size,
                              hipStream_t stream) {
    const int*   tok  = (const int*)d_in[0];
    const int*   mask = (const int*)d_in[1];
    const float* emb  = (const float*)d_in[2];
    const float* Wo   = (const float*)d_in[3];
    const float* bo   = (const float*)d_in[4];
    const float* Wf   = (const float*)d_in[5];
    const float* bf_  = (const float*)d_in[6];
    float* out = (float*)d_out;

    char* wsb = (char*)d_ws;
    __bf16* Xh   = (__bf16*)wsb;                              // 16,777,216 B
    __bf16* Xl   = (__bf16*)(wsb + 16777216);                 // 16,777,216 B
    float*  X0g  = (float*)(wsb + 33554432);                  //    262,144 B
    float*  X128g= (float*)(wsb + 33816576);                  //    262,144 B
    __bf16* Woh  = (__bf16*)(wsb + 34078720);                 //     36,864 B
    __bf16* Wol  = (__bf16*)(wsb + 34115584);                 //     36,864 B
    float*  Y    = (float*)(wsb + 34152448);                  // 33,554,432 B
    float*  Y2   = (float*)(wsb + 67706880);                  //    262,144 B
    int*    flag = (int*)(wsb + 67969024);                    // 4 B; base usage ~67.97 MB
    float*  GramA= (float*)wsb;                               // FALLBACK G: aliases Xh (dead only after ALL k_attn blocks)
    float*  GramF= (float*)(wsb + 67973120);                  // FUSED G: separate 16,777,216 B region

    const bool fg = ws_size >= 67973120ull + 16777216ull;     // room for non-aliased G?

    static bool attr_done = false;                            // >64KB dynamic LDS opt-in (host-side, capture-safe)
    if (!attr_done) {
        hipFuncSetAttribute((const void*)(k_attn<1>), hipFuncAttributeMaxDynamicSharedMemorySize, 76800);
        hipFuncSetAttribute((const void*)(k_attn<0>), hipFuncAttributeMaxDynamicSharedMemorySize, 76800);
        attr_done = true;
    }

    k_pre<<<dim3(1097), dim3(256), 0, stream>>>(tok, emb, Xh, Xl, X0g, X128g,
                                                mask, flag, Wo, Woh, Wol);
    if (fg) {
        k_attn<1><<<dim3(B_, N_ / QB), dim3(512), 75776, stream>>>(Xh, Xl, X0g, X128g, mask, flag,
                                                                   Woh, Wol, bo, Y, Y2, GramF);
        k_pool<<<dim3(B_), dim3(64), 0, stream>>>(Y, Y2, GramF, mask, flag, Wf, bf_, out);
    } else {
        k_attn<0><<<dim3(B_, N_ / QB), dim3(512), 75776, stream>>>(Xh, Xl, X0g, X128g, mask, flag,
                                                                   Woh, Wol, bo, Y, Y2, GramA);
        k_gram<<<dim3(16, B_), dim3(256), 0, stream>>>(Y, GramA);
        k_pool<<<dim3(B_), dim3(64), 0, stream>>>(Y, Y2, GramA, mask, flag, Wf, bf_, out);
    }
}